// Round 8
// baseline (601.524 us; speedup 1.0000x reference)
//
#include <hip/hip_runtime.h>

#define N_NODES 50000
#define N_EDGES 800000
#define N_GRAPH 1000

typedef short bf16x8 __attribute__((ext_vector_type(8)));
typedef float f32x4 __attribute__((ext_vector_type(4)));

__device__ inline short f2b(float f) {   // f32 -> bf16 (RNE)
    union { float f; unsigned u; } x; x.f = f;
    unsigned r = x.u + 0x7FFF + ((x.u >> 16) & 1);
    return (short)(r >> 16);
}
__device__ inline float b2f_lo(unsigned v) {
    union { unsigned u; float f; } x; x.u = v << 16; return x.f;
}
__device__ inline float b2f_hi(unsigned v) {
    union { unsigned u; float f; } x; x.u = v & 0xFFFF0000u; return x.f;
}
__device__ inline float b2f_s(short s) {
    union { unsigned u; float f; } x; x.u = ((unsigned)(unsigned short)s) << 16; return x.f;
}
__device__ inline unsigned pack2(short lo, short hi) {
    return ((unsigned)(unsigned short)lo) | (((unsigned)(unsigned short)hi) << 16);
}

// ---------------- f32 -> bf16 bulk convert (vectorized) ----------------
__global__ void f2b_bulk(const float* __restrict__ in, short* __restrict__ out, int n4) {
    int t = blockIdx.x * blockDim.x + threadIdx.x;
    if (t >= n4) return;
    float4 v = *(const float4*)(in + (size_t)t * 4);
    *(short4*)(out + (size_t)t * 4) = make_short4(f2b(v.x), f2b(v.y), f2b(v.z), f2b(v.w));
}

// ---------------- W[128(k)][128(c)] f32 -> WbT[c][k] bf16 ----------------
__global__ void wbt_k(const float* __restrict__ W, short* __restrict__ WbT) {
    int idx = blockIdx.x * blockDim.x + threadIdx.x;   // 16384
    int k = idx >> 7, c = idx & 127;
    WbT[(size_t)c * 128 + k] = f2b(W[idx]);
}

// ---------------- layer GEMM via MFMA: no LDS, no barriers ----------------
// BM=64, BN=128. 4 waves: wave = 32 rows x 64 cols. Frags direct from global.
__global__ __launch_bounds__(256) void gemm_mfma(const short* __restrict__ Ab,
                                                 const short* __restrict__ WbT,
                                                 float* __restrict__ out,
                                                 short* __restrict__ outb, int nrows) {
    const int tid = threadIdx.x;
    const int n0 = blockIdx.x * 64;
    const int wid = tid >> 6, lane = tid & 63;
    const int lr = lane & 15, kg = lane >> 4;
    const int wr = (wid >> 1) * 32;    // wave row offset (0/32)
    const int wc = (wid & 1) * 64;     // wave col offset (0/64)

    f32x4 acc[2][4] = {};

#pragma unroll
    for (int ks = 0; ks < 4; ks++) {
        const int k0 = ks * 32;
        bf16x8 a[2], b[4];
#pragma unroll
        for (int fm = 0; fm < 2; fm++) {
            int gr = n0 + wr + fm * 16 + lr;
            bf16x8 v = {};
            if (gr < nrows) v = *(const bf16x8*)(Ab + (size_t)gr * 128 + k0 + kg * 8);
            a[fm] = v;
        }
#pragma unroll
        for (int fn = 0; fn < 4; fn++)
            b[fn] = *(const bf16x8*)(WbT + (size_t)(wc + fn * 16 + lr) * 128 + k0 + kg * 8);
#pragma unroll
        for (int fm = 0; fm < 2; fm++)
#pragma unroll
            for (int fn = 0; fn < 4; fn++)
                acc[fm][fn] = __builtin_amdgcn_mfma_f32_16x16x32_bf16(
                    a[fm], b[fn], acc[fm][fn], 0, 0, 0);
    }
#pragma unroll
    for (int fm = 0; fm < 2; fm++) {
#pragma unroll
        for (int r = 0; r < 4; r++) {
            int gr = n0 + wr + fm * 16 + kg * 4 + r;
            if (gr < nrows) {
#pragma unroll
                for (int fn = 0; fn < 4; fn++) {
                    int col = wc + fn * 16 + lr;
                    float z = acc[fm][fn][r];
                    out[(size_t)gr * 128 + col] = z;
                    outb[(size_t)gr * 128 + col] = f2b(z);
                }
            }
        }
    }
}

// ---------------- per-node attention coefficients ----------------
__global__ void node_al(const float* __restrict__ xs, const float* __restrict__ a_s,
                        const float* __restrict__ a_d, float* __restrict__ alsrc,
                        float* __restrict__ aldst, int n) {
    int t = blockIdx.x * blockDim.x + threadIdx.x;
    if (t >= n * 8) return;
    int node = t >> 3, h = t & 7;
    const float4* xp = (const float4*)(xs + (size_t)node * 128 + h * 16);
    const float4* sp = (const float4*)(a_s + h * 16);
    const float4* dp = (const float4*)(a_d + h * 16);
    float ss = 0.f, dd = 0.f;
#pragma unroll
    for (int q = 0; q < 4; q++) {
        float4 x4 = xp[q], s4 = sp[q], d4 = dp[q];
        ss += x4.x * s4.x + x4.y * s4.y + x4.z * s4.z + x4.w * s4.w;
        dd += x4.x * d4.x + x4.y * d4.y + x4.z * d4.z + x4.w * d4.w;
    }
    alsrc[t] = ss;
    aldst[t] = dd;
}

// ---------------- aeW[k][h] = sum_c We[k, h*16+c] * ae[h,c] ----------------
__global__ void aew_k(const float* __restrict__ We, const float* __restrict__ ae,
                      float* __restrict__ aeW) {
    int t = threadIdx.x;   // 128 threads
    int k = t >> 3, h = t & 7;
    float s = 0.f;
#pragma unroll
    for (int c = 0; c < 16; c++) s += We[k * 128 + h * 16 + c] * ae[h * 16 + c];
    aeW[k * 8 + h] = s;
}

// ---------------- CSR build ----------------
__global__ void hist_k(const int* __restrict__ ei, int* __restrict__ cnt, int ne) {
    int e = blockIdx.x * blockDim.x + threadIdx.x;
    if (e < ne) atomicAdd(&cnt[ei[ne + e]], 1);
}

__global__ void scan1_k(const int* __restrict__ cnt, int* __restrict__ rowptr,
                        int* __restrict__ part, int n) {
    __shared__ int s[256];
    int tid = threadIdx.x;
    int i = blockIdx.x * 256 + tid;
    int v = (i < n) ? cnt[i] : 0;
    s[tid] = v; __syncthreads();
#pragma unroll
    for (int off = 1; off < 256; off <<= 1) {
        int t = (tid >= off) ? s[tid - off] : 0;
        __syncthreads();
        s[tid] += t;
        __syncthreads();
    }
    if (i < n) rowptr[i] = s[tid] - v;
    if (tid == 255) part[blockIdx.x] = s[255];
}

__global__ void scan2_k(int* __restrict__ part, int npart) {
    __shared__ int s[256];
    int tid = threadIdx.x;
    int v = (tid < npart) ? part[tid] : 0;
    s[tid] = v; __syncthreads();
#pragma unroll
    for (int off = 1; off < 256; off <<= 1) {
        int t = (tid >= off) ? s[tid - off] : 0;
        __syncthreads();
        s[tid] += t;
        __syncthreads();
    }
    if (tid < npart) part[tid] = s[tid] - v;
}

__global__ void scan3_k(int* __restrict__ rowptr, const int* __restrict__ part,
                        int* __restrict__ cursor, int n, int ne) {
    int i = blockIdx.x * 256 + threadIdx.x;
    if (i < n) {
        int r = rowptr[i] + part[blockIdx.x];
        rowptr[i] = r;
        cursor[i] = r;
    }
    if (i == 0) rowptr[n] = ne;
}

__global__ void scatter_k(const int* __restrict__ ei, int* __restrict__ cursor,
                          int* __restrict__ pos, int* __restrict__ csr_src, int ne) {
    int e = blockIdx.x * blockDim.x + threadIdx.x;
    if (e >= ne) return;
    int d = ei[ne + e];
    int p = atomicAdd(&cursor[d], 1);
    pos[e] = p;
    csr_src[p] = ei[e];
}

// ---------------- per-edge logits (alsrc + al_e), bf16, CSR order ----------------
__global__ __launch_bounds__(256) void ale_k(const int* __restrict__ ei,
                                             const float* __restrict__ eattr,
                                             const float* __restrict__ alsrc,
                                             const float* __restrict__ aeW,
                                             const int* __restrict__ pos,
                                             short* __restrict__ aleb, int ne) {
    __shared__ float sAe[128];
    if (threadIdx.x < 128) sAe[threadIdx.x] = aeW[threadIdx.x];
    __syncthreads();
    int e = blockIdx.x * blockDim.x + threadIdx.x;
    if (e >= ne) return;
    float ea[16];
    const float4* ep = (const float4*)(eattr + (size_t)e * 16);
#pragma unroll
    for (int q = 0; q < 4; q++) {
        float4 v = ep[q];
        ea[q * 4 + 0] = v.x; ea[q * 4 + 1] = v.y; ea[q * 4 + 2] = v.z; ea[q * 4 + 3] = v.w;
    }
    int s = ei[e];
    float out[8];
#pragma unroll
    for (int h = 0; h < 8; h++) out[h] = alsrc[s * 8 + h];
#pragma unroll
    for (int k = 0; k < 16; k++)
#pragma unroll
        for (int h = 0; h < 8; h++) out[h] += ea[k] * sAe[k * 8 + h];
    short v8[8];
#pragma unroll
    for (int h = 0; h < 8; h++) v8[h] = f2b(out[h]);
    short* op = aleb + (size_t)pos[e] * 8;
    *(short4*)(op)     = make_short4(v8[0], v8[1], v8[2], v8[3]);
    *(short4*)(op + 4) = make_short4(v8[4], v8[5], v8[6], v8[7]);
}

// ---------------- gather: one wave per dst; shuffle-free; writes bf16 h ----------------
__global__ __launch_bounds__(256) void gather_k(const int* __restrict__ rowptr,
                                                const int* __restrict__ csr_src,
                                                const short* __restrict__ aleb,
                                                const float* __restrict__ aldst,
                                                const short* __restrict__ xsb,
                                                const float* __restrict__ b,
                                                short* __restrict__ houtb, int n) {
    int dst = blockIdx.x * 4 + (threadIdx.x >> 6);
    if (dst >= n) return;
    const int lane = threadIdx.x & 63;
    const int h = lane >> 3;
    const float L2E = 1.44269504f;
    int p0 = rowptr[dst], p1 = rowptr[dst + 1];
    float ald = aldst[dst * 8 + h];
    float den = 0.f, acc0 = 0.f, acc1 = 0.f;
    int p = p0;
    for (; p + 1 < p1; p += 2) {
        int s0 = csr_src[p];
        int s1 = csr_src[p + 1];
        float al0 = b2f_s(aleb[(size_t)p * 8 + h]);
        float al1 = b2f_s(aleb[(size_t)(p + 1) * 8 + h]);
        unsigned v0 = *(const unsigned*)(xsb + (size_t)s0 * 128 + lane * 2);
        unsigned v1 = *(const unsigned*)(xsb + (size_t)s1 * 128 + lane * 2);
        float lg0 = al0 + ald; lg0 = lg0 > 0.f ? lg0 : 0.2f * lg0;
        float lg1 = al1 + ald; lg1 = lg1 > 0.f ? lg1 : 0.2f * lg1;
        float ex0 = exp2f(lg0 * L2E);
        float ex1 = exp2f(lg1 * L2E);
        den  += ex0 + ex1;
        acc0 += b2f_lo(v0) * ex0 + b2f_lo(v1) * ex1;
        acc1 += b2f_hi(v0) * ex0 + b2f_hi(v1) * ex1;
    }
    if (p < p1) {
        int s0 = csr_src[p];
        float al0 = b2f_s(aleb[(size_t)p * 8 + h]);
        unsigned v0 = *(const unsigned*)(xsb + (size_t)s0 * 128 + lane * 2);
        float lg0 = al0 + ald; lg0 = lg0 > 0.f ? lg0 : 0.2f * lg0;
        float ex0 = exp2f(lg0 * L2E);
        den  += ex0;
        acc0 += b2f_lo(v0) * ex0;
        acc1 += b2f_hi(v0) * ex0;
    }
    float inv = 1.f / (den + 1e-16f);
    const float2 bb = *(const float2*)(b + lane * 2);
    unsigned o = pack2(f2b(acc0 * inv + bb.x), f2b(acc1 * inv + bb.y));
    *(unsigned*)(houtb + (size_t)dst * 128 + lane * 2) = o;
}

// ---------------- global add pool (bf16 input, f32 atomics) ----------------
__global__ void pool_k(const short* __restrict__ h3b, const int* __restrict__ batch,
                       float* __restrict__ pool, int n) {
    int t = blockIdx.x * blockDim.x + threadIdx.x;
    if (t >= n * 128) return;
    int node = t >> 7, j = t & 127;
    atomicAdd(pool + (size_t)batch[node] * 128 + j, b2f_s(h3b[t]));
}

// ---------------- Wl1 [512(k),512(c)] f32 -> Wl1T [c][k] bf16 ----------------
__global__ void wl1t_k(const float* __restrict__ Wl1, short* __restrict__ Wl1T) {
    int idx = blockIdx.x * blockDim.x + threadIdx.x;   // 262144
    int k = idx >> 9, c = idx & 511;
    Wl1T[(size_t)c * 512 + k] = f2b(Wl1[idx]);
}

__global__ void init_out(float* __restrict__ out, const float* __restrict__ bl2, int n) {
    int t = blockIdx.x * blockDim.x + threadIdx.x;
    if (t < n) out[t] = bl2[0];
}

// ---------------- fused final MLP via bf16 MFMA: no LDS/barriers, BN=256 ----------------
// grid (782, 2). 4 waves per block, each 64 rows x 64 cols. VGPR capped for 4 waves/SIMD.
__global__ __launch_bounds__(256, 4) void final_mfma(
    const short* __restrict__ h1, const short* __restrict__ h2,
    const short* __restrict__ h3, const short* __restrict__ poolb,
    const int* __restrict__ batch, const short* __restrict__ Wl1T,
    const float* __restrict__ bl1, const float* __restrict__ Wl2,
    float* __restrict__ out, int nrows)
{
    const int tid = threadIdx.x;
    const int n0 = blockIdx.x * 64;
    const int j0 = blockIdx.y * 256;
    const int wid = tid >> 6, lane = tid & 63;
    const int lr = lane & 15, kg = lane >> 4;

    // pool-row (batch) indices for segment 3
    int prow[4];
#pragma unroll
    for (int fm = 0; fm < 4; fm++) {
        int gr = n0 + fm * 16 + lr;
        prow[fm] = (gr < nrows) ? batch[gr] : 0;
    }

    f32x4 acc[4][4] = {};
    const short* seg_base[4] = {h1, h2, h3, poolb};

#pragma unroll
    for (int seg = 0; seg < 4; seg++) {
        const short* base = seg_base[seg];
#pragma unroll
        for (int kk = 0; kk < 4; kk++) {
            const int k0 = seg * 128 + kk * 32;
            const int ck = kk * 32 + kg * 8;
            bf16x8 a[4], b[4];
#pragma unroll
            for (int fm = 0; fm < 4; fm++) {
                int gr = n0 + fm * 16 + lr;
                int row = (seg == 3) ? prow[fm] : gr;
                bf16x8 v = {};
                if (gr < nrows) v = *(const bf16x8*)(base + (size_t)row * 128 + ck);
                a[fm] = v;
            }
#pragma unroll
            for (int fn = 0; fn < 4; fn++)
                b[fn] = *(const bf16x8*)(Wl1T + (size_t)(j0 + wid * 64 + fn * 16 + lr) * 512
                                         + k0 + kg * 8);
#pragma unroll
            for (int fm = 0; fm < 4; fm++)
#pragma unroll
                for (int fn = 0; fn < 4; fn++)
                    acc[fm][fn] = __builtin_amdgcn_mfma_f32_16x16x32_bf16(
                        a[fm], b[fn], acc[fm][fn], 0, 0, 0);
        }
    }

    // epilogue-only constants (loaded after main loop to keep loop VGPR low)
    float w2[4], b1c[4];
#pragma unroll
    for (int fn = 0; fn < 4; fn++) {
        int c = j0 + wid * 64 + fn * 16 + lr;
        w2[fn]  = Wl2[c];
        b1c[fn] = bl1[c];
    }

#pragma unroll
    for (int fm = 0; fm < 4; fm++) {
#pragma unroll
        for (int r = 0; r < 4; r++) {
            float s = 0.f;
#pragma unroll
            for (int fn = 0; fn < 4; fn++) {
                float z = acc[fm][fn][r] + b1c[fn];
                z = z > 0.f ? z : 0.01f * z;
                s += z * w2[fn];
            }
            s += __shfl_xor(s, 1);
            s += __shfl_xor(s, 2);
            s += __shfl_xor(s, 4);
            s += __shfl_xor(s, 8);
            if (lr == 0) {
                int gr = n0 + fm * 16 + kg * 4 + r;
                if (gr < nrows) atomicAdd(out + gr, s);
            }
        }
    }
}

extern "C" void kernel_launch(void* const* d_in, const int* in_sizes, int n_in,
                              void* d_out, int out_size, void* d_ws, size_t ws_size,
                              hipStream_t stream) {
    const float* x     = (const float*)d_in[0];
    const int*   ei    = (const int*)d_in[1];
    const float* eattr = (const float*)d_in[2];
    const int*   batch = (const int*)d_in[3];
    const float* W[3]   = {(const float*)d_in[4],  (const float*)d_in[10], (const float*)d_in[16]};
    const float* We[3]  = {(const float*)d_in[5],  (const float*)d_in[11], (const float*)d_in[17]};
    const float* as_[3] = {(const float*)d_in[6],  (const float*)d_in[12], (const float*)d_in[18]};
    const float* ad_[3] = {(const float*)d_in[7],  (const float*)d_in[13], (const float*)d_in[19]};
    const float* ae_[3] = {(const float*)d_in[8],  (const float*)d_in[14], (const float*)d_in[20]};
    const float* b_[3]  = {(const float*)d_in[9],  (const float*)d_in[15], (const float*)d_in[21]};
    const float* Wl1 = (const float*)d_in[22];
    const float* bl1 = (const float*)d_in[23];
    const float* Wl2 = (const float*)d_in[24];
    const float* bl2 = (const float*)d_in[25];

    const int N = N_NODES, E = N_EDGES, G = N_GRAPH;

    float* ws    = (float*)d_ws;
    float* xs    = ws;                          // N*128 f32
    float* alsrc = xs + (size_t)N * 128;        // N*8
    float* aldst = alsrc + (size_t)N * 8;       // N*8
    float* pool  = aldst + (size_t)N * 8;       // G*128
    float* aeW   = pool + (size_t)G * 128;      // 128
    short* xb    = (short*)(aeW + 128);         // N*128 bf16 (input x)
    short* xsb   = xb + (size_t)N * 128;        // N*128 bf16 (layer GEMM out)
    short* hb0   = xsb + (size_t)N * 128;       // N*128 bf16
    short* hb1   = hb0 + (size_t)N * 128;
    short* hb2   = hb1 + (size_t)N * 128;
    short* hb[3] = {hb0, hb1, hb2};
    short* poolb = hb2 + (size_t)N * 128;       // G*128 bf16
    short* wbt0  = poolb + (size_t)G * 128;     // 3 x 128*128 bf16
    short* wbt1  = wbt0 + 16384;
    short* wbt2  = wbt1 + 16384;
    short* wbt[3] = {wbt0, wbt1, wbt2};
    short* wl1t  = wbt2 + 16384;                // 512*512 bf16
    short* aleb  = wl1t + 262144;               // E*8 bf16
    int*   cnt     = (int*)(aleb + (size_t)E * 8);  // N
    int*   rowptr  = cnt + N;                   // N+1
    int*   cursor  = rowptr + N + 1;            // N
    int*   part    = cursor + N;                // 256
    int*   pos     = part + 256;                // E
    int*   csr_src = pos + E;                   // E

    // ---- once per call: bf16 conversions + dst-CSR ----
    f2b_bulk<<<(N * 32 + 255) / 256, 256, 0, stream>>>(x, xb, N * 32);
    for (int l = 0; l < 3; l++)
        wbt_k<<<64, 256, 0, stream>>>(W[l], wbt[l]);
    wl1t_k<<<1024, 256, 0, stream>>>(Wl1, wl1t);
    hipMemsetAsync(cnt, 0, (size_t)N * sizeof(int), stream);
    hist_k<<<(E + 255) / 256, 256, 0, stream>>>(ei, cnt, E);
    const int nblk = (N + 255) / 256;   // 196
    scan1_k<<<nblk, 256, 0, stream>>>(cnt, rowptr, part, N);
    scan2_k<<<1, 256, 0, stream>>>(part, nblk);
    scan3_k<<<nblk, 256, 0, stream>>>(rowptr, part, cursor, N, E);
    scatter_k<<<(E + 255) / 256, 256, 0, stream>>>(ei, cursor, pos, csr_src, E);

    for (int l = 0; l < 3; l++) {
        const short* Ain = (l == 0) ? xb : hb[l - 1];
        gemm_mfma<<<(N + 63) / 64, 256, 0, stream>>>(Ain, wbt[l], xs, xsb, N);
        node_al<<<(N * 8 + 255) / 256, 256, 0, stream>>>(xs, as_[l], ad_[l], alsrc, aldst, N);
        aew_k<<<1, 128, 0, stream>>>(We[l], ae_[l], aeW);
        ale_k<<<(E + 255) / 256, 256, 0, stream>>>(ei, eattr, alsrc, aeW, pos, aleb, E);
        gather_k<<<(N + 3) / 4, 256, 0, stream>>>(rowptr, csr_src, aleb, aldst, xsb,
                                                  b_[l], hb[l], N);
    }
    hipMemsetAsync(pool, 0, (size_t)G * 128 * sizeof(float), stream);
    pool_k<<<(N * 128 + 255) / 256, 256, 0, stream>>>(hb[2], batch, pool, N);
    f2b_bulk<<<(G * 32 + 255) / 256, 256, 0, stream>>>(pool, poolb, G * 32);

    init_out<<<(N + 255) / 256, 256, 0, stream>>>((float*)d_out, bl2, N);
    dim3 fg((N + 63) / 64, 2);
    final_mfma<<<fg, 256, 0, stream>>>(hb[0], hb[1], hb[2], poolb, batch,
                                       wl1t, bl1, Wl2, (float*)d_out, N);
}

// Round 9
// 554.467 us; speedup vs baseline: 1.0849x; 1.0849x over previous
//
#include <hip/hip_runtime.h>

#define N_NODES 50000
#define N_EDGES 800000
#define N_GRAPH 1000

typedef short bf16x8 __attribute__((ext_vector_type(8)));
typedef float f32x4 __attribute__((ext_vector_type(4)));

__device__ inline short f2b(float f) {   // f32 -> bf16 (RNE)
    union { float f; unsigned u; } x; x.f = f;
    unsigned r = x.u + 0x7FFF + ((x.u >> 16) & 1);
    return (short)(r >> 16);
}
__device__ inline float b2f_lo(unsigned v) {
    union { unsigned u; float f; } x; x.u = v << 16; return x.f;
}
__device__ inline float b2f_hi(unsigned v) {
    union { unsigned u; float f; } x; x.u = v & 0xFFFF0000u; return x.f;
}
__device__ inline float b2f_s(short s) {
    union { unsigned u; float f; } x; x.u = ((unsigned)(unsigned short)s) << 16; return x.f;
}
__device__ inline unsigned pack2(short lo, short hi) {
    return ((unsigned)(unsigned short)lo) | (((unsigned)(unsigned short)hi) << 16);
}

// ---------------- f32 -> bf16 bulk convert (vectorized) ----------------
__global__ void f2b_bulk(const float* __restrict__ in, short* __restrict__ out, int n4) {
    int t = blockIdx.x * blockDim.x + threadIdx.x;
    if (t >= n4) return;
    float4 v = *(const float4*)(in + (size_t)t * 4);
    *(short4*)(out + (size_t)t * 4) = make_short4(f2b(v.x), f2b(v.y), f2b(v.z), f2b(v.w));
}

// ---------------- W[128(k)][128(c)] f32 -> WbT[c][k] bf16 ----------------
__global__ void wbt_k(const float* __restrict__ W, short* __restrict__ WbT) {
    int idx = blockIdx.x * blockDim.x + threadIdx.x;   // 16384
    int k = idx >> 7, c = idx & 127;
    WbT[(size_t)c * 128 + k] = f2b(W[idx]);
}

// ---------------- layer GEMM via MFMA: no LDS, no barriers ----------------
// BM=64, BN=128. 4 waves: wave = 32 rows x 64 cols. Frags direct from global.
__global__ __launch_bounds__(256) void gemm_mfma(const short* __restrict__ Ab,
                                                 const short* __restrict__ WbT,
                                                 float* __restrict__ out,
                                                 short* __restrict__ outb, int nrows) {
    const int tid = threadIdx.x;
    const int n0 = blockIdx.x * 64;
    const int wid = tid >> 6, lane = tid & 63;
    const int lr = lane & 15, kg = lane >> 4;
    const int wr = (wid >> 1) * 32;    // wave row offset (0/32)
    const int wc = (wid & 1) * 64;     // wave col offset (0/64)

    f32x4 acc[2][4] = {};

#pragma unroll
    for (int ks = 0; ks < 4; ks++) {
        const int k0 = ks * 32;
        bf16x8 a[2], b[4];
#pragma unroll
        for (int fm = 0; fm < 2; fm++) {
            int gr = n0 + wr + fm * 16 + lr;
            bf16x8 v = {};
            if (gr < nrows) v = *(const bf16x8*)(Ab + (size_t)gr * 128 + k0 + kg * 8);
            a[fm] = v;
        }
#pragma unroll
        for (int fn = 0; fn < 4; fn++)
            b[fn] = *(const bf16x8*)(WbT + (size_t)(wc + fn * 16 + lr) * 128 + k0 + kg * 8);
#pragma unroll
        for (int fm = 0; fm < 2; fm++)
#pragma unroll
            for (int fn = 0; fn < 4; fn++)
                acc[fm][fn] = __builtin_amdgcn_mfma_f32_16x16x32_bf16(
                    a[fm], b[fn], acc[fm][fn], 0, 0, 0);
    }
#pragma unroll
    for (int fm = 0; fm < 2; fm++) {
#pragma unroll
        for (int r = 0; r < 4; r++) {
            int gr = n0 + wr + fm * 16 + kg * 4 + r;
            if (gr < nrows) {
#pragma unroll
                for (int fn = 0; fn < 4; fn++) {
                    int col = wc + fn * 16 + lr;
                    float z = acc[fm][fn][r];
                    out[(size_t)gr * 128 + col] = z;
                    outb[(size_t)gr * 128 + col] = f2b(z);
                }
            }
        }
    }
}

// ---------------- per-node attention coefficients ----------------
__global__ void node_al(const float* __restrict__ xs, const float* __restrict__ a_s,
                        const float* __restrict__ a_d, float* __restrict__ alsrc,
                        float* __restrict__ aldst, int n) {
    int t = blockIdx.x * blockDim.x + threadIdx.x;
    if (t >= n * 8) return;
    int node = t >> 3, h = t & 7;
    const float4* xp = (const float4*)(xs + (size_t)node * 128 + h * 16);
    const float4* sp = (const float4*)(a_s + h * 16);
    const float4* dp = (const float4*)(a_d + h * 16);
    float ss = 0.f, dd = 0.f;
#pragma unroll
    for (int q = 0; q < 4; q++) {
        float4 x4 = xp[q], s4 = sp[q], d4 = dp[q];
        ss += x4.x * s4.x + x4.y * s4.y + x4.z * s4.z + x4.w * s4.w;
        dd += x4.x * d4.x + x4.y * d4.y + x4.z * d4.z + x4.w * d4.w;
    }
    alsrc[t] = ss;
    aldst[t] = dd;
}

// ---------------- aeW[k][h] = sum_c We[k, h*16+c] * ae[h,c] ----------------
__global__ void aew_k(const float* __restrict__ We, const float* __restrict__ ae,
                      float* __restrict__ aeW) {
    int t = threadIdx.x;   // 128 threads
    int k = t >> 3, h = t & 7;
    float s = 0.f;
#pragma unroll
    for (int c = 0; c < 16; c++) s += We[k * 128 + h * 16 + c] * ae[h * 16 + c];
    aeW[k * 8 + h] = s;
}

// ---------------- CSR build ----------------
__global__ void hist_k(const int* __restrict__ ei, int* __restrict__ cnt, int ne) {
    int e = blockIdx.x * blockDim.x + threadIdx.x;
    if (e < ne) atomicAdd(&cnt[ei[ne + e]], 1);
}

__global__ void scan1_k(const int* __restrict__ cnt, int* __restrict__ rowptr,
                        int* __restrict__ part, int n) {
    __shared__ int s[256];
    int tid = threadIdx.x;
    int i = blockIdx.x * 256 + tid;
    int v = (i < n) ? cnt[i] : 0;
    s[tid] = v; __syncthreads();
#pragma unroll
    for (int off = 1; off < 256; off <<= 1) {
        int t = (tid >= off) ? s[tid - off] : 0;
        __syncthreads();
        s[tid] += t;
        __syncthreads();
    }
    if (i < n) rowptr[i] = s[tid] - v;
    if (tid == 255) part[blockIdx.x] = s[255];
}

__global__ void scan2_k(int* __restrict__ part, int npart) {
    __shared__ int s[256];
    int tid = threadIdx.x;
    int v = (tid < npart) ? part[tid] : 0;
    s[tid] = v; __syncthreads();
#pragma unroll
    for (int off = 1; off < 256; off <<= 1) {
        int t = (tid >= off) ? s[tid - off] : 0;
        __syncthreads();
        s[tid] += t;
        __syncthreads();
    }
    if (tid < npart) part[tid] = s[tid] - v;
}

__global__ void scan3_k(int* __restrict__ rowptr, const int* __restrict__ part,
                        int* __restrict__ cursor, int n, int ne) {
    int i = blockIdx.x * 256 + threadIdx.x;
    if (i < n) {
        int r = rowptr[i] + part[blockIdx.x];
        rowptr[i] = r;
        cursor[i] = r;
    }
    if (i == 0) rowptr[n] = ne;
}

__global__ void scatter_k(const int* __restrict__ ei, int* __restrict__ cursor,
                          int* __restrict__ pos, int* __restrict__ csr_src, int ne) {
    int e = blockIdx.x * blockDim.x + threadIdx.x;
    if (e >= ne) return;
    int d = ei[ne + e];
    int p = atomicAdd(&cursor[d], 1);
    pos[e] = p;
    csr_src[p] = ei[e];
}

// ---------------- per-edge logits (alsrc + al_e), bf16, CSR order ----------------
__global__ __launch_bounds__(256) void ale_k(const int* __restrict__ ei,
                                             const float* __restrict__ eattr,
                                             const float* __restrict__ alsrc,
                                             const float* __restrict__ aeW,
                                             const int* __restrict__ pos,
                                             short* __restrict__ aleb, int ne) {
    __shared__ float sAe[128];
    if (threadIdx.x < 128) sAe[threadIdx.x] = aeW[threadIdx.x];
    __syncthreads();
    int e = blockIdx.x * blockDim.x + threadIdx.x;
    if (e >= ne) return;
    float ea[16];
    const float4* ep = (const float4*)(eattr + (size_t)e * 16);
#pragma unroll
    for (int q = 0; q < 4; q++) {
        float4 v = ep[q];
        ea[q * 4 + 0] = v.x; ea[q * 4 + 1] = v.y; ea[q * 4 + 2] = v.z; ea[q * 4 + 3] = v.w;
    }
    int s = ei[e];
    float out[8];
#pragma unroll
    for (int h = 0; h < 8; h++) out[h] = alsrc[s * 8 + h];
#pragma unroll
    for (int k = 0; k < 16; k++)
#pragma unroll
        for (int h = 0; h < 8; h++) out[h] += ea[k] * sAe[k * 8 + h];
    short v8[8];
#pragma unroll
    for (int h = 0; h < 8; h++) v8[h] = f2b(out[h]);
    short* op = aleb + (size_t)pos[e] * 8;
    *(short4*)(op)     = make_short4(v8[0], v8[1], v8[2], v8[3]);
    *(short4*)(op + 4) = make_short4(v8[4], v8[5], v8[6], v8[7]);
}

// ---------------- gather: one wave per dst; shuffle-free; writes bf16 h ----------------
__global__ __launch_bounds__(256) void gather_k(const int* __restrict__ rowptr,
                                                const int* __restrict__ csr_src,
                                                const short* __restrict__ aleb,
                                                const float* __restrict__ aldst,
                                                const short* __restrict__ xsb,
                                                const float* __restrict__ b,
                                                short* __restrict__ houtb, int n) {
    int dst = blockIdx.x * 4 + (threadIdx.x >> 6);
    if (dst >= n) return;
    const int lane = threadIdx.x & 63;
    const int h = lane >> 3;
    const float L2E = 1.44269504f;
    int p0 = rowptr[dst], p1 = rowptr[dst + 1];
    float ald = aldst[dst * 8 + h];
    float den = 0.f, acc0 = 0.f, acc1 = 0.f;
    int p = p0;
    for (; p + 1 < p1; p += 2) {
        int s0 = csr_src[p];
        int s1 = csr_src[p + 1];
        float al0 = b2f_s(aleb[(size_t)p * 8 + h]);
        float al1 = b2f_s(aleb[(size_t)(p + 1) * 8 + h]);
        unsigned v0 = *(const unsigned*)(xsb + (size_t)s0 * 128 + lane * 2);
        unsigned v1 = *(const unsigned*)(xsb + (size_t)s1 * 128 + lane * 2);
        float lg0 = al0 + ald; lg0 = lg0 > 0.f ? lg0 : 0.2f * lg0;
        float lg1 = al1 + ald; lg1 = lg1 > 0.f ? lg1 : 0.2f * lg1;
        float ex0 = exp2f(lg0 * L2E);
        float ex1 = exp2f(lg1 * L2E);
        den  += ex0 + ex1;
        acc0 += b2f_lo(v0) * ex0 + b2f_lo(v1) * ex1;
        acc1 += b2f_hi(v0) * ex0 + b2f_hi(v1) * ex1;
    }
    if (p < p1) {
        int s0 = csr_src[p];
        float al0 = b2f_s(aleb[(size_t)p * 8 + h]);
        unsigned v0 = *(const unsigned*)(xsb + (size_t)s0 * 128 + lane * 2);
        float lg0 = al0 + ald; lg0 = lg0 > 0.f ? lg0 : 0.2f * lg0;
        float ex0 = exp2f(lg0 * L2E);
        den  += ex0;
        acc0 += b2f_lo(v0) * ex0;
        acc1 += b2f_hi(v0) * ex0;
    }
    float inv = 1.f / (den + 1e-16f);
    const float2 bb = *(const float2*)(b + lane * 2);
    unsigned o = pack2(f2b(acc0 * inv + bb.x), f2b(acc1 * inv + bb.y));
    *(unsigned*)(houtb + (size_t)dst * 128 + lane * 2) = o;
}

// ---------------- global add pool (bf16 input, f32 atomics) ----------------
__global__ void pool_k(const short* __restrict__ h3b, const int* __restrict__ batch,
                       float* __restrict__ pool, int n) {
    int t = blockIdx.x * blockDim.x + threadIdx.x;
    if (t >= n * 128) return;
    int node = t >> 7, j = t & 127;
    atomicAdd(pool + (size_t)batch[node] * 128 + j, b2f_s(h3b[t]));
}

// ---------------- Wl1 [512(k),512(c)] f32 -> Wl1T [c][k] bf16 ----------------
__global__ void wl1t_k(const float* __restrict__ Wl1, short* __restrict__ Wl1T) {
    int idx = blockIdx.x * blockDim.x + threadIdx.x;   // 262144
    int k = idx >> 9, c = idx & 511;
    Wl1T[(size_t)c * 512 + k] = f2b(Wl1[idx]);
}

__global__ void init_out(float* __restrict__ out, const float* __restrict__ bl2, int n) {
    int t = blockIdx.x * blockDim.x + threadIdx.x;
    if (t < n) out[t] = bl2[0];
}

// ---------------- fused final MLP via bf16 MFMA ----------------
// Stage whole A panel (64 rows x 512 k bf16 = 64 KB) ONCE; then zero barriers.
// BM=64, BN=256 (grid.y=2). 4 waves, each 64 rows x 64 cols. B-frags from L2.
// LDS layout: Abuf[ks][row ^ (ks&7)][8]  (ks = k/8) -- XOR keeps writes/reads at
// the 8-phase bank floor (write side: ks-consecutive lanes stride 1024 B).
__global__ __launch_bounds__(256) void final_mfma(
    const short* __restrict__ h1, const short* __restrict__ h2,
    const short* __restrict__ h3, const short* __restrict__ poolb,
    const int* __restrict__ batch, const short* __restrict__ Wl1T,
    const float* __restrict__ bl1, const float* __restrict__ Wl2,
    float* __restrict__ out, int nrows)
{
    __shared__ short Abuf[64 * 64 * 8];   // 64 KB
    const int tid = threadIdx.x;
    const int n0 = blockIdx.x * 64;
    const int j0 = blockIdx.y * 256;
    const int wid = tid >> 6, lane = tid & 63;
    const int lr = lane & 15, kg = lane >> 4;

    // ---- stage A once: thread owns ks = tid&63 (fixed seg), rows i*4 + tid>>6 ----
    {
        const int sks = tid & 63;
        const int srb = tid >> 6;
        const int seg = sks >> 4;
        const short* base = (seg == 0) ? h1 : (seg == 1) ? h2 : (seg == 2) ? h3 : poolb;
        const bool isPool = (seg == 3);
        const int kin = (sks & 15) * 8;
        const int swz = (sks * 64) * 8;
        const int sx = (sks & 7);
#pragma unroll
        for (int i = 0; i < 16; i++) {
            int row = i * 4 + srb;
            int gr = n0 + row;
            uint4 v = make_uint4(0, 0, 0, 0);
            if (gr < nrows) {
                int grow = isPool ? batch[gr] : gr;
                v = *(const uint4*)(base + (size_t)grow * 128 + kin);
            }
            *(uint4*)(&Abuf[swz + ((row ^ sx) * 8)]) = v;
        }
    }
    __syncthreads();   // the ONLY barrier

    f32x4 acc[4][4] = {};
#pragma unroll
    for (int kstep = 0; kstep < 16; kstep++) {
        const int ks = kstep * 4 + kg;
        const int kx = ks & 7;
        bf16x8 a[4], b[4];
#pragma unroll
        for (int fm = 0; fm < 4; fm++)
            a[fm] = *(const bf16x8*)(&Abuf[(ks * 64 + ((fm * 16 + lr) ^ kx)) * 8]);
#pragma unroll
        for (int fn = 0; fn < 4; fn++)
            b[fn] = *(const bf16x8*)(Wl1T + (size_t)(j0 + wid * 64 + fn * 16 + lr) * 512
                                     + kstep * 32 + kg * 8);
#pragma unroll
        for (int fm = 0; fm < 4; fm++)
#pragma unroll
            for (int fn = 0; fn < 4; fn++)
                acc[fm][fn] = __builtin_amdgcn_mfma_f32_16x16x32_bf16(
                    a[fm], b[fn], acc[fm][fn], 0, 0, 0);
    }

    // epilogue-only constants (after the loop to keep loop VGPR low)
    float w2[4], b1c[4];
#pragma unroll
    for (int fn = 0; fn < 4; fn++) {
        int c = j0 + wid * 64 + fn * 16 + lr;
        w2[fn]  = Wl2[c];
        b1c[fn] = bl1[c];
    }

#pragma unroll
    for (int fm = 0; fm < 4; fm++) {
#pragma unroll
        for (int r = 0; r < 4; r++) {
            float s = 0.f;
#pragma unroll
            for (int fn = 0; fn < 4; fn++) {
                float z = acc[fm][fn][r] + b1c[fn];
                z = z > 0.f ? z : 0.01f * z;
                s += z * w2[fn];
            }
            s += __shfl_xor(s, 1);
            s += __shfl_xor(s, 2);
            s += __shfl_xor(s, 4);
            s += __shfl_xor(s, 8);
            if (lr == 0) {
                int gr = n0 + fm * 16 + kg * 4 + r;
                if (gr < nrows) atomicAdd(out + gr, s);
            }
        }
    }
}

extern "C" void kernel_launch(void* const* d_in, const int* in_sizes, int n_in,
                              void* d_out, int out_size, void* d_ws, size_t ws_size,
                              hipStream_t stream) {
    const float* x     = (const float*)d_in[0];
    const int*   ei    = (const int*)d_in[1];
    const float* eattr = (const float*)d_in[2];
    const int*   batch = (const int*)d_in[3];
    const float* W[3]   = {(const float*)d_in[4],  (const float*)d_in[10], (const float*)d_in[16]};
    const float* We[3]  = {(const float*)d_in[5],  (const float*)d_in[11], (const float*)d_in[17]};
    const float* as_[3] = {(const float*)d_in[6],  (const float*)d_in[12], (const float*)d_in[18]};
    const float* ad_[3] = {(const float*)d_in[7],  (const float*)d_in[13], (const float*)d_in[19]};
    const float* ae_[3] = {(const float*)d_in[8],  (const float*)d_in[14], (const float*)d_in[20]};
    const float* b_[3]  = {(const float*)d_in[9],  (const float*)d_in[15], (const float*)d_in[21]};
    const float* Wl1 = (const float*)d_in[22];
    const float* bl1 = (const float*)d_in[23];
    const float* Wl2 = (const float*)d_in[24];
    const float* bl2 = (const float*)d_in[25];

    const int N = N_NODES, E = N_EDGES, G = N_GRAPH;

    float* ws    = (float*)d_ws;
    float* xs    = ws;                          // N*128 f32
    float* alsrc = xs + (size_t)N * 128;        // N*8
    float* aldst = alsrc + (size_t)N * 8;       // N*8
    float* pool  = aldst + (size_t)N * 8;       // G*128
    float* aeW   = pool + (size_t)G * 128;      // 128
    short* xb    = (short*)(aeW + 128);         // N*128 bf16 (input x)
    short* xsb   = xb + (size_t)N * 128;        // N*128 bf16 (layer GEMM out)
    short* hb0   = xsb + (size_t)N * 128;       // N*128 bf16
    short* hb1   = hb0 + (size_t)N * 128;
    short* hb2   = hb1 + (size_t)N * 128;
    short* hb[3] = {hb0, hb1, hb2};
    short* poolb = hb2 + (size_t)N * 128;       // G*128 bf16
    short* wbt0  = poolb + (size_t)G * 128;     // 3 x 128*128 bf16
    short* wbt1  = wbt0 + 16384;
    short* wbt2  = wbt1 + 16384;
    short* wbt[3] = {wbt0, wbt1, wbt2};
    short* wl1t  = wbt2 + 16384;                // 512*512 bf16
    short* aleb  = wl1t + 262144;               // E*8 bf16
    int*   cnt     = (int*)(aleb + (size_t)E * 8);  // N
    int*   rowptr  = cnt + N;                   // N+1
    int*   cursor  = rowptr + N + 1;            // N
    int*   part    = cursor + N;                // 256
    int*   pos     = part + 256;                // E
    int*   csr_src = pos + E;                   // E

    // ---- once per call: bf16 conversions + dst-CSR ----
    f2b_bulk<<<(N * 32 + 255) / 256, 256, 0, stream>>>(x, xb, N * 32);
    for (int l = 0; l < 3; l++)
        wbt_k<<<64, 256, 0, stream>>>(W[l], wbt[l]);
    wl1t_k<<<1024, 256, 0, stream>>>(Wl1, wl1t);
    hipMemsetAsync(cnt, 0, (size_t)N * sizeof(int), stream);
    hist_k<<<(E + 255) / 256, 256, 0, stream>>>(ei, cnt, E);
    const int nblk = (N + 255) / 256;   // 196
    scan1_k<<<nblk, 256, 0, stream>>>(cnt, rowptr, part, N);
    scan2_k<<<1, 256, 0, stream>>>(part, nblk);
    scan3_k<<<nblk, 256, 0, stream>>>(rowptr, part, cursor, N, E);
    scatter_k<<<(E + 255) / 256, 256, 0, stream>>>(ei, cursor, pos, csr_src, E);

    for (int l = 0; l < 3; l++) {
        const short* Ain = (l == 0) ? xb : hb[l - 1];
        gemm_mfma<<<(N + 63) / 64, 256, 0, stream>>>(Ain, wbt[l], xs, xsb, N);
        node_al<<<(N * 8 + 255) / 256, 256, 0, stream>>>(xs, as_[l], ad_[l], alsrc, aldst, N);
        aew_k<<<1, 128, 0, stream>>>(We[l], ae_[l], aeW);
        ale_k<<<(E + 255) / 256, 256, 0, stream>>>(ei, eattr, alsrc, aeW, pos, aleb, E);
        gather_k<<<(N + 3) / 4, 256, 0, stream>>>(rowptr, csr_src, aleb, aldst, xsb,
                                                  b_[l], hb[l], N);
    }
    hipMemsetAsync(pool, 0, (size_t)G * 128 * sizeof(float), stream);
    pool_k<<<(N * 128 + 255) / 256, 256, 0, stream>>>(hb[2], batch, pool, N);
    f2b_bulk<<<(G * 32 + 255) / 256, 256, 0, stream>>>(pool, poolb, G * 32);

    init_out<<<(N + 255) / 256, 256, 0, stream>>>((float*)d_out, bl2, N);
    dim3 fg((N + 63) / 64, 2);
    final_mfma<<<fg, 256, 0, stream>>>(hb[0], hb[1], hb[2], poolb, batch,
                                       wl1t, bl1, Wl2, (float*)d_out, N);
}

// Round 10
// 493.207 us; speedup vs baseline: 1.2196x; 1.1242x over previous
//
#include <hip/hip_runtime.h>

#define N_NODES 50000
#define N_EDGES 800000
#define N_GRAPH 1000

typedef short bf16x8 __attribute__((ext_vector_type(8)));
typedef float f32x4 __attribute__((ext_vector_type(4)));

__device__ inline short f2b(float f) {   // f32 -> bf16 (RNE)
    union { float f; unsigned u; } x; x.f = f;
    unsigned r = x.u + 0x7FFF + ((x.u >> 16) & 1);
    return (short)(r >> 16);
}
__device__ inline float b2f_lo(unsigned v) {
    union { unsigned u; float f; } x; x.u = v << 16; return x.f;
}
__device__ inline float b2f_hi(unsigned v) {
    union { unsigned u; float f; } x; x.u = v & 0xFFFF0000u; return x.f;
}
__device__ inline float b2f_s(short s) {
    union { unsigned u; float f; } x; x.u = ((unsigned)(unsigned short)s) << 16; return x.f;
}
__device__ inline unsigned pack2(short lo, short hi) {
    return ((unsigned)(unsigned short)lo) | (((unsigned)(unsigned short)hi) << 16);
}

// ---------------- f32 -> bf16 bulk convert (vectorized) ----------------
__global__ void f2b_bulk(const float* __restrict__ in, short* __restrict__ out, int n4) {
    int t = blockIdx.x * blockDim.x + threadIdx.x;
    if (t >= n4) return;
    float4 v = *(const float4*)(in + (size_t)t * 4);
    *(short4*)(out + (size_t)t * 4) = make_short4(f2b(v.x), f2b(v.y), f2b(v.z), f2b(v.w));
}

// ---------------- W[128(k)][128(c)] f32 -> WbT[c][k] bf16 ----------------
__global__ void wbt_k(const float* __restrict__ W, short* __restrict__ WbT) {
    int idx = blockIdx.x * blockDim.x + threadIdx.x;   // 16384
    int k = idx >> 7, c = idx & 127;
    WbT[(size_t)c * 128 + k] = f2b(W[idx]);
}

// ---------------- layer GEMM via MFMA: no LDS, no barriers ----------------
__global__ __launch_bounds__(256) void gemm_mfma(const short* __restrict__ Ab,
                                                 const short* __restrict__ WbT,
                                                 float* __restrict__ out,
                                                 short* __restrict__ outb, int nrows) {
    const int tid = threadIdx.x;
    const int n0 = blockIdx.x * 64;
    const int wid = tid >> 6, lane = tid & 63;
    const int lr = lane & 15, kg = lane >> 4;
    const int wr = (wid >> 1) * 32;    // wave row offset (0/32)
    const int wc = (wid & 1) * 64;     // wave col offset (0/64)

    f32x4 acc[2][4] = {};

#pragma unroll
    for (int ks = 0; ks < 4; ks++) {
        const int k0 = ks * 32;
        bf16x8 a[2], b[4];
#pragma unroll
        for (int fm = 0; fm < 2; fm++) {
            int gr = n0 + wr + fm * 16 + lr;
            bf16x8 v = {};
            if (gr < nrows) v = *(const bf16x8*)(Ab + (size_t)gr * 128 + k0 + kg * 8);
            a[fm] = v;
        }
#pragma unroll
        for (int fn = 0; fn < 4; fn++)
            b[fn] = *(const bf16x8*)(WbT + (size_t)(wc + fn * 16 + lr) * 128 + k0 + kg * 8);
#pragma unroll
        for (int fm = 0; fm < 2; fm++)
#pragma unroll
            for (int fn = 0; fn < 4; fn++)
                acc[fm][fn] = __builtin_amdgcn_mfma_f32_16x16x32_bf16(
                    a[fm], b[fn], acc[fm][fn], 0, 0, 0);
    }
#pragma unroll
    for (int fm = 0; fm < 2; fm++) {
#pragma unroll
        for (int r = 0; r < 4; r++) {
            int gr = n0 + wr + fm * 16 + kg * 4 + r;
            if (gr < nrows) {
#pragma unroll
                for (int fn = 0; fn < 4; fn++) {
                    int col = wc + fn * 16 + lr;
                    float z = acc[fm][fn][r];
                    out[(size_t)gr * 128 + col] = z;
                    outb[(size_t)gr * 128 + col] = f2b(z);
                }
            }
        }
    }
}

// ---------------- per-node attention coefficients ----------------
__global__ void node_al(const float* __restrict__ xs, const float* __restrict__ a_s,
                        const float* __restrict__ a_d, float* __restrict__ alsrc,
                        float* __restrict__ aldst, int n) {
    int t = blockIdx.x * blockDim.x + threadIdx.x;
    if (t >= n * 8) return;
    int node = t >> 3, h = t & 7;
    const float4* xp = (const float4*)(xs + (size_t)node * 128 + h * 16);
    const float4* sp = (const float4*)(a_s + h * 16);
    const float4* dp = (const float4*)(a_d + h * 16);
    float ss = 0.f, dd = 0.f;
#pragma unroll
    for (int q = 0; q < 4; q++) {
        float4 x4 = xp[q], s4 = sp[q], d4 = dp[q];
        ss += x4.x * s4.x + x4.y * s4.y + x4.z * s4.z + x4.w * s4.w;
        dd += x4.x * d4.x + x4.y * d4.y + x4.z * d4.z + x4.w * d4.w;
    }
    alsrc[t] = ss;
    aldst[t] = dd;
}

// ---------------- aeW[k][h] = sum_c We[k, h*16+c] * ae[h,c] ----------------
__global__ void aew_k(const float* __restrict__ We, const float* __restrict__ ae,
                      float* __restrict__ aeW) {
    int t = threadIdx.x;   // 128 threads
    int k = t >> 3, h = t & 7;
    float s = 0.f;
#pragma unroll
    for (int c = 0; c < 16; c++) s += We[k * 128 + h * 16 + c] * ae[h * 16 + c];
    aeW[k * 8 + h] = s;
}

// ---------------- CSR build ----------------
__global__ void hist_k(const int* __restrict__ ei, int* __restrict__ cnt, int ne) {
    int e = blockIdx.x * blockDim.x + threadIdx.x;
    if (e < ne) atomicAdd(&cnt[ei[ne + e]], 1);
}

__global__ void scan1_k(const int* __restrict__ cnt, int* __restrict__ rowptr,
                        int* __restrict__ part, int n) {
    __shared__ int s[256];
    int tid = threadIdx.x;
    int i = blockIdx.x * 256 + tid;
    int v = (i < n) ? cnt[i] : 0;
    s[tid] = v; __syncthreads();
#pragma unroll
    for (int off = 1; off < 256; off <<= 1) {
        int t = (tid >= off) ? s[tid - off] : 0;
        __syncthreads();
        s[tid] += t;
        __syncthreads();
    }
    if (i < n) rowptr[i] = s[tid] - v;
    if (tid == 255) part[blockIdx.x] = s[255];
}

__global__ void scan2_k(int* __restrict__ part, int npart) {
    __shared__ int s[256];
    int tid = threadIdx.x;
    int v = (tid < npart) ? part[tid] : 0;
    s[tid] = v; __syncthreads();
#pragma unroll
    for (int off = 1; off < 256; off <<= 1) {
        int t = (tid >= off) ? s[tid - off] : 0;
        __syncthreads();
        s[tid] += t;
        __syncthreads();
    }
    if (tid < npart) part[tid] = s[tid] - v;
}

__global__ void scan3_k(int* __restrict__ rowptr, const int* __restrict__ part,
                        int* __restrict__ cursor, int n, int ne) {
    int i = blockIdx.x * 256 + threadIdx.x;
    if (i < n) {
        int r = rowptr[i] + part[blockIdx.x];
        rowptr[i] = r;
        cursor[i] = r;
    }
    if (i == 0) rowptr[n] = ne;
}

__global__ void scatter_k(const int* __restrict__ ei, int* __restrict__ cursor,
                          int* __restrict__ pos, int* __restrict__ csr_src, int ne) {
    int e = blockIdx.x * blockDim.x + threadIdx.x;
    if (e >= ne) return;
    int d = ei[ne + e];
    int p = atomicAdd(&cursor[d], 1);
    pos[e] = p;
    csr_src[p] = ei[e];
}

// ---------------- per-edge logits (alsrc + al_e), bf16, CSR order ----------------
__global__ __launch_bounds__(256) void ale_k(const int* __restrict__ ei,
                                             const float* __restrict__ eattr,
                                             const float* __restrict__ alsrc,
                                             const float* __restrict__ aeW,
                                             const int* __restrict__ pos,
                                             short* __restrict__ aleb, int ne) {
    __shared__ float sAe[128];
    if (threadIdx.x < 128) sAe[threadIdx.x] = aeW[threadIdx.x];
    __syncthreads();
    int e = blockIdx.x * blockDim.x + threadIdx.x;
    if (e >= ne) return;
    float ea[16];
    const float4* ep = (const float4*)(eattr + (size_t)e * 16);
#pragma unroll
    for (int q = 0; q < 4; q++) {
        float4 v = ep[q];
        ea[q * 4 + 0] = v.x; ea[q * 4 + 1] = v.y; ea[q * 4 + 2] = v.z; ea[q * 4 + 3] = v.w;
    }
    int s = ei[e];
    float out[8];
#pragma unroll
    for (int h = 0; h < 8; h++) out[h] = alsrc[s * 8 + h];
#pragma unroll
    for (int k = 0; k < 16; k++)
#pragma unroll
        for (int h = 0; h < 8; h++) out[h] += ea[k] * sAe[k * 8 + h];
    short v8[8];
#pragma unroll
    for (int h = 0; h < 8; h++) v8[h] = f2b(out[h]);
    short* op = aleb + (size_t)pos[e] * 8;
    *(short4*)(op)     = make_short4(v8[0], v8[1], v8[2], v8[3]);
    *(short4*)(op + 4) = make_short4(v8[4], v8[5], v8[6], v8[7]);
}

// ---------------- gather: one wave per dst; breadth-first 8-edge chunks ----------------
// lane owns channels 2*lane, 2*lane+1 (head h = lane>>3); every lane tracks its head's denom
__global__ __launch_bounds__(256) void gather_k(const int* __restrict__ rowptr,
                                                const int* __restrict__ csr_src,
                                                const short* __restrict__ aleb,
                                                const float* __restrict__ aldst,
                                                const short* __restrict__ xsb,
                                                const float* __restrict__ b,
                                                short* __restrict__ houtb, int n) {
    int dst = blockIdx.x * 4 + (threadIdx.x >> 6);
    if (dst >= n) return;
    const int lane = threadIdx.x & 63;
    const int h = lane >> 3;
    const float L2E = 1.44269504f;
    int p0 = rowptr[dst], p1 = rowptr[dst + 1];
    float ald = aldst[dst * 8 + h];
    float den = 0.f, acc0 = 0.f, acc1 = 0.f;
    int p = p0;
    // ---- chunks of 8 edges: coalesced index/logit loads, 8 independent row loads ----
    for (; p + 8 <= p1; p += 8) {
        int   sv  = csr_src[p + (lane & 7)];                 // lanes 0-7: the 8 srcs
        float alv = b2f_s(aleb[(size_t)p * 8 + lane]);       // 8 edges x 8 heads
        int s0 = __shfl(sv, 0), s1 = __shfl(sv, 1), s2 = __shfl(sv, 2), s3 = __shfl(sv, 3);
        int s4 = __shfl(sv, 4), s5 = __shfl(sv, 5), s6 = __shfl(sv, 6), s7 = __shfl(sv, 7);
        unsigned v0 = *(const unsigned*)(xsb + (size_t)s0 * 128 + lane * 2);
        unsigned v1 = *(const unsigned*)(xsb + (size_t)s1 * 128 + lane * 2);
        unsigned v2 = *(const unsigned*)(xsb + (size_t)s2 * 128 + lane * 2);
        unsigned v3 = *(const unsigned*)(xsb + (size_t)s3 * 128 + lane * 2);
        unsigned v4 = *(const unsigned*)(xsb + (size_t)s4 * 128 + lane * 2);
        unsigned v5 = *(const unsigned*)(xsb + (size_t)s5 * 128 + lane * 2);
        unsigned v6 = *(const unsigned*)(xsb + (size_t)s6 * 128 + lane * 2);
        unsigned v7 = *(const unsigned*)(xsb + (size_t)s7 * 128 + lane * 2);
        unsigned vv[8] = {v0, v1, v2, v3, v4, v5, v6, v7};
#pragma unroll
        for (int i = 0; i < 8; i++) {
            float al = __shfl(alv, i * 8 + h);
            float lg = al + ald; lg = lg > 0.f ? lg : 0.2f * lg;
            float ex = exp2f(lg * L2E);
            den  += ex;
            acc0 += b2f_lo(vv[i]) * ex;
            acc1 += b2f_hi(vv[i]) * ex;
        }
    }
    // ---- tail (old 2-unrolled path) ----
    for (; p + 1 < p1; p += 2) {
        int s0 = csr_src[p];
        int s1 = csr_src[p + 1];
        float al0 = b2f_s(aleb[(size_t)p * 8 + h]);
        float al1 = b2f_s(aleb[(size_t)(p + 1) * 8 + h]);
        unsigned v0 = *(const unsigned*)(xsb + (size_t)s0 * 128 + lane * 2);
        unsigned v1 = *(const unsigned*)(xsb + (size_t)s1 * 128 + lane * 2);
        float lg0 = al0 + ald; lg0 = lg0 > 0.f ? lg0 : 0.2f * lg0;
        float lg1 = al1 + ald; lg1 = lg1 > 0.f ? lg1 : 0.2f * lg1;
        float ex0 = exp2f(lg0 * L2E);
        float ex1 = exp2f(lg1 * L2E);
        den  += ex0 + ex1;
        acc0 += b2f_lo(v0) * ex0 + b2f_lo(v1) * ex1;
        acc1 += b2f_hi(v0) * ex0 + b2f_hi(v1) * ex1;
    }
    if (p < p1) {
        int s0 = csr_src[p];
        float al0 = b2f_s(aleb[(size_t)p * 8 + h]);
        unsigned v0 = *(const unsigned*)(xsb + (size_t)s0 * 128 + lane * 2);
        float lg0 = al0 + ald; lg0 = lg0 > 0.f ? lg0 : 0.2f * lg0;
        float ex0 = exp2f(lg0 * L2E);
        den  += ex0;
        acc0 += b2f_lo(v0) * ex0;
        acc1 += b2f_hi(v0) * ex0;
    }
    float inv = 1.f / (den + 1e-16f);
    const float2 bb = *(const float2*)(b + lane * 2);
    unsigned o = pack2(f2b(acc0 * inv + bb.x), f2b(acc1 * inv + bb.y));
    *(unsigned*)(houtb + (size_t)dst * 128 + lane * 2) = o;
}

// ---------------- global add pool (bf16 input, f32 atomics) ----------------
__global__ void pool_k(const short* __restrict__ h3b, const int* __restrict__ batch,
                       float* __restrict__ pool, int n) {
    int t = blockIdx.x * blockDim.x + threadIdx.x;
    if (t >= n * 128) return;
    int node = t >> 7, j = t & 127;
    atomicAdd(pool + (size_t)batch[node] * 128 + j, b2f_s(h3b[t]));
}

// ---------------- Wl1 [512(k),512(c)] f32 -> Wl1T [c][k] bf16 ----------------
__global__ void wl1t_k(const float* __restrict__ Wl1, short* __restrict__ Wl1T) {
    int idx = blockIdx.x * blockDim.x + threadIdx.x;   // 262144
    int k = idx >> 9, c = idx & 511;
    Wl1T[(size_t)c * 512 + k] = f2b(Wl1[idx]);
}

__global__ void init_out(float* __restrict__ out, const float* __restrict__ bl2, int n) {
    int t = blockIdx.x * blockDim.x + threadIdx.x;
    if (t < n) out[t] = bl2[0];
}

// ---------------- fused final MLP via bf16 MFMA ----------------
// R6 structure (per-k0 staging, 4 KB LDS, B-frags from L2) with conflict-free
// (sq=wave, row=lane) staging via global_load_lds (dest = wave base + lane*16).
// BM=64, BN=256 (grid.y=2). 4 waves, each 64 rows x 64 cols.
__global__ __launch_bounds__(256) void final_mfma(
    const short* __restrict__ h1, const short* __restrict__ h2,
    const short* __restrict__ h3, const short* __restrict__ poolb,
    const int* __restrict__ batch, const short* __restrict__ Wl1T,
    const float* __restrict__ bl1, const float* __restrict__ Wl2,
    float* __restrict__ out, int nrows)
{
    __shared__ short Abuf[4 * 64 * 8];   // 4 KB: [sq][row][8]
    __shared__ int   sBatch[64];
    const int tid = threadIdx.x;
    const int n0 = blockIdx.x * 64;
    const int j0 = blockIdx.y * 256;
    const int wid = tid >> 6, lane = tid & 63;
    const int lr = lane & 15, kg = lane >> 4;

    if (tid < 64) {
        int gr = n0 + tid;
        sBatch[tid] = (gr < nrows) ? batch[gr] : 0;
    }
    __syncthreads();

    f32x4 acc[4][4] = {};

    for (int k0 = 0; k0 < 512; k0 += 32) {
        const int seg = k0 >> 7;
        const short* base = (seg == 0) ? h1 : (seg == 1) ? h2 : (seg == 2) ? h3 : poolb;
        const int cseg = k0 & 127;
        // stage: wave wid writes [wid][lane] <- row(lane) k-slot(wid); OOB rows clamp to 0
        {
            int gr = n0 + lane;
            int grow = (seg == 3) ? sBatch[lane] : ((gr < nrows) ? gr : 0);
            const short* src = base + (size_t)grow * 128 + cseg + wid * 8;
#if __has_builtin(__builtin_amdgcn_global_load_lds)
            __builtin_amdgcn_global_load_lds(
                (const __attribute__((address_space(1))) unsigned int*)src,
                (__attribute__((address_space(3))) unsigned int*)&Abuf[(wid * 64 + lane) * 8],
                16, 0, 0);
#else
            uint4 v = *(const uint4*)src;
            *(uint4*)(&Abuf[(wid * 64 + lane) * 8]) = v;
#endif
        }
        __syncthreads();
        bf16x8 a[4], b[4];
#pragma unroll
        for (int fm = 0; fm < 4; fm++)
            a[fm] = *(const bf16x8*)(&Abuf[(kg * 64 + fm * 16 + lr) * 8]);
#pragma unroll
        for (int fn = 0; fn < 4; fn++)
            b[fn] = *(const bf16x8*)(Wl1T + (size_t)(j0 + wid * 64 + fn * 16 + lr) * 512
                                     + k0 + kg * 8);
#pragma unroll
        for (int fm = 0; fm < 4; fm++)
#pragma unroll
            for (int fn = 0; fn < 4; fn++)
                acc[fm][fn] = __builtin_amdgcn_mfma_f32_16x16x32_bf16(
                    a[fm], b[fn], acc[fm][fn], 0, 0, 0);
        __syncthreads();   // LDS reads done before next stage overwrites
    }

    // epilogue-only constants (after the loop to keep loop VGPR low)
    float w2[4], b1c[4];
#pragma unroll
    for (int fn = 0; fn < 4; fn++) {
        int c = j0 + wid * 64 + fn * 16 + lr;
        w2[fn]  = Wl2[c];
        b1c[fn] = bl1[c];
    }

#pragma unroll
    for (int fm = 0; fm < 4; fm++) {
#pragma unroll
        for (int r = 0; r < 4; r++) {
            float s = 0.f;
#pragma unroll
            for (int fn = 0; fn < 4; fn++) {
                float z = acc[fm][fn][r] + b1c[fn];
                z = z > 0.f ? z : 0.01f * z;
                s += z * w2[fn];
            }
            s += __shfl_xor(s, 1);
            s += __shfl_xor(s, 2);
            s += __shfl_xor(s, 4);
            s += __shfl_xor(s, 8);
            if (lr == 0) {
                int gr = n0 + fm * 16 + kg * 4 + r;
                if (gr < nrows) atomicAdd(out + gr, s);
            }
        }
    }
}

extern "C" void kernel_launch(void* const* d_in, const int* in_sizes, int n_in,
                              void* d_out, int out_size, void* d_ws, size_t ws_size,
                              hipStream_t stream) {
    const float* x     = (const float*)d_in[0];
    const int*   ei    = (const int*)d_in[1];
    const float* eattr = (const float*)d_in[2];
    const int*   batch = (const int*)d_in[3];
    const float* W[3]   = {(const float*)d_in[4],  (const float*)d_in[10], (const float*)d_in[16]};
    const float* We[3]  = {(const float*)d_in[5],  (const float*)d_in[11], (const float*)d_in[17]};
    const float* as_[3] = {(const float*)d_in[6],  (const float*)d_in[12], (const float*)d_in[18]};
    const float* ad_[3] = {(const float*)d_in[7],  (const float*)d_in[13], (const float*)d_in[19]};
    const float* ae_[3] = {(const float*)d_in[8],  (const float*)d_in[14], (const float*)d_in[20]};
    const float* b_[3]  = {(const float*)d_in[9],  (const float*)d_in[15], (const float*)d_in[21]};
    const float* Wl1 = (const float*)d_in[22];
    const float* bl1 = (const float*)d_in[23];
    const float* Wl2 = (const float*)d_in[24];
    const float* bl2 = (const float*)d_in[25];

    const int N = N_NODES, E = N_EDGES, G = N_GRAPH;

    float* ws    = (float*)d_ws;
    float* xs    = ws;                          // N*128 f32
    float* alsrc = xs + (size_t)N * 128;        // N*8
    float* aldst = alsrc + (size_t)N * 8;       // N*8
    float* pool  = aldst + (size_t)N * 8;       // G*128
    float* aeW   = pool + (size_t)G * 128;      // 128
    short* xb    = (short*)(aeW + 128);         // N*128 bf16 (input x)
    short* xsb   = xb + (size_t)N * 128;        // N*128 bf16 (layer GEMM out)
    short* hb0   = xsb + (size_t)N * 128;       // N*128 bf16
    short* hb1   = hb0 + (size_t)N * 128;
    short* hb2   = hb1 + (size_t)N * 128;
    short* hb[3] = {hb0, hb1, hb2};
    short* poolb = hb2 + (size_t)N * 128;       // G*128 bf16
    short* wbt0  = poolb + (size_t)G * 128;     // 3 x 128*128 bf16
    short* wbt1  = wbt0 + 16384;
    short* wbt2  = wbt1 + 16384;
    short* wbt[3] = {wbt0, wbt1, wbt2};
    short* wl1t  = wbt2 + 16384;                // 512*512 bf16
    short* aleb  = wl1t + 262144;               // E*8 bf16
    int*   cnt     = (int*)(aleb + (size_t)E * 8);  // N
    int*   rowptr  = cnt + N;                   // N+1
    int*   cursor  = rowptr + N + 1;            // N
    int*   part    = cursor + N;                // 256
    int*   pos     = part + 256;                // E
    int*   csr_src = pos + E;                   // E

    // ---- once per call: bf16 conversions + dst-CSR ----
    f2b_bulk<<<(N * 32 + 255) / 256, 256, 0, stream>>>(x, xb, N * 32);
    for (int l = 0; l < 3; l++)
        wbt_k<<<64, 256, 0, stream>>>(W[l], wbt[l]);
    wl1t_k<<<1024, 256, 0, stream>>>(Wl1, wl1t);
    hipMemsetAsync(cnt, 0, (size_t)N * sizeof(int), stream);
    hist_k<<<(E + 255) / 256, 256, 0, stream>>>(ei, cnt, E);
    const int nblk = (N + 255) / 256;   // 196
    scan1_k<<<nblk, 256, 0, stream>>>(cnt, rowptr, part, N);
    scan2_k<<<1, 256, 0, stream>>>(part, nblk);
    scan3_k<<<nblk, 256, 0, stream>>>(rowptr, part, cursor, N, E);
    scatter_k<<<(E + 255) / 256, 256, 0, stream>>>(ei, cursor, pos, csr_src, E);

    for (int l = 0; l < 3; l++) {
        const short* Ain = (l == 0) ? xb : hb[l - 1];
        gemm_mfma<<<(N + 63) / 64, 256, 0, stream>>>(Ain, wbt[l], xs, xsb, N);
        node_al<<<(N * 8 + 255) / 256, 256, 0, stream>>>(xs, as_[l], ad_[l], alsrc, aldst, N);
        aew_k<<<1, 128, 0, stream>>>(We[l], ae_[l], aeW);
        ale_k<<<(E + 255) / 256, 256, 0, stream>>>(ei, eattr, alsrc, aeW, pos, aleb, E);
        gather_k<<<(N + 3) / 4, 256, 0, stream>>>(rowptr, csr_src, aleb, aldst, xsb,
                                                  b_[l], hb[l], N);
    }
    hipMemsetAsync(pool, 0, (size_t)G * 128 * sizeof(float), stream);
    pool_k<<<(N * 128 + 255) / 256, 256, 0, stream>>>(hb[2], batch, pool, N);
    f2b_bulk<<<(G * 32 + 255) / 256, 256, 0, stream>>>(pool, poolb, G * 32);

    init_out<<<(N + 255) / 256, 256, 0, stream>>>((float*)d_out, bl2, N);
    dim3 fg((N + 63) / 64, 2);
    final_mfma<<<fg, 256, 0, stream>>>(hb[0], hb[1], hb[2], poolb, batch,
                                       wl1t, bl1, Wl2, (float*)d_out, N);
}

// Round 12
// 487.597 us; speedup vs baseline: 1.2336x; 1.0115x over previous
//
#include <hip/hip_runtime.h>

#define N_NODES 50000
#define N_EDGES 800000
#define N_GRAPH 1000

typedef short bf16x8 __attribute__((ext_vector_type(8)));
typedef float f32x4 __attribute__((ext_vector_type(4)));

__device__ inline short f2b(float f) {   // f32 -> bf16 (RNE)
    union { float f; unsigned u; } x; x.f = f;
    unsigned r = x.u + 0x7FFF + ((x.u >> 16) & 1);
    return (short)(r >> 16);
}
__device__ inline float b2f_lo(unsigned v) {
    union { unsigned u; float f; } x; x.u = v << 16; return x.f;
}
__device__ inline float b2f_hi(unsigned v) {
    union { unsigned u; float f; } x; x.u = v & 0xFFFF0000u; return x.f;
}
__device__ inline float b2f_s(short s) {
    union { unsigned u; float f; } x; x.u = ((unsigned)(unsigned short)s) << 16; return x.f;
}
__device__ inline unsigned pack2(short lo, short hi) {
    return ((unsigned)(unsigned short)lo) | (((unsigned)(unsigned short)hi) << 16);
}

// ---------------- f32 -> bf16 bulk convert (vectorized) ----------------
__global__ void f2b_bulk(const float* __restrict__ in, short* __restrict__ out, int n4) {
    int t = blockIdx.x * blockDim.x + threadIdx.x;
    if (t >= n4) return;
    float4 v = *(const float4*)(in + (size_t)t * 4);
    *(short4*)(out + (size_t)t * 4) = make_short4(f2b(v.x), f2b(v.y), f2b(v.z), f2b(v.w));
}

// ---------------- W[128(k)][128(c)] f32 -> WbT[c][k] bf16 ----------------
__global__ void wbt_k(const float* __restrict__ W, short* __restrict__ WbT) {
    int idx = blockIdx.x * blockDim.x + threadIdx.x;   // 16384
    int k = idx >> 7, c = idx & 127;
    WbT[(size_t)c * 128 + k] = f2b(W[idx]);
}

// ---------------- layer GEMM via MFMA: no LDS, no barriers ----------------
__global__ __launch_bounds__(256) void gemm_mfma(const short* __restrict__ Ab,
                                                 const short* __restrict__ WbT,
                                                 float* __restrict__ out,
                                                 short* __restrict__ outb, int nrows) {
    const int tid = threadIdx.x;
    const int n0 = blockIdx.x * 64;
    const int wid = tid >> 6, lane = tid & 63;
    const int lr = lane & 15, kg = lane >> 4;
    const int wr = (wid >> 1) * 32;    // wave row offset (0/32)
    const int wc = (wid & 1) * 64;     // wave col offset (0/64)

    f32x4 acc[2][4] = {};

#pragma unroll
    for (int ks = 0; ks < 4; ks++) {
        const int k0 = ks * 32;
        bf16x8 a[2], b[4];
#pragma unroll
        for (int fm = 0; fm < 2; fm++) {
            int gr = n0 + wr + fm * 16 + lr;
            bf16x8 v = {};
            if (gr < nrows) v = *(const bf16x8*)(Ab + (size_t)gr * 128 + k0 + kg * 8);
            a[fm] = v;
        }
#pragma unroll
        for (int fn = 0; fn < 4; fn++)
            b[fn] = *(const bf16x8*)(WbT + (size_t)(wc + fn * 16 + lr) * 128 + k0 + kg * 8);
#pragma unroll
        for (int fm = 0; fm < 2; fm++)
#pragma unroll
            for (int fn = 0; fn < 4; fn++)
                acc[fm][fn] = __builtin_amdgcn_mfma_f32_16x16x32_bf16(
                    a[fm], b[fn], acc[fm][fn], 0, 0, 0);
    }
#pragma unroll
    for (int fm = 0; fm < 2; fm++) {
#pragma unroll
        for (int r = 0; r < 4; r++) {
            int gr = n0 + wr + fm * 16 + kg * 4 + r;
            if (gr < nrows) {
#pragma unroll
                for (int fn = 0; fn < 4; fn++) {
                    int col = wc + fn * 16 + lr;
                    float z = acc[fm][fn][r];
                    out[(size_t)gr * 128 + col] = z;
                    outb[(size_t)gr * 128 + col] = f2b(z);
                }
            }
        }
    }
}

// ---------------- per-node attention coefficients ----------------
__global__ void node_al(const float* __restrict__ xs, const float* __restrict__ a_s,
                        const float* __restrict__ a_d, float* __restrict__ alsrc,
                        float* __restrict__ aldst, int n) {
    int t = blockIdx.x * blockDim.x + threadIdx.x;
    if (t >= n * 8) return;
    int node = t >> 3, h = t & 7;
    const float4* xp = (const float4*)(xs + (size_t)node * 128 + h * 16);
    const float4* sp = (const float4*)(a_s + h * 16);
    const float4* dp = (const float4*)(a_d + h * 16);
    float ss = 0.f, dd = 0.f;
#pragma unroll
    for (int q = 0; q < 4; q++) {
        float4 x4 = xp[q], s4 = sp[q], d4 = dp[q];
        ss += x4.x * s4.x + x4.y * s4.y + x4.z * s4.z + x4.w * s4.w;
        dd += x4.x * d4.x + x4.y * d4.y + x4.z * d4.z + x4.w * d4.w;
    }
    alsrc[t] = ss;
    aldst[t] = dd;
}

// ---------------- aeW[k][h] = sum_c We[k, h*16+c] * ae[h,c] ----------------
__global__ void aew_k(const float* __restrict__ We, const float* __restrict__ ae,
                      float* __restrict__ aeW) {
    int t = threadIdx.x;   // 128 threads
    int k = t >> 3, h = t & 7;
    float s = 0.f;
#pragma unroll
    for (int c = 0; c < 16; c++) s += We[k * 128 + h * 16 + c] * ae[h * 16 + c];
    aeW[k * 8 + h] = s;
}

// ---------------- CSR build ----------------
__global__ void hist_k(const int* __restrict__ ei, int* __restrict__ cnt, int ne) {
    int e = blockIdx.x * blockDim.x + threadIdx.x;
    if (e < ne) atomicAdd(&cnt[ei[ne + e]], 1);
}

__global__ void scan1_k(const int* __restrict__ cnt, int* __restrict__ rowptr,
                        int* __restrict__ part, int n) {
    __shared__ int s[256];
    int tid = threadIdx.x;
    int i = blockIdx.x * 256 + tid;
    int v = (i < n) ? cnt[i] : 0;
    s[tid] = v; __syncthreads();
#pragma unroll
    for (int off = 1; off < 256; off <<= 1) {
        int t = (tid >= off) ? s[tid - off] : 0;
        __syncthreads();
        s[tid] += t;
        __syncthreads();
    }
    if (i < n) rowptr[i] = s[tid] - v;
    if (tid == 255) part[blockIdx.x] = s[255];
}

__global__ void scan2_k(int* __restrict__ part, int npart) {
    __shared__ int s[256];
    int tid = threadIdx.x;
    int v = (tid < npart) ? part[tid] : 0;
    s[tid] = v; __syncthreads();
#pragma unroll
    for (int off = 1; off < 256; off <<= 1) {
        int t = (tid >= off) ? s[tid - off] : 0;
        __syncthreads();
        s[tid] += t;
        __syncthreads();
    }
    if (tid < npart) part[tid] = s[tid] - v;
}

__global__ void scan3_k(int* __restrict__ rowptr, const int* __restrict__ part,
                        int* __restrict__ cursor, int n, int ne) {
    int i = blockIdx.x * 256 + threadIdx.x;
    if (i < n) {
        int r = rowptr[i] + part[blockIdx.x];
        rowptr[i] = r;
        cursor[i] = r;
    }
    if (i == 0) rowptr[n] = ne;
}

__global__ void scatter_k(const int* __restrict__ ei, int* __restrict__ cursor,
                          int* __restrict__ pos, int* __restrict__ csr_src, int ne) {
    int e = blockIdx.x * blockDim.x + threadIdx.x;
    if (e >= ne) return;
    int d = ei[ne + e];
    int p = atomicAdd(&cursor[d], 1);
    pos[e] = p;
    csr_src[p] = ei[e];
}

// ---------------- per-edge logits (alsrc + al_e), bf16, CSR order ----------------
__global__ __launch_bounds__(256) void ale_k(const int* __restrict__ ei,
                                             const float* __restrict__ eattr,
                                             const float* __restrict__ alsrc,
                                             const float* __restrict__ aeW,
                                             const int* __restrict__ pos,
                                             short* __restrict__ aleb, int ne) {
    __shared__ float sAe[128];
    if (threadIdx.x < 128) sAe[threadIdx.x] = aeW[threadIdx.x];
    __syncthreads();
    int e = blockIdx.x * blockDim.x + threadIdx.x;
    if (e >= ne) return;
    float ea[16];
    const float4* ep = (const float4*)(eattr + (size_t)e * 16);
#pragma unroll
    for (int q = 0; q < 4; q++) {
        float4 v = ep[q];
        ea[q * 4 + 0] = v.x; ea[q * 4 + 1] = v.y; ea[q * 4 + 2] = v.z; ea[q * 4 + 3] = v.w;
    }
    int s = ei[e];
    float out[8];
#pragma unroll
    for (int h = 0; h < 8; h++) out[h] = alsrc[s * 8 + h];
#pragma unroll
    for (int k = 0; k < 16; k++)
#pragma unroll
        for (int h = 0; h < 8; h++) out[h] += ea[k] * sAe[k * 8 + h];
    short v8[8];
#pragma unroll
    for (int h = 0; h < 8; h++) v8[h] = f2b(out[h]);
    short* op = aleb + (size_t)pos[e] * 8;
    *(short4*)(op)     = make_short4(v8[0], v8[1], v8[2], v8[3]);
    *(short4*)(op + 4) = make_short4(v8[4], v8[5], v8[6], v8[7]);
}

// ---------------- gather: one wave per dst; breadth-first 8-edge chunks ----------------
__global__ __launch_bounds__(256) void gather_k(const int* __restrict__ rowptr,
                                                const int* __restrict__ csr_src,
                                                const short* __restrict__ aleb,
                                                const float* __restrict__ aldst,
                                                const short* __restrict__ xsb,
                                                const float* __restrict__ b,
                                                short* __restrict__ houtb, int n) {
    int dst = blockIdx.x * 4 + (threadIdx.x >> 6);
    if (dst >= n) return;
    const int lane = threadIdx.x & 63;
    const int h = lane >> 3;
    const float L2E = 1.44269504f;
    int p0 = rowptr[dst], p1 = rowptr[dst + 1];
    float ald = aldst[dst * 8 + h];
    float den = 0.f, acc0 = 0.f, acc1 = 0.f;
    int p = p0;
    for (; p + 8 <= p1; p += 8) {
        int   sv  = csr_src[p + (lane & 7)];                 // lanes 0-7: the 8 srcs
        float alv = b2f_s(aleb[(size_t)p * 8 + lane]);       // 8 edges x 8 heads
        int s0 = __shfl(sv, 0), s1 = __shfl(sv, 1), s2 = __shfl(sv, 2), s3 = __shfl(sv, 3);
        int s4 = __shfl(sv, 4), s5 = __shfl(sv, 5), s6 = __shfl(sv, 6), s7 = __shfl(sv, 7);
        unsigned v0 = *(const unsigned*)(xsb + (size_t)s0 * 128 + lane * 2);
        unsigned v1 = *(const unsigned*)(xsb + (size_t)s1 * 128 + lane * 2);
        unsigned v2 = *(const unsigned*)(xsb + (size_t)s2 * 128 + lane * 2);
        unsigned v3 = *(const unsigned*)(xsb + (size_t)s3 * 128 + lane * 2);
        unsigned v4 = *(const unsigned*)(xsb + (size_t)s4 * 128 + lane * 2);
        unsigned v5 = *(const unsigned*)(xsb + (size_t)s5 * 128 + lane * 2);
        unsigned v6 = *(const unsigned*)(xsb + (size_t)s6 * 128 + lane * 2);
        unsigned v7 = *(const unsigned*)(xsb + (size_t)s7 * 128 + lane * 2);
        unsigned vv[8] = {v0, v1, v2, v3, v4, v5, v6, v7};
#pragma unroll
        for (int i = 0; i < 8; i++) {
            float al = __shfl(alv, i * 8 + h);
            float lg = al + ald; lg = lg > 0.f ? lg : 0.2f * lg;
            float ex = exp2f(lg * L2E);
            den  += ex;
            acc0 += b2f_lo(vv[i]) * ex;
            acc1 += b2f_hi(vv[i]) * ex;
        }
    }
    for (; p + 1 < p1; p += 2) {
        int s0 = csr_src[p];
        int s1 = csr_src[p + 1];
        float al0 = b2f_s(aleb[(size_t)p * 8 + h]);
        float al1 = b2f_s(aleb[(size_t)(p + 1) * 8 + h]);
        unsigned v0 = *(const unsigned*)(xsb + (size_t)s0 * 128 + lane * 2);
        unsigned v1 = *(const unsigned*)(xsb + (size_t)s1 * 128 + lane * 2);
        float lg0 = al0 + ald; lg0 = lg0 > 0.f ? lg0 : 0.2f * lg0;
        float lg1 = al1 + ald; lg1 = lg1 > 0.f ? lg1 : 0.2f * lg1;
        float ex0 = exp2f(lg0 * L2E);
        float ex1 = exp2f(lg1 * L2E);
        den  += ex0 + ex1;
        acc0 += b2f_lo(v0) * ex0 + b2f_lo(v1) * ex1;
        acc1 += b2f_hi(v0) * ex0 + b2f_hi(v1) * ex1;
    }
    if (p < p1) {
        int s0 = csr_src[p];
        float al0 = b2f_s(aleb[(size_t)p * 8 + h]);
        unsigned v0 = *(const unsigned*)(xsb + (size_t)s0 * 128 + lane * 2);
        float lg0 = al0 + ald; lg0 = lg0 > 0.f ? lg0 : 0.2f * lg0;
        float ex0 = exp2f(lg0 * L2E);
        den  += ex0;
        acc0 += b2f_lo(v0) * ex0;
        acc1 += b2f_hi(v0) * ex0;
    }
    float inv = 1.f / (den + 1e-16f);
    const float2 bb = *(const float2*)(b + lane * 2);
    unsigned o = pack2(f2b(acc0 * inv + bb.x), f2b(acc1 * inv + bb.y));
    *(unsigned*)(houtb + (size_t)dst * 128 + lane * 2) = o;
}

// ---------------- global add pool (bf16 input, f32 atomics) ----------------
__global__ void pool_k(const short* __restrict__ h3b, const int* __restrict__ batch,
                       float* __restrict__ pool, int n) {
    int t = blockIdx.x * blockDim.x + threadIdx.x;
    if (t >= n * 128) return;
    int node = t >> 7, j = t & 127;
    atomicAdd(pool + (size_t)batch[node] * 128 + j, b2f_s(h3b[t]));
}

// ---------------- Wl1 [512(k),512(c)] f32 -> Wl1T [c][k] bf16 ----------------
__global__ void wl1t_k(const float* __restrict__ Wl1, short* __restrict__ Wl1T) {
    int idx = blockIdx.x * blockDim.x + threadIdx.x;   // 262144
    int k = idx >> 9, c = idx & 511;
    Wl1T[(size_t)c * 512 + k] = f2b(Wl1[idx]);
}

__global__ void init_out(float* __restrict__ out, const float* __restrict__ bl2, int n) {
    int t = blockIdx.x * blockDim.x + threadIdx.x;
    if (t < n) out[t] = bl2[0];
}

// ---------------- fused final MLP via bf16 MFMA: safe 2-phase double-buffer ----------------
// T3 minimum recipe: issue STAGE(t+1) BEFORE compute; ONE __syncthreads per k-step
// AFTER the MFMAs (stage latency hides under ds_read+MFMA). No inline asm.
// BM=64, BN=256 (grid.y=2). 4 waves, each 64 rows x 64 cols. B-frags from L2 (reg dbuf).
__global__ __launch_bounds__(256) void final_mfma(
    const short* __restrict__ h1, const short* __restrict__ h2,
    const short* __restrict__ h3, const short* __restrict__ poolb,
    const int* __restrict__ batch, const short* __restrict__ Wl1T,
    const float* __restrict__ bl1, const float* __restrict__ Wl2,
    float* __restrict__ out, int nrows)
{
    __shared__ short Abuf[2][4 * 64 * 8];   // 2 x 4 KB: [buf][sq][row][8]
    __shared__ int   sBatch[64];
    const int tid = threadIdx.x;
    const int n0 = blockIdx.x * 64;
    const int j0 = blockIdx.y * 256;
    const int wid = tid >> 6, lane = tid & 63;
    const int lr = lane & 15, kg = lane >> 4;

    if (tid < 64) {
        int gr = n0 + tid;
        sBatch[tid] = (gr < nrows) ? batch[gr] : 0;
    }
    __syncthreads();

    const short* seg_base[4] = {h1, h2, h3, poolb};

    // stage k-step t (k0 = t*32) into Abuf[t&1]; wave wid owns k-slot wid, row = lane
    auto STAGE = [&](int t) {
        const int k0 = t * 32;
        const int seg = k0 >> 7;
        const short* base = seg_base[seg];
        const int cseg = k0 & 127;
        int gr = n0 + lane;
        int grow = (seg == 3) ? sBatch[lane] : ((gr < nrows) ? gr : 0);
        const short* src = base + (size_t)grow * 128 + cseg + wid * 8;
#if __has_builtin(__builtin_amdgcn_global_load_lds)
        __builtin_amdgcn_global_load_lds(
            (const __attribute__((address_space(1))) unsigned int*)src,
            (__attribute__((address_space(3))) unsigned int*)&Abuf[t & 1][(wid * 64 + lane) * 8],
            16, 0, 0);
#else
        uint4 v = *(const uint4*)src;
        *(uint4*)(&Abuf[t & 1][(wid * 64 + lane) * 8]) = v;
#endif
    };
    auto LOADB = [&](int t, bf16x8* bb) {
        const int k0 = t * 32;
#pragma unroll
        for (int fn = 0; fn < 4; fn++)
            bb[fn] = *(const bf16x8*)(Wl1T + (size_t)(j0 + wid * 64 + fn * 16 + lr) * 512
                                      + k0 + kg * 8);
    };

    f32x4 acc[4][4] = {};
    bf16x8 bc[4], bn[4];

    STAGE(0);
    LOADB(0, bc);
    __syncthreads();   // stage 0 landed (full drain)
#pragma unroll
    for (int t = 0; t < 16; t++) {
        if (t < 15) {
            STAGE(t + 1);      // into buf t&1^1 -- hides under this iter's compute
            LOADB(t + 1, bn);
        }
        bf16x8 a[4];
#pragma unroll
        for (int fm = 0; fm < 4; fm++)
            a[fm] = *(const bf16x8*)(&Abuf[t & 1][(kg * 64 + fm * 16 + lr) * 8]);
#pragma unroll
        for (int fm = 0; fm < 4; fm++)
#pragma unroll
            for (int fn = 0; fn < 4; fn++)
                acc[fm][fn] = __builtin_amdgcn_mfma_f32_16x16x32_bf16(
                    a[fm], bc[fn], acc[fm][fn], 0, 0, 0);
        if (t < 15) {
            __syncthreads();   // drains STAGE(t+1)+LOADB(t+1); all waves' reads of buf done
#pragma unroll
            for (int fn = 0; fn < 4; fn++) bc[fn] = bn[fn];
        }
    }

    // epilogue-only constants
    float w2[4], b1c[4];
#pragma unroll
    for (int fn = 0; fn < 4; fn++) {
        int c = j0 + wid * 64 + fn * 16 + lr;
        w2[fn]  = Wl2[c];
        b1c[fn] = bl1[c];
    }

#pragma unroll
    for (int fm = 0; fm < 4; fm++) {
#pragma unroll
        for (int r = 0; r < 4; r++) {
            float s = 0.f;
#pragma unroll
            for (int fn = 0; fn < 4; fn++) {
                float z = acc[fm][fn][r] + b1c[fn];
                z = z > 0.f ? z : 0.01f * z;
                s += z * w2[fn];
            }
            s += __shfl_xor(s, 1);
            s += __shfl_xor(s, 2);
            s += __shfl_xor(s, 4);
            s += __shfl_xor(s, 8);
            if (lr == 0) {
                int gr = n0 + fm * 16 + kg * 4 + r;
                if (gr < nrows) atomicAdd(out + gr, s);
            }
        }
    }
}

extern "C" void kernel_launch(void* const* d_in, const int* in_sizes, int n_in,
                              void* d_out, int out_size, void* d_ws, size_t ws_size,
                              hipStream_t stream) {
    const float* x     = (const float*)d_in[0];
    const int*   ei    = (const int*)d_in[1];
    const float* eattr = (const float*)d_in[2];
    const int*   batch = (const int*)d_in[3];
    const float* W[3]   = {(const float*)d_in[4],  (const float*)d_in[10], (const float*)d_in[16]};
    const float* We[3]  = {(const float*)d_in[5],  (const float*)d_in[11], (const float*)d_in[17]};
    const float* as_[3] = {(const float*)d_in[6],  (const float*)d_in[12], (const float*)d_in[18]};
    const float* ad_[3] = {(const float*)d_in[7],  (const float*)d_in[13], (const float*)d_in[19]};
    const float* ae_[3] = {(const float*)d_in[8],  (const float*)d_in[14], (const float*)d_in[20]};
    const float* b_[3]  = {(const float*)d_in[9],  (const float*)d_in[15], (const float*)d_in[21]};
    const float* Wl1 = (const float*)d_in[22];
    const float* bl1 = (const float*)d_in[23];
    const float* Wl2 = (const float*)d_in[24];
    const float* bl2 = (const float*)d_in[25];

    const int N = N_NODES, E = N_EDGES, G = N_GRAPH;

    float* ws    = (float*)d_ws;
    float* xs    = ws;                          // N*128 f32
    float* alsrc = xs + (size_t)N * 128;        // N*8
    float* aldst = alsrc + (size_t)N * 8;       // N*8
    float* pool  = aldst + (size_t)N * 8;       // G*128
    float* aeW   = pool + (size_t)G * 128;      // 128
    short* xb    = (short*)(aeW + 128);         // N*128 bf16 (input x)
    short* xsb   = xb + (size_t)N * 128;        // N*128 bf16 (layer GEMM out)
    short* hb0   = xsb + (size_t)N * 128;       // N*128 bf16
    short* hb1   = hb0 + (size_t)N * 128;
    short* hb2   = hb1 + (size_t)N * 128;
    short* hb[3] = {hb0, hb1, hb2};
    short* poolb = hb2 + (size_t)N * 128;       // G*128 bf16
    short* wbt0  = poolb + (size_t)G * 128;     // 3 x 128*128 bf16
    short* wbt1  = wbt0 + 16384;
    short* wbt2  = wbt1 + 16384;
    short* wbt[3] = {wbt0, wbt1, wbt2};
    short* wl1t  = wbt2 + 16384;                // 512*512 bf16
    short* aleb  = wl1t + 262144;               // E*8 bf16
    int*   cnt     = (int*)(aleb + (size_t)E * 8);  // N
    int*   rowptr  = cnt + N;                   // N+1
    int*   cursor  = rowptr + N + 1;            // N
    int*   part    = cursor + N;                // 256
    int*   pos     = part + 256;                // E
    int*   csr_src = pos + E;                   // E

    // ---- once per call: bf16 conversions + dst-CSR ----
    f2b_bulk<<<(N * 32 + 255) / 256, 256, 0, stream>>>(x, xb, N * 32);
    for (int l = 0; l < 3; l++)
        wbt_k<<<64, 256, 0, stream>>>(W[l], wbt[l]);
    wl1t_k<<<1024, 256, 0, stream>>>(Wl1, wl1t);
    hipMemsetAsync(cnt, 0, (size_t)N * sizeof(int), stream);
    hist_k<<<(E + 255) / 256, 256, 0, stream>>>(ei, cnt, E);
    const int nblk = (N + 255) / 256;   // 196
    scan1_k<<<nblk, 256, 0, stream>>>(cnt, rowptr, part, N);
    scan2_k<<<1, 256, 0, stream>>>(part, nblk);
    scan3_k<<<nblk, 256, 0, stream>>>(rowptr, part, cursor, N, E);
    scatter_k<<<(E + 255) / 256, 256, 0, stream>>>(ei, cursor, pos, csr_src, E);

    for (int l = 0; l < 3; l++) {
        const short* Ain = (l == 0) ? xb : hb[l - 1];
        gemm_mfma<<<(N + 63) / 64, 256, 0, stream>>>(Ain, wbt[l], xs, xsb, N);
        node_al<<<(N * 8 + 255) / 256, 256, 0, stream>>>(xs, as_[l], ad_[l], alsrc, aldst, N);
        aew_k<<<1, 128, 0, stream>>>(We[l], ae_[l], aeW);
        ale_k<<<(E + 255) / 256, 256, 0, stream>>>(ei, eattr, alsrc, aeW, pos, aleb, E);
        gather_k<<<(N + 3) / 4, 256, 0, stream>>>(rowptr, csr_src, aleb, aldst, xsb,
                                                  b_[l], hb[l], N);
    }
    hipMemsetAsync(pool, 0, (size_t)G * 128 * sizeof(float), stream);
    pool_k<<<(N * 128 + 255) / 256, 256, 0, stream>>>(hb[2], batch, pool, N);
    f2b_bulk<<<(G * 32 + 255) / 256, 256, 0, stream>>>(pool, poolb, G * 32);

    init_out<<<(N + 255) / 256, 256, 0, stream>>>((float*)d_out, bl2, N);
    dim3 fg((N + 63) / 64, 2);
    final_mfma<<<fg, 256, 0, stream>>>(hb[0], hb[1], hb[2], poolb, batch,
                                       wl1t, bl1, Wl2, (float*)d_out, N);
}

// Round 13
// 482.198 us; speedup vs baseline: 1.2475x; 1.0112x over previous
//
#include <hip/hip_runtime.h>

#define N_NODES 50000
#define N_EDGES 800000
#define N_GRAPH 1000

typedef short bf16x8 __attribute__((ext_vector_type(8)));
typedef float f32x4 __attribute__((ext_vector_type(4)));

__device__ inline short f2b(float f) {   // f32 -> bf16 (RNE)
    union { float f; unsigned u; } x; x.f = f;
    unsigned r = x.u + 0x7FFF + ((x.u >> 16) & 1);
    return (short)(r >> 16);
}
__device__ inline float b2f_lo(unsigned v) {
    union { unsigned u; float f; } x; x.u = v << 16; return x.f;
}
__device__ inline float b2f_hi(unsigned v) {
    union { unsigned u; float f; } x; x.u = v & 0xFFFF0000u; return x.f;
}
__device__ inline float b2f_s(short s) {
    union { unsigned u; float f; } x; x.u = ((unsigned)(unsigned short)s) << 16; return x.f;
}
__device__ inline unsigned pack2(short lo, short hi) {
    return ((unsigned)(unsigned short)lo) | (((unsigned)(unsigned short)hi) << 16);
}

// ---------------- f32 -> bf16 bulk convert (vectorized) ----------------
__global__ void f2b_bulk(const float* __restrict__ in, short* __restrict__ out, int n4) {
    int t = blockIdx.x * blockDim.x + threadIdx.x;
    if (t >= n4) return;
    float4 v = *(const float4*)(in + (size_t)t * 4);
    *(short4*)(out + (size_t)t * 4) = make_short4(f2b(v.x), f2b(v.y), f2b(v.z), f2b(v.w));
}

// ---------------- W[128(k)][128(c)] f32 -> WbT[c][k] bf16 ----------------
__global__ void wbt_k(const float* __restrict__ W, short* __restrict__ WbT) {
    int idx = blockIdx.x * blockDim.x + threadIdx.x;   // 16384
    int k = idx >> 7, c = idx & 127;
    WbT[(size_t)c * 128 + k] = f2b(W[idx]);
}

// ---------------- layer GEMM via MFMA: no LDS, no barriers; bf16 out only ----------------
__global__ __launch_bounds__(256) void gemm_mfma(const short* __restrict__ Ab,
                                                 const short* __restrict__ WbT,
                                                 short* __restrict__ outb, int nrows) {
    const int tid = threadIdx.x;
    const int n0 = blockIdx.x * 64;
    const int wid = tid >> 6, lane = tid & 63;
    const int lr = lane & 15, kg = lane >> 4;
    const int wr = (wid >> 1) * 32;    // wave row offset (0/32)
    const int wc = (wid & 1) * 64;     // wave col offset (0/64)

    f32x4 acc[2][4] = {};

#pragma unroll
    for (int ks = 0; ks < 4; ks++) {
        const int k0 = ks * 32;
        bf16x8 a[2], b[4];
#pragma unroll
        for (int fm = 0; fm < 2; fm++) {
            int gr = n0 + wr + fm * 16 + lr;
            bf16x8 v = {};
            if (gr < nrows) v = *(const bf16x8*)(Ab + (size_t)gr * 128 + k0 + kg * 8);
            a[fm] = v;
        }
#pragma unroll
        for (int fn = 0; fn < 4; fn++)
            b[fn] = *(const bf16x8*)(WbT + (size_t)(wc + fn * 16 + lr) * 128 + k0 + kg * 8);
#pragma unroll
        for (int fm = 0; fm < 2; fm++)
#pragma unroll
            for (int fn = 0; fn < 4; fn++)
                acc[fm][fn] = __builtin_amdgcn_mfma_f32_16x16x32_bf16(
                    a[fm], b[fn], acc[fm][fn], 0, 0, 0);
    }
#pragma unroll
    for (int fm = 0; fm < 2; fm++) {
#pragma unroll
        for (int r = 0; r < 4; r++) {
            int gr = n0 + wr + fm * 16 + kg * 4 + r;
            if (gr < nrows) {
#pragma unroll
                for (int fn = 0; fn < 4; fn++) {
                    int col = wc + fn * 16 + lr;
                    outb[(size_t)gr * 128 + col] = f2b(acc[fm][fn][r]);
                }
            }
        }
    }
}

// ---------------- per-node attention coefficients (bf16 input) ----------------
__global__ void node_al(const short* __restrict__ xsb, const float* __restrict__ a_s,
                        const float* __restrict__ a_d, float* __restrict__ alsrc,
                        float* __restrict__ aldst, int n) {
    int t = blockIdx.x * blockDim.x + threadIdx.x;
    if (t >= n * 8) return;
    int node = t >> 3, h = t & 7;
    const short* xp = xsb + (size_t)node * 128 + h * 16;
    uint4 u0 = *(const uint4*)(xp);
    uint4 u1 = *(const uint4*)(xp + 8);
    unsigned w[8] = {u0.x, u0.y, u0.z, u0.w, u1.x, u1.y, u1.z, u1.w};
    float ss = 0.f, dd = 0.f;
#pragma unroll
    for (int q = 0; q < 8; q++) {
        float lo = b2f_lo(w[q]), hi = b2f_hi(w[q]);
        ss += lo * a_s[h * 16 + q * 2] + hi * a_s[h * 16 + q * 2 + 1];
        dd += lo * a_d[h * 16 + q * 2] + hi * a_d[h * 16 + q * 2 + 1];
    }
    alsrc[t] = ss;
    aldst[t] = dd;
}

// ---------------- CSR build ----------------
__global__ void hist_k(const int* __restrict__ ei, int* __restrict__ cnt, int ne) {
    int e = blockIdx.x * blockDim.x + threadIdx.x;
    if (e < ne) atomicAdd(&cnt[ei[ne + e]], 1);
}

__global__ void scan1_k(const int* __restrict__ cnt, int* __restrict__ rowptr,
                        int* __restrict__ part, int n) {
    __shared__ int s[256];
    int tid = threadIdx.x;
    int i = blockIdx.x * 256 + tid;
    int v = (i < n) ? cnt[i] : 0;
    s[tid] = v; __syncthreads();
#pragma unroll
    for (int off = 1; off < 256; off <<= 1) {
        int t = (tid >= off) ? s[tid - off] : 0;
        __syncthreads();
        s[tid] += t;
        __syncthreads();
    }
    if (i < n) rowptr[i] = s[tid] - v;
    if (tid == 255) part[blockIdx.x] = s[255];
}

__global__ void scan2_k(int* __restrict__ part, int npart) {
    __shared__ int s[256];
    int tid = threadIdx.x;
    int v = (tid < npart) ? part[tid] : 0;
    s[tid] = v; __syncthreads();
#pragma unroll
    for (int off = 1; off < 256; off <<= 1) {
        int t = (tid >= off) ? s[tid - off] : 0;
        __syncthreads();
        s[tid] += t;
        __syncthreads();
    }
    if (tid < npart) part[tid] = s[tid] - v;
}

__global__ void scan3_k(int* __restrict__ rowptr, const int* __restrict__ part,
                        int* __restrict__ cursor, int n, int ne) {
    int i = blockIdx.x * 256 + threadIdx.x;
    if (i < n) {
        int r = rowptr[i] + part[blockIdx.x];
        rowptr[i] = r;
        cursor[i] = r;
    }
    if (i == 0) rowptr[n] = ne;
}

__global__ void scatter_k(const int* __restrict__ ei, int* __restrict__ cursor,
                          int* __restrict__ pos, int* __restrict__ csr_src, int ne) {
    int e = blockIdx.x * blockDim.x + threadIdx.x;
    if (e >= ne) return;
    int d = ei[ne + e];
    int p = atomicAdd(&cursor[d], 1);
    pos[e] = p;
    csr_src[p] = ei[e];
}

// ---------------- per-edge logits (alsrc + al_e), bf16, CSR order ----------------
// aeW[k][h] computed in-block from We/ae (folds former aew_k kernel)
__global__ __launch_bounds__(256) void ale_k(const int* __restrict__ ei,
                                             const float* __restrict__ eattr,
                                             const float* __restrict__ alsrc,
                                             const float* __restrict__ We,
                                             const float* __restrict__ ae,
                                             const int* __restrict__ pos,
                                             short* __restrict__ aleb, int ne) {
    __shared__ float sAe[128];
    if (threadIdx.x < 128) {
        int k = threadIdx.x >> 3, h = threadIdx.x & 7;
        float s = 0.f;
#pragma unroll
        for (int c = 0; c < 16; c++) s += We[k * 128 + h * 16 + c] * ae[h * 16 + c];
        sAe[threadIdx.x] = s;   // layout [k*8+h] == tid
    }
    __syncthreads();
    int e = blockIdx.x * blockDim.x + threadIdx.x;
    if (e >= ne) return;
    float ea[16];
    const float4* ep = (const float4*)(eattr + (size_t)e * 16);
#pragma unroll
    for (int q = 0; q < 4; q++) {
        float4 v = ep[q];
        ea[q * 4 + 0] = v.x; ea[q * 4 + 1] = v.y; ea[q * 4 + 2] = v.z; ea[q * 4 + 3] = v.w;
    }
    int s = ei[e];
    float out[8];
#pragma unroll
    for (int h = 0; h < 8; h++) out[h] = alsrc[s * 8 + h];
#pragma unroll
    for (int k = 0; k < 16; k++)
#pragma unroll
        for (int h = 0; h < 8; h++) out[h] += ea[k] * sAe[k * 8 + h];
    short v8[8];
#pragma unroll
    for (int h = 0; h < 8; h++) v8[h] = f2b(out[h]);
    short* op = aleb + (size_t)pos[e] * 8;
    *(short4*)(op)     = make_short4(v8[0], v8[1], v8[2], v8[3]);
    *(short4*)(op + 4) = make_short4(v8[4], v8[5], v8[6], v8[7]);
}

// ---------------- gather: one wave per dst; pipelined breadth-first 8-edge chunks ----------------
__global__ __launch_bounds__(256) void gather_k(const int* __restrict__ rowptr,
                                                const int* __restrict__ csr_src,
                                                const short* __restrict__ aleb,
                                                const float* __restrict__ aldst,
                                                const short* __restrict__ xsb,
                                                const float* __restrict__ b,
                                                short* __restrict__ houtb, int n) {
    int dst = blockIdx.x * 4 + (threadIdx.x >> 6);
    if (dst >= n) return;
    const int lane = threadIdx.x & 63;
    const int h = lane >> 3;
    const float L2E = 1.44269504f;
    int p0 = rowptr[dst], p1 = rowptr[dst + 1];
    float ald = aldst[dst * 8 + h];
    float den = 0.f, acc0 = 0.f, acc1 = 0.f;
    int p = p0;
    const int nfull = (p1 - p0) >> 3;
    int   sv  = 0;
    float alv = 0.f;
    if (nfull > 0) {                                         // prefetch chunk 0
        sv  = csr_src[p + (lane & 7)];
        alv = b2f_s(aleb[(size_t)p * 8 + lane]);
    }
    for (int c = 0; c < nfull; c++) {
        int csv = sv; float calv = alv;
        int pn = p + 8;
        if (c + 1 < nfull) {                                 // prefetch chunk c+1
            sv  = csr_src[pn + (lane & 7)];
            alv = b2f_s(aleb[(size_t)pn * 8 + lane]);
        }
        int s0 = __shfl(csv, 0), s1 = __shfl(csv, 1), s2 = __shfl(csv, 2), s3 = __shfl(csv, 3);
        int s4 = __shfl(csv, 4), s5 = __shfl(csv, 5), s6 = __shfl(csv, 6), s7 = __shfl(csv, 7);
        unsigned v0 = *(const unsigned*)(xsb + (size_t)s0 * 128 + lane * 2);
        unsigned v1 = *(const unsigned*)(xsb + (size_t)s1 * 128 + lane * 2);
        unsigned v2 = *(const unsigned*)(xsb + (size_t)s2 * 128 + lane * 2);
        unsigned v3 = *(const unsigned*)(xsb + (size_t)s3 * 128 + lane * 2);
        unsigned v4 = *(const unsigned*)(xsb + (size_t)s4 * 128 + lane * 2);
        unsigned v5 = *(const unsigned*)(xsb + (size_t)s5 * 128 + lane * 2);
        unsigned v6 = *(const unsigned*)(xsb + (size_t)s6 * 128 + lane * 2);
        unsigned v7 = *(const unsigned*)(xsb + (size_t)s7 * 128 + lane * 2);
        unsigned vv[8] = {v0, v1, v2, v3, v4, v5, v6, v7};
#pragma unroll
        for (int i = 0; i < 8; i++) {
            float al = __shfl(calv, i * 8 + h);
            float lg = al + ald; lg = lg > 0.f ? lg : 0.2f * lg;
            float ex = exp2f(lg * L2E);
            den  += ex;
            acc0 += b2f_lo(vv[i]) * ex;
            acc1 += b2f_hi(vv[i]) * ex;
        }
        p = pn;
    }
    for (; p + 1 < p1; p += 2) {
        int s0 = csr_src[p];
        int s1 = csr_src[p + 1];
        float al0 = b2f_s(aleb[(size_t)p * 8 + h]);
        float al1 = b2f_s(aleb[(size_t)(p + 1) * 8 + h]);
        unsigned v0 = *(const unsigned*)(xsb + (size_t)s0 * 128 + lane * 2);
        unsigned v1 = *(const unsigned*)(xsb + (size_t)s1 * 128 + lane * 2);
        float lg0 = al0 + ald; lg0 = lg0 > 0.f ? lg0 : 0.2f * lg0;
        float lg1 = al1 + ald; lg1 = lg1 > 0.f ? lg1 : 0.2f * lg1;
        float ex0 = exp2f(lg0 * L2E);
        float ex1 = exp2f(lg1 * L2E);
        den  += ex0 + ex1;
        acc0 += b2f_lo(v0) * ex0 + b2f_lo(v1) * ex1;
        acc1 += b2f_hi(v0) * ex0 + b2f_hi(v1) * ex1;
    }
    if (p < p1) {
        int s0 = csr_src[p];
        float al0 = b2f_s(aleb[(size_t)p * 8 + h]);
        unsigned v0 = *(const unsigned*)(xsb + (size_t)s0 * 128 + lane * 2);
        float lg0 = al0 + ald; lg0 = lg0 > 0.f ? lg0 : 0.2f * lg0;
        float ex0 = exp2f(lg0 * L2E);
        den  += ex0;
        acc0 += b2f_lo(v0) * ex0;
        acc1 += b2f_hi(v0) * ex0;
    }
    float inv = 1.f / (den + 1e-16f);
    const float2 bb = *(const float2*)(b + lane * 2);
    unsigned o = pack2(f2b(acc0 * inv + bb.x), f2b(acc1 * inv + bb.y));
    *(unsigned*)(houtb + (size_t)dst * 128 + lane * 2) = o;
}

// ---------------- global add pool (bf16 input, f32 atomics) ----------------
__global__ void pool_k(const short* __restrict__ h3b, const int* __restrict__ batch,
                       float* __restrict__ pool, int n) {
    int t = blockIdx.x * blockDim.x + threadIdx.x;
    if (t >= n * 128) return;
    int node = t >> 7, j = t & 127;
    atomicAdd(pool + (size_t)batch[node] * 128 + j, b2f_s(h3b[t]));
}

// ---------------- Wl1 [512(k),512(c)] f32 -> Wl1T [c][k] bf16 ----------------
__global__ void wl1t_k(const float* __restrict__ Wl1, short* __restrict__ Wl1T) {
    int idx = blockIdx.x * blockDim.x + threadIdx.x;   // 262144
    int k = idx >> 9, c = idx & 511;
    Wl1T[(size_t)c * 512 + k] = f2b(Wl1[idx]);
}

__global__ void init_out(float* __restrict__ out, const float* __restrict__ bl2, int n) {
    int t = blockIdx.x * blockDim.x + threadIdx.x;
    if (t < n) out[t] = bl2[0];
}

// ---------------- fused final MLP via bf16 MFMA: safe 2-phase double-buffer ----------------
__global__ __launch_bounds__(256) void final_mfma(
    const short* __restrict__ h1, const short* __restrict__ h2,
    const short* __restrict__ h3, const short* __restrict__ poolb,
    const int* __restrict__ batch, const short* __restrict__ Wl1T,
    const float* __restrict__ bl1, const float* __restrict__ Wl2,
    float* __restrict__ out, int nrows)
{
    __shared__ short Abuf[2][4 * 64 * 8];   // 2 x 4 KB: [buf][sq][row][8]
    __shared__ int   sBatch[64];
    const int tid = threadIdx.x;
    const int n0 = blockIdx.x * 64;
    const int j0 = blockIdx.y * 256;
    const int wid = tid >> 6, lane = tid & 63;
    const int lr = lane & 15, kg = lane >> 4;

    if (tid < 64) {
        int gr = n0 + tid;
        sBatch[tid] = (gr < nrows) ? batch[gr] : 0;
    }
    __syncthreads();

    const short* seg_base[4] = {h1, h2, h3, poolb};

    auto STAGE = [&](int t) {
        const int k0 = t * 32;
        const int seg = k0 >> 7;
        const short* base = seg_base[seg];
        const int cseg = k0 & 127;
        int gr = n0 + lane;
        int grow = (seg == 3) ? sBatch[lane] : ((gr < nrows) ? gr : 0);
        const short* src = base + (size_t)grow * 128 + cseg + wid * 8;
#if __has_builtin(__builtin_amdgcn_global_load_lds)
        __builtin_amdgcn_global_load_lds(
            (const __attribute__((address_space(1))) unsigned int*)src,
            (__attribute__((address_space(3))) unsigned int*)&Abuf[t & 1][(wid * 64 + lane) * 8],
            16, 0, 0);
#else
        uint4 v = *(const uint4*)src;
        *(uint4*)(&Abuf[t & 1][(wid * 64 + lane) * 8]) = v;
#endif
    };
    auto LOADB = [&](int t, bf16x8* bb) {
        const int k0 = t * 32;
#pragma unroll
        for (int fn = 0; fn < 4; fn++)
            bb[fn] = *(const bf16x8*)(Wl1T + (size_t)(j0 + wid * 64 + fn * 16 + lr) * 512
                                      + k0 + kg * 8);
    };

    f32x4 acc[4][4] = {};
    bf16x8 bc[4], bn[4];

    STAGE(0);
    LOADB(0, bc);
    __syncthreads();   // stage 0 landed (full drain)
#pragma unroll
    for (int t = 0; t < 16; t++) {
        if (t < 15) {
            STAGE(t + 1);      // hides under this iter's compute
            LOADB(t + 1, bn);
        }
        bf16x8 a[4];
#pragma unroll
        for (int fm = 0; fm < 4; fm++)
            a[fm] = *(const bf16x8*)(&Abuf[t & 1][(kg * 64 + fm * 16 + lr) * 8]);
#pragma unroll
        for (int fm = 0; fm < 4; fm++)
#pragma unroll
            for (int fn = 0; fn < 4; fn++)
                acc[fm][fn] = __builtin_amdgcn_mfma_f32_16x16x32_bf16(
                    a[fm], bc[fn], acc[fm][fn], 0, 0, 0);
        if (t < 15) {
            __syncthreads();
#pragma unroll
            for (int fn = 0; fn < 4; fn++) bc[fn] = bn[fn];
        }
    }

    float w2[4], b1c[4];
#pragma unroll
    for (int fn = 0; fn < 4; fn++) {
        int c = j0 + wid * 64 + fn * 16 + lr;
        w2[fn]  = Wl2[c];
        b1c[fn] = bl1[c];
    }

#pragma unroll
    for (int fm = 0; fm < 4; fm++) {
#pragma unroll
        for (int r = 0; r < 4; r++) {
            float s = 0.f;
#pragma unroll
            for (int fn = 0; fn < 4; fn++) {
                float z = acc[fm][fn][r] + b1c[fn];
                z = z > 0.f ? z : 0.01f * z;
                s += z * w2[fn];
            }
            s += __shfl_xor(s, 1);
            s += __shfl_xor(s, 2);
            s += __shfl_xor(s, 4);
            s += __shfl_xor(s, 8);
            if (lr == 0) {
                int gr = n0 + fm * 16 + kg * 4 + r;
                if (gr < nrows) atomicAdd(out + gr, s);
            }
        }
    }
}

extern "C" void kernel_launch(void* const* d_in, const int* in_sizes, int n_in,
                              void* d_out, int out_size, void* d_ws, size_t ws_size,
                              hipStream_t stream) {
    const float* x     = (const float*)d_in[0];
    const int*   ei    = (const int*)d_in[1];
    const float* eattr = (const float*)d_in[2];
    const int*   batch = (const int*)d_in[3];
    const float* W[3]   = {(const float*)d_in[4],  (const float*)d_in[10], (const float*)d_in[16]};
    const float* We[3]  = {(const float*)d_in[5],  (const float*)d_in[11], (const float*)d_in[17]};
    const float* as_[3] = {(const float*)d_in[6],  (const float*)d_in[12], (const float*)d_in[18]};
    const float* ad_[3] = {(const float*)d_in[7],  (const float*)d_in[13], (const float*)d_in[19]};
    const float* ae_[3] = {(const float*)d_in[8],  (const float*)d_in[14], (const float*)d_in[20]};
    const float* b_[3]  = {(const float*)d_in[9],  (const float*)d_in[15], (const float*)d_in[21]};
    const float* Wl1 = (const float*)d_in[22];
    const float* bl1 = (const float*)d_in[23];
    const float* Wl2 = (const float*)d_in[24];
    const float* bl2 = (const float*)d_in[25];

    const int N = N_NODES, E = N_EDGES, G = N_GRAPH;

    float* ws    = (float*)d_ws;
    float* alsrc = ws;                          // N*8
    float* aldst = alsrc + (size_t)N * 8;       // N*8
    float* pool  = aldst + (size_t)N * 8;       // G*128
    short* xb    = (short*)(pool + (size_t)G * 128);   // N*128 bf16 (input x)
    short* xsb   = xb + (size_t)N * 128;        // N*128 bf16 (layer GEMM out)
    short* hb0   = xsb + (size_t)N * 128;       // N*128 bf16
    short* hb1   = hb0 + (size_t)N * 128;
    short* hb2   = hb1 + (size_t)N * 128;
    short* hb[3] = {hb0, hb1, hb2};
    short* poolb = hb2 + (size_t)N * 128;       // G*128 bf16
    short* wbt0  = poolb + (size_t)G * 128;     // 3 x 128*128 bf16
    short* wbt1  = wbt0 + 16384;
    short* wbt2  = wbt1 + 16384;
    short* wbt[3] = {wbt0, wbt1, wbt2};
    short* wl1t  = wbt2 + 16384;                // 512*512 bf16
    short* aleb  = wl1t + 262144;               // E*8 bf16
    int*   cnt     = (int*)(aleb + (size_t)E * 8);  // N
    int*   rowptr  = cnt + N;                   // N+1
    int*   cursor  = rowptr + N + 1;            // N
    int*   part    = cursor + N;                // 256
    int*   pos     = part + 256;                // E
    int*   csr_src = pos + E;                   // E

    // ---- once per call: bf16 conversions + dst-CSR ----
    f2b_bulk<<<(N * 32 + 255) / 256, 256, 0, stream>>>(x, xb, N * 32);
    for (int l = 0; l < 3; l++)
        wbt_k<<<64, 256, 0, stream>>>(W[l], wbt[l]);
    wl1t_k<<<1024, 256, 0, stream>>>(Wl1, wl1t);
    hipMemsetAsync(cnt, 0, (size_t)N * sizeof(int), stream);
    hist_k<<<(E + 255) / 256, 256, 0, stream>>>(ei, cnt, E);
    const int nblk = (N + 255) / 256;   // 196
    scan1_k<<<nblk, 256, 0, stream>>>(cnt, rowptr, part, N);
    scan2_k<<<1, 256, 0, stream>>>(part, nblk);
    scan3_k<<<nblk, 256, 0, stream>>>(rowptr, part, cursor, N, E);
    scatter_k<<<(E + 255) / 256, 256, 0, stream>>>(ei, cursor, pos, csr_src, E);

    for (int l = 0; l < 3; l++) {
        const short* Ain = (l == 0) ? xb : hb[l - 1];
        gemm_mfma<<<(N + 63) / 64, 256, 0, stream>>>(Ain, wbt[l], xsb, N);
        node_al<<<(N * 8 + 255) / 256, 256, 0, stream>>>(xsb, as_[l], ad_[l], alsrc, aldst, N);
        ale_k<<<(E + 255) / 256, 256, 0, stream>>>(ei, eattr, alsrc, We[l], ae_[l],
                                                   pos, aleb, E);
        gather_k<<<(N + 3) / 4, 256, 0, stream>>>(rowptr, csr_src, aleb, aldst, xsb,
                                                  b_[l], hb[l], N);
    }
    hipMemsetAsync(pool, 0, (size_t)G * 128 * sizeof(float), stream);
    pool_k<<<(N * 128 + 255) / 256, 256, 0, stream>>>(hb[2], batch, pool, N);
    f2b_bulk<<<(G * 32 + 255) / 256, 256, 0, stream>>>(pool, poolb, G * 32);

    init_out<<<(N + 255) / 256, 256, 0, stream>>>((float*)d_out, bl2, N);
    dim3 fg((N + 63) / 64, 2);
    final_mfma<<<fg, 256, 0, stream>>>(hb[0], hb[1], hb[2], poolb, batch,
                                       wl1t, bl1, Wl2, (float*)d_out, N);
}

// Round 14
// 453.739 us; speedup vs baseline: 1.3257x; 1.0627x over previous
//
#include <hip/hip_runtime.h>

#define N_NODES 50000
#define N_EDGES 800000
#define N_GRAPH 1000
#define EPAD (N_EDGES + 8 * N_NODES)   // padded CSR capacity

typedef short bf16x8 __attribute__((ext_vector_type(8)));
typedef float f32x4 __attribute__((ext_vector_type(4)));

__device__ inline short f2b(float f) {   // f32 -> bf16 (RNE)
    union { float f; unsigned u; } x; x.f = f;
    unsigned r = x.u + 0x7FFF + ((x.u >> 16) & 1);
    return (short)(r >> 16);
}
__device__ inline float b2f_lo(unsigned v) {
    union { unsigned u; float f; } x; x.u = v << 16; return x.f;
}
__device__ inline float b2f_hi(unsigned v) {
    union { unsigned u; float f; } x; x.u = v & 0xFFFF0000u; return x.f;
}
__device__ inline float b2f_s(short s) {
    union { unsigned u; float f; } x; x.u = ((unsigned)(unsigned short)s) << 16; return x.f;
}
__device__ inline unsigned pack2(short lo, short hi) {
    return ((unsigned)(unsigned short)lo) | (((unsigned)(unsigned short)hi) << 16);
}

// ---------------- f32 -> bf16 bulk convert (vectorized) ----------------
__global__ void f2b_bulk(const float* __restrict__ in, short* __restrict__ out, int n4) {
    int t = blockIdx.x * blockDim.x + threadIdx.x;
    if (t >= n4) return;
    float4 v = *(const float4*)(in + (size_t)t * 4);
    *(short4*)(out + (size_t)t * 4) = make_short4(f2b(v.x), f2b(v.y), f2b(v.z), f2b(v.w));
}

// ---------------- W[128(k)][128(c)] f32 -> WbT[c][k] bf16 ----------------
__global__ void wbt_k(const float* __restrict__ W, short* __restrict__ WbT) {
    int idx = blockIdx.x * blockDim.x + threadIdx.x;   // 16384
    int k = idx >> 7, c = idx & 127;
    WbT[(size_t)c * 128 + k] = f2b(W[idx]);
}

// ---------------- layer GEMM via MFMA: no LDS, no barriers; bf16 out only ----------------
__global__ __launch_bounds__(256) void gemm_mfma(const short* __restrict__ Ab,
                                                 const short* __restrict__ WbT,
                                                 short* __restrict__ outb, int nrows) {
    const int tid = threadIdx.x;
    const int n0 = blockIdx.x * 64;
    const int wid = tid >> 6, lane = tid & 63;
    const int lr = lane & 15, kg = lane >> 4;
    const int wr = (wid >> 1) * 32;    // wave row offset (0/32)
    const int wc = (wid & 1) * 64;     // wave col offset (0/64)

    f32x4 acc[2][4] = {};

#pragma unroll
    for (int ks = 0; ks < 4; ks++) {
        const int k0 = ks * 32;
        bf16x8 a[2], b[4];
#pragma unroll
        for (int fm = 0; fm < 2; fm++) {
            int gr = n0 + wr + fm * 16 + lr;
            bf16x8 v = {};
            if (gr < nrows) v = *(const bf16x8*)(Ab + (size_t)gr * 128 + k0 + kg * 8);
            a[fm] = v;
        }
#pragma unroll
        for (int fn = 0; fn < 4; fn++)
            b[fn] = *(const bf16x8*)(WbT + (size_t)(wc + fn * 16 + lr) * 128 + k0 + kg * 8);
#pragma unroll
        for (int fm = 0; fm < 2; fm++)
#pragma unroll
            for (int fn = 0; fn < 4; fn++)
                acc[fm][fn] = __builtin_amdgcn_mfma_f32_16x16x32_bf16(
                    a[fm], b[fn], acc[fm][fn], 0, 0, 0);
    }
#pragma unroll
    for (int fm = 0; fm < 2; fm++) {
#pragma unroll
        for (int r = 0; r < 4; r++) {
            int gr = n0 + wr + fm * 16 + kg * 4 + r;
            if (gr < nrows) {
#pragma unroll
                for (int fn = 0; fn < 4; fn++) {
                    int col = wc + fn * 16 + lr;
                    outb[(size_t)gr * 128 + col] = f2b(acc[fm][fn][r]);
                }
            }
        }
    }
}

// ---------------- per-node attention coefficients (bf16 input) ----------------
__global__ void node_al(const short* __restrict__ xsb, const float* __restrict__ a_s,
                        const float* __restrict__ a_d, float* __restrict__ alsrc,
                        float* __restrict__ aldst, int n) {
    int t = blockIdx.x * blockDim.x + threadIdx.x;
    if (t >= n * 8) return;
    int node = t >> 3, h = t & 7;
    const short* xp = xsb + (size_t)node * 128 + h * 16;
    uint4 u0 = *(const uint4*)(xp);
    uint4 u1 = *(const uint4*)(xp + 8);
    unsigned w[8] = {u0.x, u0.y, u0.z, u0.w, u1.x, u1.y, u1.z, u1.w};
    float ss = 0.f, dd = 0.f;
#pragma unroll
    for (int q = 0; q < 8; q++) {
        float lo = b2f_lo(w[q]), hi = b2f_hi(w[q]);
        ss += lo * a_s[h * 16 + q * 2] + hi * a_s[h * 16 + q * 2 + 1];
        dd += lo * a_d[h * 16 + q * 2] + hi * a_d[h * 16 + q * 2 + 1];
    }
    alsrc[t] = ss;
    aldst[t] = dd;
}

// ---------------- CSR build (padded to multiples of 8 per dst) ----------------
__global__ void hist_k(const int* __restrict__ ei, int* __restrict__ cnt, int ne) {
    int e = blockIdx.x * blockDim.x + threadIdx.x;
    if (e < ne) atomicAdd(&cnt[ei[ne + e]], 1);
}

__global__ void scan1_k(const int* __restrict__ cnt, int* __restrict__ rowptr,
                        int* __restrict__ part, int n) {
    __shared__ int s[256];
    int tid = threadIdx.x;
    int i = blockIdx.x * 256 + tid;
    int v = (i < n) ? ((cnt[i] + 7) & ~7) : 0;   // padded count
    s[tid] = v; __syncthreads();
#pragma unroll
    for (int off = 1; off < 256; off <<= 1) {
        int t = (tid >= off) ? s[tid - off] : 0;
        __syncthreads();
        s[tid] += t;
        __syncthreads();
    }
    if (i < n) rowptr[i] = s[tid] - v;
    if (tid == 255) part[blockIdx.x] = s[255];
}

__global__ void scan2_k(int* __restrict__ part, int npart) {
    __shared__ int s[256];
    int tid = threadIdx.x;
    int v = (tid < npart) ? part[tid] : 0;
    s[tid] = v; __syncthreads();
#pragma unroll
    for (int off = 1; off < 256; off <<= 1) {
        int t = (tid >= off) ? s[tid - off] : 0;
        __syncthreads();
        s[tid] += t;
        __syncthreads();
    }
    if (tid < npart) part[tid] = s[tid] - v;
}

__global__ void scan3_k(int* __restrict__ rowptr, const int* __restrict__ part,
                        const int* __restrict__ cnt, int* __restrict__ cursor, int n) {
    int i = blockIdx.x * 256 + threadIdx.x;
    if (i < n) {
        int r = rowptr[i] + part[blockIdx.x];
        rowptr[i] = r;
        cursor[i] = r;
        if (i == n - 1) rowptr[n] = r + ((cnt[i] + 7) & ~7);
    }
}

// scatter: build csr_src + CSR-ordered bf16 edge attrs (pads remain 0x80808080 from memset)
__global__ void scatter_k(const int* __restrict__ ei, const float* __restrict__ eattr,
                          int* __restrict__ cursor, int* __restrict__ csr_src,
                          short* __restrict__ eatb, int ne) {
    int e = blockIdx.x * blockDim.x + threadIdx.x;
    if (e >= ne) return;
    int d = ei[ne + e];
    int p = atomicAdd(&cursor[d], 1);
    csr_src[p] = ei[e];
    const float4* ep = (const float4*)(eattr + (size_t)e * 16);
    short* op = eatb + (size_t)p * 16;
#pragma unroll
    for (int q = 0; q < 4; q++) {
        float4 v = ep[q];
        *(short4*)(op + q * 4) = make_short4(f2b(v.x), f2b(v.y), f2b(v.z), f2b(v.w));
    }
}

// ---------------- per-edge logits, CSR order, coalesced (pads -> -300) ----------------
__global__ __launch_bounds__(256) void ale_k(const int* __restrict__ csr_src,
                                             const short* __restrict__ eatb,
                                             const float* __restrict__ alsrc,
                                             const float* __restrict__ We,
                                             const float* __restrict__ ae,
                                             short* __restrict__ aleb, int ntot) {
    __shared__ float sAe[128];
    if (threadIdx.x < 128) {
        int k = threadIdx.x >> 3, h = threadIdx.x & 7;
        float s = 0.f;
#pragma unroll
        for (int c = 0; c < 16; c++) s += We[k * 128 + h * 16 + c] * ae[h * 16 + c];
        sAe[threadIdx.x] = s;   // [k*8+h]
    }
    __syncthreads();
    int e = blockIdx.x * blockDim.x + threadIdx.x;
    if (e >= ntot) return;
    int s = csr_src[e];
    short* op = aleb + (size_t)e * 8;
    if (s < 0) {   // pad slot
        short m = f2b(-300.f);
        *(short4*)(op)     = make_short4(m, m, m, m);
        *(short4*)(op + 4) = make_short4(m, m, m, m);
        return;
    }
    uint4 u0 = *(const uint4*)(eatb + (size_t)e * 16);
    uint4 u1 = *(const uint4*)(eatb + (size_t)e * 16 + 8);
    unsigned w[8] = {u0.x, u0.y, u0.z, u0.w, u1.x, u1.y, u1.z, u1.w};
    float ea[16];
#pragma unroll
    for (int q = 0; q < 8; q++) { ea[q * 2] = b2f_lo(w[q]); ea[q * 2 + 1] = b2f_hi(w[q]); }
    float out[8];
    const float4* ap = (const float4*)(alsrc + (size_t)s * 8);
    float4 a0 = ap[0], a1 = ap[1];
    out[0] = a0.x; out[1] = a0.y; out[2] = a0.z; out[3] = a0.w;
    out[4] = a1.x; out[5] = a1.y; out[6] = a1.z; out[7] = a1.w;
#pragma unroll
    for (int k = 0; k < 16; k++)
#pragma unroll
        for (int h = 0; h < 8; h++) out[h] += ea[k] * sAe[k * 8 + h];
    short v8[8];
#pragma unroll
    for (int h = 0; h < 8; h++) v8[h] = f2b(out[h]);
    *(short4*)(op)     = make_short4(v8[0], v8[1], v8[2], v8[3]);
    *(short4*)(op + 4) = make_short4(v8[4], v8[5], v8[6], v8[7]);
}

// ---------------- gather: one wave per dst; tail-free padded 8-edge chunks ----------------
__global__ __launch_bounds__(256) void gather_k(const int* __restrict__ rowptr,
                                                const int* __restrict__ csr_src,
                                                const short* __restrict__ aleb,
                                                const float* __restrict__ aldst,
                                                const short* __restrict__ xsb,
                                                const float* __restrict__ b,
                                                short* __restrict__ houtb, int n) {
    int dst = blockIdx.x * 4 + (threadIdx.x >> 6);
    if (dst >= n) return;
    const int lane = threadIdx.x & 63;
    const int h = lane >> 3;
    const float L2E = 1.44269504f;
    int p0 = rowptr[dst], p1 = rowptr[dst + 1];
    float ald = aldst[dst * 8 + h];
    float den = 0.f, acc0 = 0.f, acc1 = 0.f;
    const int nfull = (p1 - p0) >> 3;   // segment is padded: no tail
    int p = p0;
    int   sv  = 0;
    float alv = 0.f;
    if (nfull > 0) {
        sv  = csr_src[p + (lane & 7)];
        alv = b2f_s(aleb[(size_t)p * 8 + lane]);
    }
    for (int c = 0; c < nfull; c++) {
        int csv = sv; float calv = alv;
        int pn = p + 8;
        if (c + 1 < nfull) {
            sv  = csr_src[pn + (lane & 7)];
            alv = b2f_s(aleb[(size_t)pn * 8 + lane]);
        }
        int s0 = __shfl(csv, 0), s1 = __shfl(csv, 1), s2 = __shfl(csv, 2), s3 = __shfl(csv, 3);
        int s4 = __shfl(csv, 4), s5 = __shfl(csv, 5), s6 = __shfl(csv, 6), s7 = __shfl(csv, 7);
        s0 = s0 < 0 ? 0 : s0;  s1 = s1 < 0 ? 0 : s1;
        s2 = s2 < 0 ? 0 : s2;  s3 = s3 < 0 ? 0 : s3;
        s4 = s4 < 0 ? 0 : s4;  s5 = s5 < 0 ? 0 : s5;
        s6 = s6 < 0 ? 0 : s6;  s7 = s7 < 0 ? 0 : s7;
        unsigned v0 = *(const unsigned*)(xsb + (size_t)s0 * 128 + lane * 2);
        unsigned v1 = *(const unsigned*)(xsb + (size_t)s1 * 128 + lane * 2);
        unsigned v2 = *(const unsigned*)(xsb + (size_t)s2 * 128 + lane * 2);
        unsigned v3 = *(const unsigned*)(xsb + (size_t)s3 * 128 + lane * 2);
        unsigned v4 = *(const unsigned*)(xsb + (size_t)s4 * 128 + lane * 2);
        unsigned v5 = *(const unsigned*)(xsb + (size_t)s5 * 128 + lane * 2);
        unsigned v6 = *(const unsigned*)(xsb + (size_t)s6 * 128 + lane * 2);
        unsigned v7 = *(const unsigned*)(xsb + (size_t)s7 * 128 + lane * 2);
        unsigned vv[8] = {v0, v1, v2, v3, v4, v5, v6, v7};
#pragma unroll
        for (int i = 0; i < 8; i++) {
            float al = __shfl(calv, i * 8 + h);
            float lg = al + ald; lg = lg > 0.f ? lg : 0.2f * lg;
            float ex = exp2f(lg * L2E);
            den  += ex;
            acc0 += b2f_lo(vv[i]) * ex;
            acc1 += b2f_hi(vv[i]) * ex;
        }
        p = pn;
    }
    float inv = 1.f / (den + 1e-16f);
    const float2 bb = *(const float2*)(b + lane * 2);
    unsigned o = pack2(f2b(acc0 * inv + bb.x), f2b(acc1 * inv + bb.y));
    *(unsigned*)(houtb + (size_t)dst * 128 + lane * 2) = o;
}

// ---------------- global add pool (bf16 input, f32 atomics) ----------------
__global__ void pool_k(const short* __restrict__ h3b, const int* __restrict__ batch,
                       float* __restrict__ pool, int n) {
    int t = blockIdx.x * blockDim.x + threadIdx.x;
    if (t >= n * 128) return;
    int node = t >> 7, j = t & 127;
    atomicAdd(pool + (size_t)batch[node] * 128 + j, b2f_s(h3b[t]));
}

// ---------------- Wl1 [512(k),512(c)] f32 -> Wl1T [c][k] bf16 ----------------
__global__ void wl1t_k(const float* __restrict__ Wl1, short* __restrict__ Wl1T) {
    int idx = blockIdx.x * blockDim.x + threadIdx.x;   // 262144
    int k = idx >> 9, c = idx & 511;
    Wl1T[(size_t)c * 512 + k] = f2b(Wl1[idx]);
}

__global__ void init_out(float* __restrict__ out, const float* __restrict__ bl2, int n) {
    int t = blockIdx.x * blockDim.x + threadIdx.x;
    if (t < n) out[t] = bl2[0];
}

// ---------------- fused final MLP via bf16 MFMA: safe 2-phase double-buffer ----------------
__global__ __launch_bounds__(256) void final_mfma(
    const short* __restrict__ h1, const short* __restrict__ h2,
    const short* __restrict__ h3, const short* __restrict__ poolb,
    const int* __restrict__ batch, const short* __restrict__ Wl1T,
    const float* __restrict__ bl1, const float* __restrict__ Wl2,
    float* __restrict__ out, int nrows)
{
    __shared__ short Abuf[2][4 * 64 * 8];   // 2 x 4 KB: [buf][sq][row][8]
    __shared__ int   sBatch[64];
    const int tid = threadIdx.x;
    const int n0 = blockIdx.x * 64;
    const int j0 = blockIdx.y * 256;
    const int wid = tid >> 6, lane = tid & 63;
    const int lr = lane & 15, kg = lane >> 4;

    if (tid < 64) {
        int gr = n0 + tid;
        sBatch[tid] = (gr < nrows) ? batch[gr] : 0;
    }
    __syncthreads();

    const short* seg_base[4] = {h1, h2, h3, poolb};

    auto STAGE = [&](int t) {
        const int k0 = t * 32;
        const int seg = k0 >> 7;
        const short* base = seg_base[seg];
        const int cseg = k0 & 127;
        int gr = n0 + lane;
        int grow = (seg == 3) ? sBatch[lane] : ((gr < nrows) ? gr : 0);
        const short* src = base + (size_t)grow * 128 + cseg + wid * 8;
#if __has_builtin(__builtin_amdgcn_global_load_lds)
        __builtin_amdgcn_global_load_lds(
            (const __attribute__((address_space(1))) unsigned int*)src,
            (__attribute__((address_space(3))) unsigned int*)&Abuf[t & 1][(wid * 64 + lane) * 8],
            16, 0, 0);
#else
        uint4 v = *(const uint4*)src;
        *(uint4*)(&Abuf[t & 1][(wid * 64 + lane) * 8]) = v;
#endif
    };
    auto LOADB = [&](int t, bf16x8* bb) {
        const int k0 = t * 32;
#pragma unroll
        for (int fn = 0; fn < 4; fn++)
            bb[fn] = *(const bf16x8*)(Wl1T + (size_t)(j0 + wid * 64 + fn * 16 + lr) * 512
                                      + k0 + kg * 8);
    };

    f32x4 acc[4][4] = {};
    bf16x8 bc[4], bn[4];

    STAGE(0);
    LOADB(0, bc);
    __syncthreads();   // stage 0 landed (full drain)
#pragma unroll
    for (int t = 0; t < 16; t++) {
        if (t < 15) {
            STAGE(t + 1);      // hides under this iter's compute
            LOADB(t + 1, bn);
        }
        bf16x8 a[4];
#pragma unroll
        for (int fm = 0; fm < 4; fm++)
            a[fm] = *(const bf16x8*)(&Abuf[t & 1][(kg * 64 + fm * 16 + lr) * 8]);
#pragma unroll
        for (int fm = 0; fm < 4; fm++)
#pragma unroll
            for (int fn = 0; fn < 4; fn++)
                acc[fm][fn] = __builtin_amdgcn_mfma_f32_16x16x32_bf16(
                    a[fm], bc[fn], acc[fm][fn], 0, 0, 0);
        if (t < 15) {
            __syncthreads();
#pragma unroll
            for (int fn = 0; fn < 4; fn++) bc[fn] = bn[fn];
        }
    }

    float w2[4], b1c[4];
#pragma unroll
    for (int fn = 0; fn < 4; fn++) {
        int c = j0 + wid * 64 + fn * 16 + lr;
        w2[fn]  = Wl2[c];
        b1c[fn] = bl1[c];
    }

#pragma unroll
    for (int fm = 0; fm < 4; fm++) {
#pragma unroll
        for (int r = 0; r < 4; r++) {
            float s = 0.f;
#pragma unroll
            for (int fn = 0; fn < 4; fn++) {
                float z = acc[fm][fn][r] + b1c[fn];
                z = z > 0.f ? z : 0.01f * z;
                s += z * w2[fn];
            }
            s += __shfl_xor(s, 1);
            s += __shfl_xor(s, 2);
            s += __shfl_xor(s, 4);
            s += __shfl_xor(s, 8);
            if (lr == 0) {
                int gr = n0 + fm * 16 + kg * 4 + r;
                if (gr < nrows) atomicAdd(out + gr, s);
            }
        }
    }
}

extern "C" void kernel_launch(void* const* d_in, const int* in_sizes, int n_in,
                              void* d_out, int out_size, void* d_ws, size_t ws_size,
                              hipStream_t stream) {
    const float* x     = (const float*)d_in[0];
    const int*   ei    = (const int*)d_in[1];
    const float* eattr = (const float*)d_in[2];
    const int*   batch = (const int*)d_in[3];
    const float* W[3]   = {(const float*)d_in[4],  (const float*)d_in[10], (const float*)d_in[16]};
    const float* We[3]  = {(const float*)d_in[5],  (const float*)d_in[11], (const float*)d_in[17]};
    const float* as_[3] = {(const float*)d_in[6],  (const float*)d_in[12], (const float*)d_in[18]};
    const float* ad_[3] = {(const float*)d_in[7],  (const float*)d_in[13], (const float*)d_in[19]};
    const float* ae_[3] = {(const float*)d_in[8],  (const float*)d_in[14], (const float*)d_in[20]};
    const float* b_[3]  = {(const float*)d_in[9],  (const float*)d_in[15], (const float*)d_in[21]};
    const float* Wl1 = (const float*)d_in[22];
    const float* bl1 = (const float*)d_in[23];
    const float* Wl2 = (const float*)d_in[24];
    const float* bl2 = (const float*)d_in[25];

    const int N = N_NODES, E = N_EDGES, G = N_GRAPH;

    float* ws    = (float*)d_ws;
    float* alsrc = ws;                          // N*8
    float* aldst = alsrc + (size_t)N * 8;       // N*8
    float* pool  = aldst + (size_t)N * 8;       // G*128
    short* xb    = (short*)(pool + (size_t)G * 128);   // N*128 bf16
    short* xsb   = xb + (size_t)N * 128;        // N*128 bf16
    short* hb0   = xsb + (size_t)N * 128;       // N*128 bf16
    short* hb1   = hb0 + (size_t)N * 128;
    short* hb2   = hb1 + (size_t)N * 128;
    short* hb[3] = {hb0, hb1, hb2};
    short* poolb = hb2 + (size_t)N * 128;       // G*128 bf16
    short* wbt0  = poolb + (size_t)G * 128;     // 3 x 128*128 bf16
    short* wbt1  = wbt0 + 16384;
    short* wbt2  = wbt1 + 16384;
    short* wbt[3] = {wbt0, wbt1, wbt2};
    short* wl1t  = wbt2 + 16384;                // 512*512 bf16
    short* aleb  = wl1t + 262144;               // EPAD*8 bf16
    short* eatb  = aleb + (size_t)EPAD * 8;     // EPAD*16 bf16
    int*   cnt     = (int*)(eatb + (size_t)EPAD * 16);  // N
    int*   rowptr  = cnt + N;                   // N+1
    int*   cursor  = rowptr + N + 1;            // N
    int*   part    = cursor + N;                // 256
    int*   csr_src = part + 256;                // EPAD

    // ---- once per call: bf16 conversions + padded dst-CSR ----
    f2b_bulk<<<(N * 32 + 255) / 256, 256, 0, stream>>>(x, xb, N * 32);
    for (int l = 0; l < 3; l++)
        wbt_k<<<64, 256, 0, stream>>>(W[l], wbt[l]);
    wl1t_k<<<1024, 256, 0, stream>>>(Wl1, wl1t);
    hipMemsetAsync(cnt, 0, (size_t)N * sizeof(int), stream);
    hipMemsetAsync(csr_src, 0x80, (size_t)EPAD * sizeof(int), stream);  // pads negative
    hist_k<<<(E + 255) / 256, 256, 0, stream>>>(ei, cnt, E);
    const int nblk = (N + 255) / 256;   // 196
    scan1_k<<<nblk, 256, 0, stream>>>(cnt, rowptr, part, N);
    scan2_k<<<1, 256, 0, stream>>>(part, nblk);
    scan3_k<<<nblk, 256, 0, stream>>>(rowptr, part, cnt, cursor, N);
    scatter_k<<<(E + 255) / 256, 256, 0, stream>>>(ei, eattr, cursor, csr_src, eatb, E);

    const int aleGrid = (EPAD + 255) / 256;
    for (int l = 0; l < 3; l++) {
        const short* Ain = (l == 0) ? xb : hb[l - 1];
        gemm_mfma<<<(N + 63) / 64, 256, 0, stream>>>(Ain, wbt[l], xsb, N);
        node_al<<<(N * 8 + 255) / 256, 256, 0, stream>>>(xsb, as_[l], ad_[l], alsrc, aldst, N);
        ale_k<<<aleGrid, 256, 0, stream>>>(csr_src, eatb, alsrc, We[l], ae_[l], aleb, EPAD);
        gather_k<<<(N + 3) / 4, 256, 0, stream>>>(rowptr, csr_src, aleb, aldst, xsb,
                                                  b_[l], hb[l], N);
    }
    hipMemsetAsync(pool, 0, (size_t)G * 128 * sizeof(float), stream);
    pool_k<<<(N * 128 + 255) / 256, 256, 0, stream>>>(hb[2], batch, pool, N);
    f2b_bulk<<<(G * 32 + 255) / 256, 256, 0, stream>>>(pool, poolb, G * 32);

    init_out<<<(N + 255) / 256, 256, 0, stream>>>((float*)d_out, bl2, N);
    dim3 fg((N + 63) / 64, 2);
    final_mfma<<<fg, 256, 0, stream>>>(hb[0], hb[1], hb[2], poolb, batch,
                                       wl1t, bl1, Wl2, (float*)d_out, N);
}

// Round 15
// 435.300 us; speedup vs baseline: 1.3819x; 1.0424x over previous
//
#include <hip/hip_runtime.h>

#define N_NODES 50000
#define N_EDGES 800000
#define N_GRAPH 1000
#define EPAD (N_EDGES + 8 * N_NODES)   // padded CSR capacity

typedef short bf16x8 __attribute__((ext_vector_type(8)));
typedef float f32x4 __attribute__((ext_vector_type(4)));

__device__ inline short f2b(float f) {   // f32 -> bf16 (RNE)
    union { float f; unsigned u; } x; x.f = f;
    unsigned r = x.u + 0x7FFF + ((x.u >> 16) & 1);
    return (short)(r >> 16);
}
__device__ inline float b2f_lo(unsigned v) {
    union { unsigned u; float f; } x; x.u = v << 16; return x.f;
}
__device__ inline float b2f_hi(unsigned v) {
    union { unsigned u; float f; } x; x.u = v & 0xFFFF0000u; return x.f;
}
__device__ inline float b2f_s(short s) {
    union { unsigned u; float f; } x; x.u = ((unsigned)(unsigned short)s) << 16; return x.f;
}
__device__ inline unsigned pack2(short lo, short hi) {
    return ((unsigned)(unsigned short)lo) | (((unsigned)(unsigned short)hi) << 16);
}

// ---------------- f32 -> bf16 bulk convert (vectorized) ----------------
__global__ void f2b_bulk(const float* __restrict__ in, short* __restrict__ out, int n4) {
    int t = blockIdx.x * blockDim.x + threadIdx.x;
    if (t >= n4) return;
    float4 v = *(const float4*)(in + (size_t)t * 4);
    *(short4*)(out + (size_t)t * 4) = make_short4(f2b(v.x), f2b(v.y), f2b(v.z), f2b(v.w));
}

// ---------------- W[128(k)][128(c)] f32 -> WbT[c][k] bf16 ----------------
__global__ void wbt_k(const float* __restrict__ W, short* __restrict__ WbT) {
    int idx = blockIdx.x * blockDim.x + threadIdx.x;   // 16384
    int k = idx >> 7, c = idx & 127;
    WbT[(size_t)c * 128 + k] = f2b(W[idx]);
}

// ---------------- aeW for all 3 layers: aeW3[l][k*8+h] = sum_c We_l[k,h*16+c]*ae_l[h,c] ----------------
__global__ void aew3_k(const float* __restrict__ We0, const float* __restrict__ ae0,
                       const float* __restrict__ We1, const float* __restrict__ ae1,
                       const float* __restrict__ We2, const float* __restrict__ ae2,
                       float* __restrict__ aeW3) {
    const float* We = (blockIdx.x == 0) ? We0 : (blockIdx.x == 1) ? We1 : We2;
    const float* ae = (blockIdx.x == 0) ? ae0 : (blockIdx.x == 1) ? ae1 : ae2;
    int t = threadIdx.x;   // 128
    int k = t >> 3, h = t & 7;
    float s = 0.f;
#pragma unroll
    for (int c = 0; c < 16; c++) s += We[k * 128 + h * 16 + c] * ae[h * 16 + c];
    aeW3[blockIdx.x * 128 + t] = s;
}

// ---------------- layer GEMM via MFMA: no LDS, no barriers; bf16 out only ----------------
__global__ __launch_bounds__(256) void gemm_mfma(const short* __restrict__ Ab,
                                                 const short* __restrict__ WbT,
                                                 short* __restrict__ outb, int nrows) {
    const int tid = threadIdx.x;
    const int n0 = blockIdx.x * 64;
    const int wid = tid >> 6, lane = tid & 63;
    const int lr = lane & 15, kg = lane >> 4;
    const int wr = (wid >> 1) * 32;    // wave row offset (0/32)
    const int wc = (wid & 1) * 64;     // wave col offset (0/64)

    f32x4 acc[2][4] = {};

#pragma unroll
    for (int ks = 0; ks < 4; ks++) {
        const int k0 = ks * 32;
        bf16x8 a[2], b[4];
#pragma unroll
        for (int fm = 0; fm < 2; fm++) {
            int gr = n0 + wr + fm * 16 + lr;
            bf16x8 v = {};
            if (gr < nrows) v = *(const bf16x8*)(Ab + (size_t)gr * 128 + k0 + kg * 8);
            a[fm] = v;
        }
#pragma unroll
        for (int fn = 0; fn < 4; fn++)
            b[fn] = *(const bf16x8*)(WbT + (size_t)(wc + fn * 16 + lr) * 128 + k0 + kg * 8);
#pragma unroll
        for (int fm = 0; fm < 2; fm++)
#pragma unroll
            for (int fn = 0; fn < 4; fn++)
                acc[fm][fn] = __builtin_amdgcn_mfma_f32_16x16x32_bf16(
                    a[fm], b[fn], acc[fm][fn], 0, 0, 0);
    }
#pragma unroll
    for (int fm = 0; fm < 2; fm++) {
#pragma unroll
        for (int r = 0; r < 4; r++) {
            int gr = n0 + wr + fm * 16 + kg * 4 + r;
            if (gr < nrows) {
#pragma unroll
                for (int fn = 0; fn < 4; fn++) {
                    int col = wc + fn * 16 + lr;
                    outb[(size_t)gr * 128 + col] = f2b(acc[fm][fn][r]);
                }
            }
        }
    }
}

// ---------------- per-node attention coefficients (bf16 input) ----------------
__global__ void node_al(const short* __restrict__ xsb, const float* __restrict__ a_s,
                        const float* __restrict__ a_d, float* __restrict__ alsrc,
                        float* __restrict__ aldst, int n) {
    int t = blockIdx.x * blockDim.x + threadIdx.x;
    if (t >= n * 8) return;
    int node = t >> 3, h = t & 7;
    const short* xp = xsb + (size_t)node * 128 + h * 16;
    uint4 u0 = *(const uint4*)(xp);
    uint4 u1 = *(const uint4*)(xp + 8);
    unsigned w[8] = {u0.x, u0.y, u0.z, u0.w, u1.x, u1.y, u1.z, u1.w};
    float ss = 0.f, dd = 0.f;
#pragma unroll
    for (int q = 0; q < 8; q++) {
        float lo = b2f_lo(w[q]), hi = b2f_hi(w[q]);
        ss += lo * a_s[h * 16 + q * 2] + hi * a_s[h * 16 + q * 2 + 1];
        dd += lo * a_d[h * 16 + q * 2] + hi * a_d[h * 16 + q * 2 + 1];
    }
    alsrc[t] = ss;
    aldst[t] = dd;
}

// ---------------- CSR build (padded to multiples of 8 per dst) ----------------
__global__ void hist_k(const int* __restrict__ ei, int* __restrict__ cnt, int ne) {
    int e = blockIdx.x * blockDim.x + threadIdx.x;
    if (e < ne) atomicAdd(&cnt[ei[ne + e]], 1);
}

__global__ void scan1_k(const int* __restrict__ cnt, int* __restrict__ rowptr,
                        int* __restrict__ part, int n) {
    __shared__ int s[256];
    int tid = threadIdx.x;
    int i = blockIdx.x * 256 + tid;
    int v = (i < n) ? ((cnt[i] + 7) & ~7) : 0;   // padded count
    s[tid] = v; __syncthreads();
#pragma unroll
    for (int off = 1; off < 256; off <<= 1) {
        int t = (tid >= off) ? s[tid - off] : 0;
        __syncthreads();
        s[tid] += t;
        __syncthreads();
    }
    if (i < n) rowptr[i] = s[tid] - v;
    if (tid == 255) part[blockIdx.x] = s[255];
}

__global__ void scan2_k(int* __restrict__ part, int npart) {
    __shared__ int s[256];
    int tid = threadIdx.x;
    int v = (tid < npart) ? part[tid] : 0;
    s[tid] = v; __syncthreads();
#pragma unroll
    for (int off = 1; off < 256; off <<= 1) {
        int t = (tid >= off) ? s[tid - off] : 0;
        __syncthreads();
        s[tid] += t;
        __syncthreads();
    }
    if (tid < npart) part[tid] = s[tid] - v;
}

__global__ void scan3_k(int* __restrict__ rowptr, const int* __restrict__ part,
                        const int* __restrict__ cnt, int* __restrict__ cursor, int n) {
    int i = blockIdx.x * 256 + threadIdx.x;
    if (i < n) {
        int r = rowptr[i] + part[blockIdx.x];
        rowptr[i] = r;
        cursor[i] = r;
        if (i == n - 1) rowptr[n] = r + ((cnt[i] + 7) & ~7);
    }
}

// scatter: build csr_src + CSR-ordered bf16 edge attrs (pads remain 0x80808080 from memset)
__global__ void scatter_k(const int* __restrict__ ei, const float* __restrict__ eattr,
                          int* __restrict__ cursor, int* __restrict__ csr_src,
                          short* __restrict__ eatb, int ne) {
    int e = blockIdx.x * blockDim.x + threadIdx.x;
    if (e >= ne) return;
    int d = ei[ne + e];
    int p = atomicAdd(&cursor[d], 1);
    csr_src[p] = ei[e];
    const float4* ep = (const float4*)(eattr + (size_t)e * 16);
    short* op = eatb + (size_t)p * 16;
#pragma unroll
    for (int q = 0; q < 4; q++) {
        float4 v = ep[q];
        *(short4*)(op + q * 4) = make_short4(f2b(v.x), f2b(v.y), f2b(v.z), f2b(v.w));
    }
}

// ---------------- graph boundaries from sorted batch ----------------
__global__ void gbound_k(const int* __restrict__ batch, int* __restrict__ gb, int n, int g) {
    int i = blockIdx.x * 256 + threadIdx.x;
    if (i >= n) return;
    int b1 = batch[i];
    int b0 = (i == 0) ? -1 : batch[i - 1];
    for (int q = b0 + 1; q <= b1; q++) gb[q] = i;
    if (i == n - 1)
        for (int q = b1 + 1; q <= g; q++) gb[q] = n;
}

// ---------------- segmented pool: one block per graph (sorted batch), bf16 out ----------------
__global__ __launch_bounds__(256) void pools_k(const short* __restrict__ h3b,
                                               const int* __restrict__ gb,
                                               short* __restrict__ poolb) {
    __shared__ float red[128];
    int g = blockIdx.x;
    int c = threadIdx.x & 127;
    int par = threadIdx.x >> 7;   // 0/1
    int i0 = gb[g], i1 = gb[g + 1];
    float s = 0.f;
    for (int i = i0 + par; i < i1; i += 2) s += b2f_s(h3b[(size_t)i * 128 + c]);
    if (par == 1) red[c] = s;
    __syncthreads();
    if (par == 0) poolb[(size_t)g * 128 + c] = f2b(s + red[c]);
}

// ---------------- gather: fused logits + softmax-aggregate; padded 8-edge chunks ----------------
// producer role: lane = (edge pe=lane>>3, head ph=lane&7) computes pal = alsrc[src]+al_e
// consumer role: lane owns channels 2*lane,2*lane+1 (head h=lane>>3)
__global__ __launch_bounds__(256) void gather_k(const int* __restrict__ rowptr,
                                                const int* __restrict__ csr_src,
                                                const short* __restrict__ eatb,
                                                const float* __restrict__ aeW,
                                                const float* __restrict__ alsrc,
                                                const float* __restrict__ aldst,
                                                const short* __restrict__ xsb,
                                                const float* __restrict__ b,
                                                short* __restrict__ houtb, int n) {
    __shared__ float sAe[128];
    if (threadIdx.x < 128) sAe[threadIdx.x] = aeW[threadIdx.x];
    __syncthreads();
    int dst = blockIdx.x * 4 + (threadIdx.x >> 6);
    if (dst >= n) return;
    const int lane = threadIdx.x & 63;
    const int h  = lane >> 3;   // consumer head
    const int pe = lane >> 3;   // producer edge
    const int ph = lane & 7;    // producer head
    const float L2E = 1.44269504f;
    int p0 = rowptr[dst], p1 = rowptr[dst + 1];
    float ald = aldst[dst * 8 + h];
    float den = 0.f, acc0 = 0.f, acc1 = 0.f;
    const int nfull = (p1 - p0) >> 3;   // padded: no tail
    int p = p0;
    int svo = 0; unsigned w = 0;
    if (nfull > 0) {
        svo = csr_src[p + pe];
        w = *(const unsigned*)(eatb + (size_t)(p + pe) * 16 + ph * 2);
    }
    for (int c = 0; c < nfull; c++) {
        int csv = svo; unsigned cw = w;
        int pn = p + 8;
        if (c + 1 < nfull) {                         // prefetch next chunk
            svo = csr_src[pn + pe];
            w = *(const unsigned*)(eatb + (size_t)(pn + pe) * 16 + ph * 2);
        }
        // ---- producer: pal for (edge pe, head ph) ----
        int sc = csv < 0 ? 0 : csv;
        float pal = alsrc[sc * 8 + ph];
#pragma unroll
        for (int k = 0; k < 8; k++) {
            unsigned u = __shfl(cw, pe * 8 + k);
            pal += b2f_lo(u) * sAe[k * 16 + ph] + b2f_hi(u) * sAe[k * 16 + 8 + ph];
        }
        if (csv < 0) pal = -300.f;
        // ---- rows ----
        int t0 = __shfl(csv, 0),  t1 = __shfl(csv, 8),  t2 = __shfl(csv, 16), t3 = __shfl(csv, 24);
        int t4 = __shfl(csv, 32), t5 = __shfl(csv, 40), t6 = __shfl(csv, 48), t7 = __shfl(csv, 56);
        t0 = t0 < 0 ? 0 : t0;  t1 = t1 < 0 ? 0 : t1;
        t2 = t2 < 0 ? 0 : t2;  t3 = t3 < 0 ? 0 : t3;
        t4 = t4 < 0 ? 0 : t4;  t5 = t5 < 0 ? 0 : t5;
        t6 = t6 < 0 ? 0 : t6;  t7 = t7 < 0 ? 0 : t7;
        unsigned v0 = *(const unsigned*)(xsb + (size_t)t0 * 128 + lane * 2);
        unsigned v1 = *(const unsigned*)(xsb + (size_t)t1 * 128 + lane * 2);
        unsigned v2 = *(const unsigned*)(xsb + (size_t)t2 * 128 + lane * 2);
        unsigned v3 = *(const unsigned*)(xsb + (size_t)t3 * 128 + lane * 2);
        unsigned v4 = *(const unsigned*)(xsb + (size_t)t4 * 128 + lane * 2);
        unsigned v5 = *(const unsigned*)(xsb + (size_t)t5 * 128 + lane * 2);
        unsigned v6 = *(const unsigned*)(xsb + (size_t)t6 * 128 + lane * 2);
        unsigned v7 = *(const unsigned*)(xsb + (size_t)t7 * 128 + lane * 2);
        unsigned vv[8] = {v0, v1, v2, v3, v4, v5, v6, v7};
        // ---- consumer: weighted accumulate ----
#pragma unroll
        for (int i = 0; i < 8; i++) {
            float al = __shfl(pal, i * 8 + h);
            float lg = al + ald; lg = lg > 0.f ? lg : 0.2f * lg;
            float ex = exp2f(lg * L2E);
            den  += ex;
            acc0 += b2f_lo(vv[i]) * ex;
            acc1 += b2f_hi(vv[i]) * ex;
        }
        p = pn;
    }
    float inv = 1.f / (den + 1e-16f);
    const float2 bb = *(const float2*)(b + lane * 2);
    unsigned o = pack2(f2b(acc0 * inv + bb.x), f2b(acc1 * inv + bb.y));
    *(unsigned*)(houtb + (size_t)dst * 128 + lane * 2) = o;
}

// ---------------- Wl1 [512(k),512(c)] f32 -> Wl1T [c][k] bf16 ----------------
__global__ void wl1t_k(const float* __restrict__ Wl1, short* __restrict__ Wl1T) {
    int idx = blockIdx.x * blockDim.x + threadIdx.x;   // 262144
    int k = idx >> 9, c = idx & 511;
    Wl1T[(size_t)c * 512 + k] = f2b(Wl1[idx]);
}

__global__ void init_out(float* __restrict__ out, const float* __restrict__ bl2, int n) {
    int t = blockIdx.x * blockDim.x + threadIdx.x;
    if (t < n) out[t] = bl2[0];
}

// ---------------- fused final MLP via bf16 MFMA: safe 2-phase double-buffer ----------------
__global__ __launch_bounds__(256) void final_mfma(
    const short* __restrict__ h1, const short* __restrict__ h2,
    const short* __restrict__ h3, const short* __restrict__ poolb,
    const int* __restrict__ batch, const short* __restrict__ Wl1T,
    const float* __restrict__ bl1, const float* __restrict__ Wl2,
    float* __restrict__ out, int nrows)
{
    __shared__ short Abuf[2][4 * 64 * 8];   // 2 x 4 KB: [buf][sq][row][8]
    __shared__ int   sBatch[64];
    const int tid = threadIdx.x;
    const int n0 = blockIdx.x * 64;
    const int j0 = blockIdx.y * 256;
    const int wid = tid >> 6, lane = tid & 63;
    const int lr = lane & 15, kg = lane >> 4;

    if (tid < 64) {
        int gr = n0 + tid;
        sBatch[tid] = (gr < nrows) ? batch[gr] : 0;
    }
    __syncthreads();

    const short* seg_base[4] = {h1, h2, h3, poolb};

    auto STAGE = [&](int t) {
        const int k0 = t * 32;
        const int seg = k0 >> 7;
        const short* base = seg_base[seg];
        const int cseg = k0 & 127;
        int gr = n0 + lane;
        int grow = (seg == 3) ? sBatch[lane] : ((gr < nrows) ? gr : 0);
        const short* src = base + (size_t)grow * 128 + cseg + wid * 8;
#if __has_builtin(__builtin_amdgcn_global_load_lds)
        __builtin_amdgcn_global_load_lds(
            (const __attribute__((address_space(1))) unsigned int*)src,
            (__attribute__((address_space(3))) unsigned int*)&Abuf[t & 1][(wid * 64 + lane) * 8],
            16, 0, 0);
#else
        uint4 v = *(const uint4*)src;
        *(uint4*)(&Abuf[t & 1][(wid * 64 + lane) * 8]) = v;
#endif
    };
    auto LOADB = [&](int t, bf16x8* bb) {
        const int k0 = t * 32;
#pragma unroll
        for (int fn = 0; fn < 4; fn++)
            bb[fn] = *(const bf16x8*)(Wl1T + (size_t)(j0 + wid * 64 + fn * 16 + lr) * 512
                                      + k0 + kg * 8);
    };

    f32x4 acc[4][4] = {};
    bf16x8 bc[4], bn[4];

    STAGE(0);
    LOADB(0, bc);
    __syncthreads();   // stage 0 landed (full drain)
#pragma unroll
    for (int t = 0; t < 16; t++) {
        if (t < 15) {
            STAGE(t + 1);      // hides under this iter's compute
            LOADB(t + 1, bn);
        }
        bf16x8 a[4];
#pragma unroll
        for (int fm = 0; fm < 4; fm++)
            a[fm] = *(const bf16x8*)(&Abuf[t & 1][(kg * 64 + fm * 16 + lr) * 8]);
#pragma unroll
        for (int fm = 0; fm < 4; fm++)
#pragma unroll
            for (int fn = 0; fn < 4; fn++)
                acc[fm][fn] = __builtin_amdgcn_mfma_f32_16x16x32_bf16(
                    a[fm], bc[fn], acc[fm][fn], 0, 0, 0);
        if (t < 15) {
            __syncthreads();
#pragma unroll
            for (int fn = 0; fn < 4; fn++) bc[fn] = bn[fn];
        }
    }

    float w2[4], b1c[4];
#pragma unroll
    for (int fn = 0; fn < 4; fn++) {
        int c = j0 + wid * 64 + fn * 16 + lr;
        w2[fn]  = Wl2[c];
        b1c[fn] = bl1[c];
    }

#pragma unroll
    for (int fm = 0; fm < 4; fm++) {
#pragma unroll
        for (int r = 0; r < 4; r++) {
            float s = 0.f;
#pragma unroll
            for (int fn = 0; fn < 4; fn++) {
                float z = acc[fm][fn][r] + b1c[fn];
                z = z > 0.f ? z : 0.01f * z;
                s += z * w2[fn];
            }
            s += __shfl_xor(s, 1);
            s += __shfl_xor(s, 2);
            s += __shfl_xor(s, 4);
            s += __shfl_xor(s, 8);
            if (lr == 0) {
                int gr = n0 + fm * 16 + kg * 4 + r;
                if (gr < nrows) atomicAdd(out + gr, s);
            }
        }
    }
}

extern "C" void kernel_launch(void* const* d_in, const int* in_sizes, int n_in,
                              void* d_out, int out_size, void* d_ws, size_t ws_size,
                              hipStream_t stream) {
    const float* x     = (const float*)d_in[0];
    const int*   ei    = (const int*)d_in[1];
    const float* eattr = (const float*)d_in[2];
    const int*   batch = (const int*)d_in[3];
    const float* W[3]   = {(const float*)d_in[4],  (const float*)d_in[10], (const float*)d_in[16]};
    const float* We[3]  = {(const float*)d_in[5],  (const float*)d_in[11], (const float*)d_in[17]};
    const float* as_[3] = {(const float*)d_in[6],  (const float*)d_in[12], (const float*)d_in[18]};
    const float* ad_[3] = {(const float*)d_in[7],  (const float*)d_in[13], (const float*)d_in[19]};
    const float* ae_[3] = {(const float*)d_in[8],  (const float*)d_in[14], (const float*)d_in[20]};
    const float* b_[3]  = {(const float*)d_in[9],  (const float*)d_in[15], (const float*)d_in[21]};
    const float* Wl1 = (const float*)d_in[22];
    const float* bl1 = (const float*)d_in[23];
    const float* Wl2 = (const float*)d_in[24];
    const float* bl2 = (const float*)d_in[25];

    const int N = N_NODES, E = N_EDGES, G = N_GRAPH;

    float* ws    = (float*)d_ws;
    float* alsrc = ws;                          // N*8
    float* aldst = alsrc + (size_t)N * 8;       // N*8
    float* aeW3  = aldst + (size_t)N * 8;       // 3*128
    short* xb    = (short*)(aeW3 + 384);        // N*128 bf16
    short* xsb   = xb + (size_t)N * 128;        // N*128 bf16
    short* hb0   = xsb + (size_t)N * 128;       // N*128 bf16
    short* hb1   = hb0 + (size_t)N * 128;
    short* hb2   = hb1 + (size_t)N * 128;
    short* hb[3] = {hb0, hb1, hb2};
    short* poolb = hb2 + (size_t)N * 128;       // G*128 bf16
    short* wbt0  = poolb + (size_t)G * 128;     // 3 x 128*128 bf16
    short* wbt1  = wbt0 + 16384;
    short* wbt2  = wbt1 + 16384;
    short* wbt[3] = {wbt0, wbt1, wbt2};
    short* wl1t  = wbt2 + 16384;                // 512*512 bf16
    short* eatb  = wl1t + 262144;               // EPAD*16 bf16
    int*   cnt     = (int*)(eatb + (size_t)EPAD * 16);  // N
    int*   rowptr  = cnt + N;                   // N+1
    int*   cursor  = rowptr + N + 1;            // N
    int*   part    = cursor + N;                // 256
    int*   gb      = part + 256;                // G+1
    int*   csr_src = gb + G + 1;                // EPAD

    // ---- once per call: bf16 conversions + padded dst-CSR + graph bounds ----
    f2b_bulk<<<(N * 32 + 255) / 256, 256, 0, stream>>>(x, xb, N * 32);
    for (int l = 0; l < 3; l++)
        wbt_k<<<64, 256, 0, stream>>>(W[l], wbt[l]);
    wl1t_k<<<1024, 256, 0, stream>>>(Wl1, wl1t);
    aew3_k<<<3, 128, 0, stream>>>(We[0], ae_[0], We[1], ae_[1], We[2], ae_[2], aeW3);
    hipMemsetAsync(cnt, 0, (size_t)N * sizeof(int), stream);
    hipMemsetAsync(csr_src, 0x80, (size_t)EPAD * sizeof(int), stream);  // pads negative
    hist_k<<<(E + 255) / 256, 256, 0, stream>>>(ei, cnt, E);
    const int nblk = (N + 255) / 256;   // 196
    scan1_k<<<nblk, 256, 0, stream>>>(cnt, rowptr, part, N);
    scan2_k<<<1, 256, 0, stream>>>(part, nblk);
    scan3_k<<<nblk, 256, 0, stream>>>(rowptr, part, cnt, cursor, N);
    scatter_k<<<(E + 255) / 256, 256, 0, stream>>>(ei, eattr, cursor, csr_src, eatb, E);
    gbound_k<<<nblk, 256, 0, stream>>>(batch, gb, N, G);

    for (int l = 0; l < 3; l++) {
        const short* Ain = (l == 0) ? xb : hb[l - 1];
        gemm_mfma<<<(N + 63) / 64, 256, 0, stream>>>(Ain, wbt[l], xsb, N);
        node_al<<<(N * 8 + 255) / 256, 256, 0, stream>>>(xsb, as_[l], ad_[l], alsrc, aldst, N);
        gather_k<<<(N + 3) / 4, 256, 0, stream>>>(rowptr, csr_src, eatb, aeW3 + l * 128,
                                                  alsrc, aldst, xsb, b_[l], hb[l], N);
    }
    pools_k<<<G, 256, 0, stream>>>(hb[2], gb, poolb);

    init_out<<<(N + 255) / 256, 256, 0, stream>>>((float*)d_out, bl2, N);
    dim3 fg((N + 63) / 64, 2);
    final_mfma<<<fg, 256, 0, stream>>>(hb[0], hb[1], hb[2], poolb, batch,
                                       wl1t, bl1, Wl2, (float*)d_out, N);
}

// Round 16
// 434.726 us; speedup vs baseline: 1.3837x; 1.0013x over previous
//
#include <hip/hip_runtime.h>

#define N_NODES 50000
#define N_EDGES 800000
#define N_GRAPH 1000
#define EPAD (N_EDGES + 8 * N_NODES)   // padded CSR capacity

typedef short bf16x8 __attribute__((ext_vector_type(8)));
typedef float f32x4 __attribute__((ext_vector_type(4)));

__device__ inline short f2b(float f) {   // f32 -> bf16 (RNE)
    union { float f; unsigned u; } x; x.f = f;
    unsigned r = x.u + 0x7FFF + ((x.u >> 16) & 1);
    return (short)(r >> 16);
}
__device__ inline float b2f_lo(unsigned v) {
    union { unsigned u; float f; } x; x.u = v << 16; return x.f;
}
__device__ inline float b2f_hi(unsigned v) {
    union { unsigned u; float f; } x; x.u = v & 0xFFFF0000u; return x.f;
}
__device__ inline float b2f_s(short s) {
    union { unsigned u; float f; } x; x.u = ((unsigned)(unsigned short)s) << 16; return x.f;
}
__device__ inline unsigned pack2(short lo, short hi) {
    return ((unsigned)(unsigned short)lo) | (((unsigned)(unsigned short)hi) << 16);
}

// ---------------- f32 -> bf16 bulk convert (vectorized) ----------------
__global__ void f2b_bulk(const float* __restrict__ in, short* __restrict__ out, int n4) {
    int t = blockIdx.x * blockDim.x + threadIdx.x;
    if (t >= n4) return;
    float4 v = *(const float4*)(in + (size_t)t * 4);
    *(short4*)(out + (size_t)t * 4) = make_short4(f2b(v.x), f2b(v.y), f2b(v.z), f2b(v.w));
}

// ---------------- W[128(k)][128(c)] f32 -> WbT[c][k] bf16 ----------------
__global__ void wbt_k(const float* __restrict__ W, short* __restrict__ WbT) {
    int idx = blockIdx.x * blockDim.x + threadIdx.x;   // 16384
    int k = idx >> 7, c = idx & 127;
    WbT[(size_t)c * 128 + k] = f2b(W[idx]);
}

// ---------------- aeW for all 3 layers ----------------
__global__ void aew3_k(const float* __restrict__ We0, const float* __restrict__ ae0,
                       const float* __restrict__ We1, const float* __restrict__ ae1,
                       const float* __restrict__ We2, const float* __restrict__ ae2,
                       float* __restrict__ aeW3) {
    const float* We = (blockIdx.x == 0) ? We0 : (blockIdx.x == 1) ? We1 : We2;
    const float* ae = (blockIdx.x == 0) ? ae0 : (blockIdx.x == 1) ? ae1 : ae2;
    int t = threadIdx.x;   // 128
    int k = t >> 3, h = t & 7;
    float s = 0.f;
#pragma unroll
    for (int c = 0; c < 16; c++) s += We[k * 128 + h * 16 + c] * ae[h * 16 + c];
    aeW3[blockIdx.x * 128 + t] = s;
}

// ---------------- layer GEMM via MFMA: no LDS, no barriers; bf16 out only ----------------
__global__ __launch_bounds__(256) void gemm_mfma(const short* __restrict__ Ab,
                                                 const short* __restrict__ WbT,
                                                 short* __restrict__ outb, int nrows) {
    const int tid = threadIdx.x;
    const int n0 = blockIdx.x * 64;
    const int wid = tid >> 6, lane = tid & 63;
    const int lr = lane & 15, kg = lane >> 4;
    const int wr = (wid >> 1) * 32;
    const int wc = (wid & 1) * 64;

    f32x4 acc[2][4] = {};

#pragma unroll
    for (int ks = 0; ks < 4; ks++) {
        const int k0 = ks * 32;
        bf16x8 a[2], b[4];
#pragma unroll
        for (int fm = 0; fm < 2; fm++) {
            int gr = n0 + wr + fm * 16 + lr;
            bf16x8 v = {};
            if (gr < nrows) v = *(const bf16x8*)(Ab + (size_t)gr * 128 + k0 + kg * 8);
            a[fm] = v;
        }
#pragma unroll
        for (int fn = 0; fn < 4; fn++)
            b[fn] = *(const bf16x8*)(WbT + (size_t)(wc + fn * 16 + lr) * 128 + k0 + kg * 8);
#pragma unroll
        for (int fm = 0; fm < 2; fm++)
#pragma unroll
            for (int fn = 0; fn < 4; fn++)
                acc[fm][fn] = __builtin_amdgcn_mfma_f32_16x16x32_bf16(
                    a[fm], b[fn], acc[fm][fn], 0, 0, 0);
    }
#pragma unroll
    for (int fm = 0; fm < 2; fm++) {
#pragma unroll
        for (int r = 0; r < 4; r++) {
            int gr = n0 + wr + fm * 16 + kg * 4 + r;
            if (gr < nrows) {
#pragma unroll
                for (int fn = 0; fn < 4; fn++) {
                    int col = wc + fn * 16 + lr;
                    outb[(size_t)gr * 128 + col] = f2b(acc[fm][fn][r]);
                }
            }
        }
    }
}

// ---------------- per-node attention coefficients (bf16 input) ----------------
__global__ void node_al(const short* __restrict__ xsb, const float* __restrict__ a_s,
                        const float* __restrict__ a_d, float* __restrict__ alsrc,
                        float* __restrict__ aldst, int n) {
    int t = blockIdx.x * blockDim.x + threadIdx.x;
    if (t >= n * 8) return;
    int node = t >> 3, h = t & 7;
    const short* xp = xsb + (size_t)node * 128 + h * 16;
    uint4 u0 = *(const uint4*)(xp);
    uint4 u1 = *(const uint4*)(xp + 8);
    unsigned w[8] = {u0.x, u0.y, u0.z, u0.w, u1.x, u1.y, u1.z, u1.w};
    float ss = 0.f, dd = 0.f;
#pragma unroll
    for (int q = 0; q < 8; q++) {
        float lo = b2f_lo(w[q]), hi = b2f_hi(w[q]);
        ss += lo * a_s[h * 16 + q * 2] + hi * a_s[h * 16 + q * 2 + 1];
        dd += lo * a_d[h * 16 + q * 2] + hi * a_d[h * 16 + q * 2 + 1];
    }
    alsrc[t] = ss;
    aldst[t] = dd;
}

// ---------------- CSR build (padded to multiples of 8 per dst) ----------------
__global__ void hist_k(const int* __restrict__ ei, int* __restrict__ cnt, int ne) {
    int e = blockIdx.x * blockDim.x + threadIdx.x;
    if (e < ne) atomicAdd(&cnt[ei[ne + e]], 1);
}

__global__ void scan1_k(const int* __restrict__ cnt, int* __restrict__ rowptr,
                        int* __restrict__ part, int n) {
    __shared__ int s[256];
    int tid = threadIdx.x;
    int i = blockIdx.x * 256 + tid;
    int v = (i < n) ? ((cnt[i] + 7) & ~7) : 0;   // padded count
    s[tid] = v; __syncthreads();
#pragma unroll
    for (int off = 1; off < 256; off <<= 1) {
        int t = (tid >= off) ? s[tid - off] : 0;
        __syncthreads();
        s[tid] += t;
        __syncthreads();
    }
    if (i < n) rowptr[i] = s[tid] - v;
    if (tid == 255) part[blockIdx.x] = s[255];
}

__global__ void scan2_k(int* __restrict__ part, int npart) {
    __shared__ int s[256];
    int tid = threadIdx.x;
    int v = (tid < npart) ? part[tid] : 0;
    s[tid] = v; __syncthreads();
#pragma unroll
    for (int off = 1; off < 256; off <<= 1) {
        int t = (tid >= off) ? s[tid - off] : 0;
        __syncthreads();
        s[tid] += t;
        __syncthreads();
    }
    if (tid < npart) part[tid] = s[tid] - v;
}

__global__ void scan3_k(int* __restrict__ rowptr, const int* __restrict__ part,
                        const int* __restrict__ cnt, int* __restrict__ cursor, int n) {
    int i = blockIdx.x * 256 + threadIdx.x;
    if (i < n) {
        int r = rowptr[i] + part[blockIdx.x];
        rowptr[i] = r;
        cursor[i] = r;
        if (i == n - 1) rowptr[n] = r + ((cnt[i] + 7) & ~7);
    }
}

// scatter: build csr_src + CSR-ordered bf16 edge attrs (pads remain 0x80808080 from memset)
__global__ void scatter_k(const int* __restrict__ ei, const float* __restrict__ eattr,
                          int* __restrict__ cursor, int* __restrict__ csr_src,
                          short* __restrict__ eatb, int ne) {
    int e = blockIdx.x * blockDim.x + threadIdx.x;
    if (e >= ne) return;
    int d = ei[ne + e];
    int p = atomicAdd(&cursor[d], 1);
    csr_src[p] = ei[e];
    const float4* ep = (const float4*)(eattr + (size_t)e * 16);
    short* op = eatb + (size_t)p * 16;
#pragma unroll
    for (int q = 0; q < 4; q++) {
        float4 v = ep[q];
        *(short4*)(op + q * 4) = make_short4(f2b(v.x), f2b(v.y), f2b(v.z), f2b(v.w));
    }
}

// ---------------- graph boundaries from sorted batch ----------------
__global__ void gbound_k(const int* __restrict__ batch, int* __restrict__ gb, int n, int g) {
    int i = blockIdx.x * 256 + threadIdx.x;
    if (i >= n) return;
    int b1 = batch[i];
    int b0 = (i == 0) ? -1 : batch[i - 1];
    for (int q = b0 + 1; q <= b1; q++) gb[q] = i;
    if (i == n - 1)
        for (int q = b1 + 1; q <= g; q++) gb[q] = n;
}

// ---------------- segmented pool: one block per graph (sorted batch), bf16 out ----------------
__global__ __launch_bounds__(256) void pools_k(const short* __restrict__ h3b,
                                               const int* __restrict__ gb,
                                               short* __restrict__ poolb) {
    __shared__ float red[128];
    int g = blockIdx.x;
    int c = threadIdx.x & 127;
    int par = threadIdx.x >> 7;   // 0/1
    int i0 = gb[g], i1 = gb[g + 1];
    float s = 0.f;
    for (int i = i0 + par; i < i1; i += 2) s += b2f_s(h3b[(size_t)i * 128 + c]);
    if (par == 1) red[c] = s;
    __syncthreads();
    if (par == 0) poolb[(size_t)g * 128 + c] = f2b(s + red[c]);
}

// ---------------- gather: fused logits + softmax-aggregate; padded 8-edge chunks ----------------
__global__ __launch_bounds__(256) void gather_k(const int* __restrict__ rowptr,
                                                const int* __restrict__ csr_src,
                                                const short* __restrict__ eatb,
                                                const float* __restrict__ aeW,
                                                const float* __restrict__ alsrc,
                                                const float* __restrict__ aldst,
                                                const short* __restrict__ xsb,
                                                const float* __restrict__ b,
                                                short* __restrict__ houtb, int n) {
    __shared__ float sAe[128];
    if (threadIdx.x < 128) sAe[threadIdx.x] = aeW[threadIdx.x];
    __syncthreads();
    int dst = blockIdx.x * 4 + (threadIdx.x >> 6);
    if (dst >= n) return;
    const int lane = threadIdx.x & 63;
    const int h  = lane >> 3;   // consumer head
    const int pe = lane >> 3;   // producer edge
    const int ph = lane & 7;    // producer head
    const float L2E = 1.44269504f;
    int p0 = rowptr[dst], p1 = rowptr[dst + 1];
    float ald = aldst[dst * 8 + h];
    float den = 0.f, acc0 = 0.f, acc1 = 0.f;
    const int nfull = (p1 - p0) >> 3;   // padded: no tail
    int p = p0;
    int svo = 0; unsigned w = 0;
    if (nfull > 0) {
        svo = csr_src[p + pe];
        w = *(const unsigned*)(eatb + (size_t)(p + pe) * 16 + ph * 2);
    }
    for (int c = 0; c < nfull; c++) {
        int csv = svo; unsigned cw = w;
        int pn = p + 8;
        if (c + 1 < nfull) {                         // prefetch next chunk
            svo = csr_src[pn + pe];
            w = *(const unsigned*)(eatb + (size_t)(pn + pe) * 16 + ph * 2);
        }
        // ---- producer: pal for (edge pe, head ph) ----
        int sc = csv < 0 ? 0 : csv;
        float pal = alsrc[sc * 8 + ph];
#pragma unroll
        for (int k = 0; k < 8; k++) {
            unsigned u = __shfl(cw, pe * 8 + k);
            pal += b2f_lo(u) * sAe[k * 16 + ph] + b2f_hi(u) * sAe[k * 16 + 8 + ph];
        }
        if (csv < 0) pal = -300.f;
        // ---- rows ----
        int t0 = __shfl(csv, 0),  t1 = __shfl(csv, 8),  t2 = __shfl(csv, 16), t3 = __shfl(csv, 24);
        int t4 = __shfl(csv, 32), t5 = __shfl(csv, 40), t6 = __shfl(csv, 48), t7 = __shfl(csv, 56);
        t0 = t0 < 0 ? 0 : t0;  t1 = t1 < 0 ? 0 : t1;
        t2 = t2 < 0 ? 0 : t2;  t3 = t3 < 0 ? 0 : t3;
        t4 = t4 < 0 ? 0 : t4;  t5 = t5 < 0 ? 0 : t5;
        t6 = t6 < 0 ? 0 : t6;  t7 = t7 < 0 ? 0 : t7;
        unsigned v0 = *(const unsigned*)(xsb + (size_t)t0 * 128 + lane * 2);
        unsigned v1 = *(const unsigned*)(xsb + (size_t)t1 * 128 + lane * 2);
        unsigned v2 = *(const unsigned*)(xsb + (size_t)t2 * 128 + lane * 2);
        unsigned v3 = *(const unsigned*)(xsb + (size_t)t3 * 128 + lane * 2);
        unsigned v4 = *(const unsigned*)(xsb + (size_t)t4 * 128 + lane * 2);
        unsigned v5 = *(const unsigned*)(xsb + (size_t)t5 * 128 + lane * 2);
        unsigned v6 = *(const unsigned*)(xsb + (size_t)t6 * 128 + lane * 2);
        unsigned v7 = *(const unsigned*)(xsb + (size_t)t7 * 128 + lane * 2);
        unsigned vv[8] = {v0, v1, v2, v3, v4, v5, v6, v7};
        // ---- consumer: weighted accumulate ----
#pragma unroll
        for (int i = 0; i < 8; i++) {
            float al = __shfl(pal, i * 8 + h);
            float lg = al + ald; lg = lg > 0.f ? lg : 0.2f * lg;
            float ex = exp2f(lg * L2E);
            den  += ex;
            acc0 += b2f_lo(vv[i]) * ex;
            acc1 += b2f_hi(vv[i]) * ex;
        }
        p = pn;
    }
    float inv = 1.f / (den + 1e-16f);
    const float2 bb = *(const float2*)(b + lane * 2);
    unsigned o = pack2(f2b(acc0 * inv + bb.x), f2b(acc1 * inv + bb.y));
    *(unsigned*)(houtb + (size_t)dst * 128 + lane * 2) = o;
}

// ---------------- Wl1 [512(k),512(c)] f32 -> Wl1T [c][k] bf16 ----------------
__global__ void wl1t_k(const float* __restrict__ Wl1, short* __restrict__ Wl1T) {
    int idx = blockIdx.x * blockDim.x + threadIdx.x;   // 262144
    int k = idx >> 9, c = idx & 511;
    Wl1T[(size_t)c * 512 + k] = f2b(Wl1[idx]);
}

__global__ void init_out(float* __restrict__ out, const float* __restrict__ bl2, int n) {
    int t = blockIdx.x * blockDim.x + threadIdx.x;
    if (t < n) out[t] = bl2[0];
}

// ---------------- fused final MLP via bf16 MFMA: BK=128 double-buffer ----------------
// Each outer iteration stages one full 128-k segment (= h1/h2/h3/pool) as 16 KB via
// global_load_lds, then runs 4 barrier-free sub-steps of {B-from-L2, ds_read A, 16 MFMA}.
// Barrier drains: 4 instead of 16 -> 4x less exposed HBM latency.
__global__ __launch_bounds__(256) void final_mfma(
    const short* __restrict__ h1, const short* __restrict__ h2,
    const short* __restrict__ h3, const short* __restrict__ poolb,
    const int* __restrict__ batch, const short* __restrict__ Wl1T,
    const float* __restrict__ bl1, const float* __restrict__ Wl2,
    float* __restrict__ out, int nrows)
{
    __shared__ short Abuf[2][16 * 64 * 8];   // 2 x 16 KB: [buf][slot][row-lane][8]
    __shared__ int   sBatch[64];
    const int tid = threadIdx.x;
    const int n0 = blockIdx.x * 64;
    const int j0 = blockIdx.y * 256;
    const int wid = tid >> 6, lane = tid & 63;
    const int lr = lane & 15, kg = lane >> 4;

    if (tid < 64) {
        int gr = n0 + tid;
        sBatch[tid] = (gr < nrows) ? batch[gr] : 0;
    }
    __syncthreads();

    const short* seg_base[4] = {h1, h2, h3, poolb};

    // stage segment t (128 k's, 16 KB) into Abuf[t&1]; slot (q*4+wid) holds cols q*32+wid*8
    auto STAGE = [&](int t) {
        const short* base = seg_base[t];
        int gr = n0 + lane;
        int grow = (t == 3) ? sBatch[lane] : ((gr < nrows) ? gr : 0);
        const short* rowp = base + (size_t)grow * 128;
#pragma unroll
        for (int q = 0; q < 4; q++) {
            const short* src = rowp + q * 32 + wid * 8;
#if __has_builtin(__builtin_amdgcn_global_load_lds)
            __builtin_amdgcn_global_load_lds(
                (const __attribute__((address_space(1))) unsigned int*)src,
                (__attribute__((address_space(3))) unsigned int*)
                    &Abuf[t & 1][((q * 4 + wid) * 64 + lane) * 8],
                16, 0, 0);
#else
            uint4 v = *(const uint4*)src;
            *(uint4*)(&Abuf[t & 1][((q * 4 + wid) * 64 + lane) * 8]) = v;
#endif
        }
    };

    f32x4 acc[4][4] = {};

    STAGE(0);
    __syncthreads();   // segment 0 landed (full drain)
#pragma unroll
    for (int t = 0; t < 4; t++) {
        if (t < 3) STAGE(t + 1);   // hides under this segment's 64 MFMAs
#pragma unroll
        for (int ks = 0; ks < 4; ks++) {
            bf16x8 a[4], b[4];
#pragma unroll
            for (int fn = 0; fn < 4; fn++)
                b[fn] = *(const bf16x8*)(Wl1T + (size_t)(j0 + wid * 64 + fn * 16 + lr) * 512
                                         + t * 128 + ks * 32 + kg * 8);
#pragma unroll
            for (int fm = 0; fm < 4; fm++)
                a[fm] = *(const bf16x8*)(&Abuf[t & 1][((ks * 4 + kg) * 64 + fm * 16 + lr) * 8]);
#pragma unroll
            for (int fm = 0; fm < 4; fm++)
#pragma unroll
                for (int fn = 0; fn < 4; fn++)
                    acc[fm][fn] = __builtin_amdgcn_mfma_f32_16x16x32_bf16(
                        a[fm], b[fn], acc[fm][fn], 0, 0, 0);
        }
        if (t < 3) __syncthreads();   // drains STAGE(t+1); buffer reads done
    }

    float w2[4], b1c[4];
#pragma unroll
    for (int fn = 0; fn < 4; fn++) {
        int c = j0 + wid * 64 + fn * 16 + lr;
        w2[fn]  = Wl2[c];
        b1c[fn] = bl1[c];
    }

#pragma unroll
    for (int fm = 0; fm < 4; fm++) {
#pragma unroll
        for (int r = 0; r < 4; r++) {
            float s = 0.f;
#pragma unroll
            for (int fn = 0; fn < 4; fn++) {
                float z = acc[fm][fn][r] + b1c[fn];
                z = z > 0.f ? z : 0.01f * z;
                s += z * w2[fn];
            }
            s += __shfl_xor(s, 1);
            s += __shfl_xor(s, 2);
            s += __shfl_xor(s, 4);
            s += __shfl_xor(s, 8);
            if (lr == 0) {
                int gr = n0 + fm * 16 + kg * 4 + r;
                if (gr < nrows) atomicAdd(out + gr, s);
            }
        }
    }
}

extern "C" void kernel_launch(void* const* d_in, const int* in_sizes, int n_in,
                              void* d_out, int out_size, void* d_ws, size_t ws_size,
                              hipStream_t stream) {
    const float* x     = (const float*)d_in[0];
    const int*   ei    = (const int*)d_in[1];
    const float* eattr = (const float*)d_in[2];
    const int*   batch = (const int*)d_in[3];
    const float* W[3]   = {(const float*)d_in[4],  (const float*)d_in[10], (const float*)d_in[16]};
    const float* We[3]  = {(const float*)d_in[5],  (const float*)d_in[11], (const float*)d_in[17]};
    const float* as_[3] = {(const float*)d_in[6],  (const float*)d_in[12], (const float*)d_in[18]};
    const float* ad_[3] = {(const float*)d_in[7],  (const float*)d_in[13], (const float*)d_in[19]};
    const float* ae_[3] = {(const float*)d_in[8],  (const float*)d_in[14], (const float*)d_in[20]};
    const float* b_[3]  = {(const float*)d_in[9],  (const float*)d_in[15], (const float*)d_in[21]};
    const float* Wl1 = (const float*)d_in[22];
    const float* bl1 = (const float*)d_in[23];
    const float* Wl2 = (const float*)d_in[24];
    const float* bl2 = (const float*)d_in[25];

    const int N = N_NODES, E = N_EDGES, G = N_GRAPH;

    float* ws    = (float*)d_ws;
    float* alsrc = ws;                          // N*8
    float* aldst = alsrc + (size_t)N * 8;       // N*8
    float* aeW3  = aldst + (size_t)N * 8;       // 3*128
    short* xb    = (short*)(aeW3 + 384);        // N*128 bf16
    short* xsb   = xb + (size_t)N * 128;        // N*128 bf16
    short* hb0   = xsb + (size_t)N * 128;       // N*128 bf16
    short* hb1   = hb0 + (size_t)N * 128;
    short* hb2   = hb1 + (size_t)N * 128;
    short* hb[3] = {hb0, hb1, hb2};
    short* poolb = hb2 + (size_t)N * 128;       // G*128 bf16
    short* wbt0  = poolb + (size_t)G * 128;     // 3 x 128*128 bf16
    short* wbt1  = wbt0 + 16384;
    short* wbt2  = wbt1 + 16384;
    short* wbt[3] = {wbt0, wbt1, wbt2};
    short* wl1t  = wbt2 + 16384;                // 512*512 bf16
    short* eatb  = wl1t + 262144;               // EPAD*16 bf16
    int*   cnt     = (int*)(eatb + (size_t)EPAD * 16);  // N
    int*   rowptr  = cnt + N;                   // N+1
    int*   cursor  = rowptr + N + 1;            // N
    int*   part    = cursor + N;                // 256
    int*   gb      = part + 256;                // G+1
    int*   csr_src = gb + G + 1;                // EPAD

    // ---- once per call: bf16 conversions + padded dst-CSR + graph bounds ----
    f2b_bulk<<<(N * 32 + 255) / 256, 256, 0, stream>>>(x, xb, N * 32);
    for (int l = 0; l < 3; l++)
        wbt_k<<<64, 256, 0, stream>>>(W[l], wbt[l]);
    wl1t_k<<<1024, 256, 0, stream>>>(Wl1, wl1t);
    aew3_k<<<3, 128, 0, stream>>>(We[0], ae_[0], We[1], ae_[1], We[2], ae_[2], aeW3);
    hipMemsetAsync(cnt, 0, (size_t)N * sizeof(int), stream);
    hipMemsetAsync(csr_src, 0x80, (size_t)EPAD * sizeof(int), stream);  // pads negative
    hist_k<<<(E + 255) / 256, 256, 0, stream>>>(ei, cnt, E);
    const int nblk = (N + 255) / 256;   // 196
    scan1_k<<<nblk, 256, 0, stream>>>(cnt, rowptr, part, N);
    scan2_k<<<1, 256, 0, stream>>>(part, nblk);
    scan3_k<<<nblk, 256, 0, stream>>>(rowptr, part, cnt, cursor, N);
    scatter_k<<<(E + 255) / 256, 256, 0, stream>>>(ei, eattr, cursor, csr_src, eatb, E);
    gbound_k<<<nblk, 256, 0, stream>>>(batch, gb, N, G);

    for (int l = 0; l < 3; l++) {
        const short* Ain = (l == 0) ? xb : hb[l - 1];
        gemm_mfma<<<(N + 63) / 64, 256, 0, stream>>>(Ain, wbt[l], xsb, N);
        node_al<<<(N * 8 + 255) / 256, 256, 0, stream>>>(xsb, as_[l], ad_[l], alsrc, aldst, N);
        gather_k<<<(N + 3) / 4, 256, 0, stream>>>(rowptr, csr_src, eatb, aeW3 + l * 128,
                                                  alsrc, aldst, xsb, b_[l], hb[l], N);
    }
    pools_k<<<G, 256, 0, stream>>>(hb[2], gb, poolb);

    init_out<<<(N + 255) / 256, 256, 0, stream>>>((float*)d_out, bl2, N);
    dim3 fg((N + 63) / 64, 2);
    final_mfma<<<fg, 256, 0, stream>>>(hb[0], hb[1], hb[2], poolb, batch,
                                       wl1t, bl1, Wl2, (float*)d_out, N);
}

// Round 17
// 405.195 us; speedup vs baseline: 1.4845x; 1.0729x over previous
//
#include <hip/hip_runtime.h>

#define N_NODES 50000
#define N_EDGES 800000
#define N_GRAPH 1000
#define EPAD (N_EDGES + 8 * N_NODES)   // padded CSR capacity

typedef short bf16x8 __attribute__((ext_vector_type(8)));
typedef float f32x4 __attribute__((ext_vector_type(4)));

__device__ inline short f2b(float f) {   // f32 -> bf16 (RNE)
    union { float f; unsigned u; } x; x.f = f;
    unsigned r = x.u + 0x7FFF + ((x.u >> 16) & 1);
    return (short)(r >> 16);
}
__device__ inline float b2f_lo(unsigned v) {
    union { unsigned u; float f; } x; x.u = v << 16; return x.f;
}
__device__ inline float b2f_hi(unsigned v) {
    union { unsigned u; float f; } x; x.u = v & 0xFFFF0000u; return x.f;
}
__device__ inline float b2f_s(short s) {
    union { unsigned u; float f; } x; x.u = ((unsigned)(unsigned short)s) << 16; return x.f;
}
__device__ inline unsigned pack2(short lo, short hi) {
    return ((unsigned)(unsigned short)lo) | (((unsigned)(unsigned short)hi) << 16);
}

// ---------------- W[128(k)][128(c)] f32 -> WbT[c][k] bf16 ----------------
__global__ void wbt_k(const float* __restrict__ W, short* __restrict__ WbT) {
    int idx = blockIdx.x * blockDim.x + threadIdx.x;   // 16384
    int k = idx >> 7, c = idx & 127;
    WbT[(size_t)c * 128 + k] = f2b(W[idx]);
}

// ---------------- aeW for all 3 layers ----------------
__global__ void aew3_k(const float* __restrict__ We0, const float* __restrict__ ae0,
                       const float* __restrict__ We1, const float* __restrict__ ae1,
                       const float* __restrict__ We2, const float* __restrict__ ae2,
                       float* __restrict__ aeW3) {
    const float* We = (blockIdx.x == 0) ? We0 : (blockIdx.x == 1) ? We1 : We2;
    const float* ae = (blockIdx.x == 0) ? ae0 : (blockIdx.x == 1) ? ae1 : ae2;
    int t = threadIdx.x;   // 128
    int k = t >> 3, h = t & 7;
    float s = 0.f;
#pragma unroll
    for (int c = 0; c < 16; c++) s += We[k * 128 + h * 16 + c] * ae[h * 16 + c];
    aeW3[blockIdx.x * 128 + t] = s;
}

// ---------------- layer GEMM via MFMA (A dtype templated); bf16 out ----------------
template <bool AF32>
__global__ __launch_bounds__(256) void gemm_mfma(const void* __restrict__ Aptr,
                                                 const short* __restrict__ WbT,
                                                 short* __restrict__ outb, int nrows) {
    const int tid = threadIdx.x;
    const int n0 = blockIdx.x * 64;
    const int wid = tid >> 6, lane = tid & 63;
    const int lr = lane & 15, kg = lane >> 4;
    const int wr = (wid >> 1) * 32;
    const int wc = (wid & 1) * 64;

    f32x4 acc[2][4] = {};

#pragma unroll
    for (int ks = 0; ks < 4; ks++) {
        const int k0 = ks * 32;
        bf16x8 a[2], b[4];
#pragma unroll
        for (int fm = 0; fm < 2; fm++) {
            int gr = n0 + wr + fm * 16 + lr;
            bf16x8 v = {};
            if (gr < nrows) {
                if (AF32) {
                    const float* ap = (const float*)Aptr + (size_t)gr * 128 + k0 + kg * 8;
                    float4 f0 = *(const float4*)(ap);
                    float4 f1 = *(const float4*)(ap + 4);
                    v[0] = f2b(f0.x); v[1] = f2b(f0.y); v[2] = f2b(f0.z); v[3] = f2b(f0.w);
                    v[4] = f2b(f1.x); v[5] = f2b(f1.y); v[6] = f2b(f1.z); v[7] = f2b(f1.w);
                } else {
                    v = *(const bf16x8*)((const short*)Aptr + (size_t)gr * 128 + k0 + kg * 8);
                }
            }
            a[fm] = v;
        }
#pragma unroll
        for (int fn = 0; fn < 4; fn++)
            b[fn] = *(const bf16x8*)(WbT + (size_t)(wc + fn * 16 + lr) * 128 + k0 + kg * 8);
#pragma unroll
        for (int fm = 0; fm < 2; fm++)
#pragma unroll
            for (int fn = 0; fn < 4; fn++)
                acc[fm][fn] = __builtin_amdgcn_mfma_f32_16x16x32_bf16(
                    a[fm], b[fn], acc[fm][fn], 0, 0, 0);
    }
#pragma unroll
    for (int fm = 0; fm < 2; fm++) {
#pragma unroll
        for (int r = 0; r < 4; r++) {
            int gr = n0 + wr + fm * 16 + kg * 4 + r;
            if (gr < nrows) {
#pragma unroll
                for (int fn = 0; fn < 4; fn++) {
                    int col = wc + fn * 16 + lr;
                    outb[(size_t)gr * 128 + col] = f2b(acc[fm][fn][r]);
                }
            }
        }
    }
}

// ---------------- per-node attention coefficients (bf16 input) ----------------
__global__ void node_al(const short* __restrict__ xsb, const float* __restrict__ a_s,
                        const float* __restrict__ a_d, float* __restrict__ alsrc,
                        float* __restrict__ aldst, int n) {
    int t = blockIdx.x * blockDim.x + threadIdx.x;
    if (t >= n * 8) return;
    int node = t >> 3, h = t & 7;
    const short* xp = xsb + (size_t)node * 128 + h * 16;
    uint4 u0 = *(const uint4*)(xp);
    uint4 u1 = *(const uint4*)(xp + 8);
    unsigned w[8] = {u0.x, u0.y, u0.z, u0.w, u1.x, u1.y, u1.z, u1.w};
    float ss = 0.f, dd = 0.f;
#pragma unroll
    for (int q = 0; q < 8; q++) {
        float lo = b2f_lo(w[q]), hi = b2f_hi(w[q]);
        ss += lo * a_s[h * 16 + q * 2] + hi * a_s[h * 16 + q * 2 + 1];
        dd += lo * a_d[h * 16 + q * 2] + hi * a_d[h * 16 + q * 2 + 1];
    }
    alsrc[t] = ss;
    aldst[t] = dd;
}

// ---------------- CSR build (padded to multiples of 8 per dst) ----------------
__global__ void hist_k(const int* __restrict__ ei, int* __restrict__ cnt, int ne) {
    int e = blockIdx.x * blockDim.x + threadIdx.x;
    if (e < ne) atomicAdd(&cnt[ei[ne + e]], 1);
}

__global__ void scan1_k(const int* __restrict__ cnt, int* __restrict__ rowptr,
                        int* __restrict__ part, int n) {
    __shared__ int s[256];
    int tid = threadIdx.x;
    int i = blockIdx.x * 256 + tid;
    int v = (i < n) ? ((cnt[i] + 7) & ~7) : 0;   // padded count
    s[tid] = v; __syncthreads();
#pragma unroll
    for (int off = 1; off < 256; off <<= 1) {
        int t = (tid >= off) ? s[tid - off] : 0;
        __syncthreads();
        s[tid] += t;
        __syncthreads();
    }
    if (i < n) rowptr[i] = s[tid] - v;
    if (tid == 255) part[blockIdx.x] = s[255];
}

__global__ void scan2_k(int* __restrict__ part, int npart) {
    __shared__ int s[256];
    int tid = threadIdx.x;
    int v = (tid < npart) ? part[tid] : 0;
    s[tid] = v; __syncthreads();
#pragma unroll
    for (int off = 1; off < 256; off <<= 1) {
        int t = (tid >= off) ? s[tid - off] : 0;
        __syncthreads();
        s[tid] += t;
        __syncthreads();
    }
    if (tid < npart) part[tid] = s[tid] - v;
}

__global__ void scan3_k(int* __restrict__ rowptr, const int* __restrict__ part,
                        const int* __restrict__ cnt, int* __restrict__ cursor, int n) {
    int i = blockIdx.x * 256 + threadIdx.x;
    if (i < n) {
        int r = rowptr[i] + part[blockIdx.x];
        rowptr[i] = r;
        cursor[i] = r;
        if (i == n - 1) rowptr[n] = r + ((cnt[i] + 7) & ~7);
    }
}

// scatter: build csr_src + CSR-ordered bf16 edge attrs (pads remain 0x80808080 from memset)
__global__ void scatter_k(const int* __restrict__ ei, const float* __restrict__ eattr,
                          int* __restrict__ cursor, int* __restrict__ csr_src,
                          short* __restrict__ eatb, int ne) {
    int e = blockIdx.x * blockDim.x + threadIdx.x;
    if (e >= ne) return;
    int d = ei[ne + e];
    int p = atomicAdd(&cursor[d], 1);
    csr_src[p] = ei[e];
    const float4* ep = (const float4*)(eattr + (size_t)e * 16);
    short* op = eatb + (size_t)p * 16;
#pragma unroll
    for (int q = 0; q < 4; q++) {
        float4 v = ep[q];
        *(short4*)(op + q * 4) = make_short4(f2b(v.x), f2b(v.y), f2b(v.z), f2b(v.w));
    }
}

// ---------------- graph boundaries from sorted batch ----------------
__global__ void gbound_k(const int* __restrict__ batch, int* __restrict__ gb, int n, int g) {
    int i = blockIdx.x * 256 + threadIdx.x;
    if (i >= n) return;
    int b1 = batch[i];
    int b0 = (i == 0) ? -1 : batch[i - 1];
    for (int q = b0 + 1; q <= b1; q++) gb[q] = i;
    if (i == n - 1)
        for (int q = b1 + 1; q <= g; q++) gb[q] = n;
}

// ---------------- segmented pool: one block per graph (sorted batch), bf16 out ----------------
__global__ __launch_bounds__(256) void pools_k(const short* __restrict__ h3b,
                                               const int* __restrict__ gb,
                                               short* __restrict__ poolb) {
    __shared__ float red[128];
    int g = blockIdx.x;
    int c = threadIdx.x & 127;
    int par = threadIdx.x >> 7;   // 0/1
    int i0 = gb[g], i1 = gb[g + 1];
    float s = 0.f;
    for (int i = i0 + par; i < i1; i += 2) s += b2f_s(h3b[(size_t)i * 128 + c]);
    if (par == 1) red[c] = s;
    __syncthreads();
    if (par == 0) poolb[(size_t)g * 128 + c] = f2b(s + red[c]);
}

// ---------------- gather: fused logits + softmax-aggregate; producer-side exp ----------------
// producer role: lane (pe=lane>>3, ph=lane&7) computes pex = exp(leaky(alsrc+al_e+aldst))
//                (pads -> pex = 0)
// consumer role: lane owns channels 2*lane,2*lane+1 (head h=lane>>3); shuffles ready pex
__global__ __launch_bounds__(256) void gather_k(const int* __restrict__ rowptr,
                                                const int* __restrict__ csr_src,
                                                const short* __restrict__ eatb,
                                                const float* __restrict__ aeW,
                                                const float* __restrict__ alsrc,
                                                const float* __restrict__ aldst,
                                                const short* __restrict__ xsb,
                                                const float* __restrict__ b,
                                                short* __restrict__ houtb, int n) {
    __shared__ float sAe[128];
    if (threadIdx.x < 128) sAe[threadIdx.x] = aeW[threadIdx.x];
    __syncthreads();
    int dst = blockIdx.x * 4 + (threadIdx.x >> 6);
    if (dst >= n) return;
    const int lane = threadIdx.x & 63;
    const int h  = lane >> 3;   // consumer head
    const int pe = lane >> 3;   // producer edge
    const int ph = lane & 7;    // producer head
    const float L2E = 1.44269504f;
    int p0 = rowptr[dst], p1 = rowptr[dst + 1];
    float ald_p = aldst[dst * 8 + ph];   // producer-role dst coefficient
    float den = 0.f, acc0 = 0.f, acc1 = 0.f;
    const int nfull = (p1 - p0) >> 3;   // padded: no tail
    int p = p0;
    int svo = 0; unsigned w = 0;
    if (nfull > 0) {
        svo = csr_src[p + pe];
        w = *(const unsigned*)(eatb + (size_t)(p + pe) * 16 + ph * 2);
    }
    for (int c = 0; c < nfull; c++) {
        int csv = svo; unsigned cw = w;
        int pn = p + 8;
        if (c + 1 < nfull) {                         // prefetch next chunk
            svo = csr_src[pn + pe];
            w = *(const unsigned*)(eatb + (size_t)(pn + pe) * 16 + ph * 2);
        }
        // ---- producer: finished exp weight for (edge pe, head ph) ----
        int sc = csv < 0 ? 0 : csv;
        float pal = alsrc[sc * 8 + ph];
#pragma unroll
        for (int k = 0; k < 8; k++) {
            unsigned u = __shfl(cw, pe * 8 + k);
            pal += b2f_lo(u) * sAe[k * 16 + ph] + b2f_hi(u) * sAe[k * 16 + 8 + ph];
        }
        float lg = pal + ald_p;
        lg = lg > 0.f ? lg : 0.2f * lg;              // leaky_relu(0.2)
        float pex = exp2f(lg * L2E);
        if (csv < 0) pex = 0.f;                      // pad edge contributes nothing
        // ---- rows ----
        int t0 = __shfl(csv, 0),  t1 = __shfl(csv, 8),  t2 = __shfl(csv, 16), t3 = __shfl(csv, 24);
        int t4 = __shfl(csv, 32), t5 = __shfl(csv, 40), t6 = __shfl(csv, 48), t7 = __shfl(csv, 56);
        t0 = t0 < 0 ? 0 : t0;  t1 = t1 < 0 ? 0 : t1;
        t2 = t2 < 0 ? 0 : t2;  t3 = t3 < 0 ? 0 : t3;
        t4 = t4 < 0 ? 0 : t4;  t5 = t5 < 0 ? 0 : t5;
        t6 = t6 < 0 ? 0 : t6;  t7 = t7 < 0 ? 0 : t7;
        unsigned v0 = *(const unsigned*)(xsb + (size_t)t0 * 128 + lane * 2);
        unsigned v1 = *(const unsigned*)(xsb + (size_t)t1 * 128 + lane * 2);
        unsigned v2 = *(const unsigned*)(xsb + (size_t)t2 * 128 + lane * 2);
        unsigned v3 = *(const unsigned*)(xsb + (size_t)t3 * 128 + lane * 2);
        unsigned v4 = *(const unsigned*)(xsb + (size_t)t4 * 128 + lane * 2);
        unsigned v5 = *(const unsigned*)(xsb + (size_t)t5 * 128 + lane * 2);
        unsigned v6 = *(const unsigned*)(xsb + (size_t)t6 * 128 + lane * 2);
        unsigned v7 = *(const unsigned*)(xsb + (size_t)t7 * 128 + lane * 2);
        unsigned vv[8] = {v0, v1, v2, v3, v4, v5, v6, v7};
        // ---- consumer: weighted accumulate with ready weights ----
#pragma unroll
        for (int i = 0; i < 8; i++) {
            float ex = __shfl(pex, i * 8 + h);
            den  += ex;
            acc0 += b2f_lo(vv[i]) * ex;
            acc1 += b2f_hi(vv[i]) * ex;
        }
        p = pn;
    }
    float inv = 1.f / (den + 1e-16f);
    const float2 bb = *(const float2*)(b + lane * 2);
    unsigned o = pack2(f2b(acc0 * inv + bb.x), f2b(acc1 * inv + bb.y));
    *(unsigned*)(houtb + (size_t)dst * 128 + lane * 2) = o;
}

// ---------------- Wl1 [512(k),512(c)] f32 -> Wl1T [c][k] bf16 ----------------
__global__ void wl1t_k(const float* __restrict__ Wl1, short* __restrict__ Wl1T) {
    int idx = blockIdx.x * blockDim.x + threadIdx.x;   // 262144
    int k = idx >> 9, c = idx & 511;
    Wl1T[(size_t)c * 512 + k] = f2b(Wl1[idx]);
}

__global__ void init_out(float* __restrict__ out, const float* __restrict__ bl2, int n) {
    int t = blockIdx.x * blockDim.x + threadIdx.x;
    if (t < n) out[t] = bl2[0];
}

// ---------------- fused final MLP via bf16 MFMA: BK=128 double-buffer ----------------
__global__ __launch_bounds__(256) void final_mfma(
    const short* __restrict__ h1, const short* __restrict__ h2,
    const short* __restrict__ h3, const short* __restrict__ poolb,
    const int* __restrict__ batch, const short* __restrict__ Wl1T,
    const float* __restrict__ bl1, const float* __restrict__ Wl2,
    float* __restrict__ out, int nrows)
{
    __shared__ short Abuf[2][16 * 64 * 8];   // 2 x 16 KB: [buf][slot][row-lane][8]
    __shared__ int   sBatch[64];
    const int tid = threadIdx.x;
    const int n0 = blockIdx.x * 64;
    const int j0 = blockIdx.y * 256;
    const int wid = tid >> 6, lane = tid & 63;
    const int lr = lane & 15, kg = lane >> 4;

    if (tid < 64) {
        int gr = n0 + tid;
        sBatch[tid] = (gr < nrows) ? batch[gr] : 0;
    }
    __syncthreads();

    const short* seg_base[4] = {h1, h2, h3, poolb};

    auto STAGE = [&](int t) {
        const short* base = seg_base[t];
        int gr = n0 + lane;
        int grow = (t == 3) ? sBatch[lane] : ((gr < nrows) ? gr : 0);
        const short* rowp = base + (size_t)grow * 128;
#pragma unroll
        for (int q = 0; q < 4; q++) {
            const short* src = rowp + q * 32 + wid * 8;
#if __has_builtin(__builtin_amdgcn_global_load_lds)
            __builtin_amdgcn_global_load_lds(
                (const __attribute__((address_space(1))) unsigned int*)src,
                (__attribute__((address_space(3))) unsigned int*)
                    &Abuf[t & 1][((q * 4 + wid) * 64 + lane) * 8],
                16, 0, 0);
#else
            uint4 v = *(const uint4*)src;
            *(uint4*)(&Abuf[t & 1][((q * 4 + wid) * 64 + lane) * 8]) = v;
#endif
        }
    };

    f32x4 acc[4][4] = {};

    STAGE(0);
    __syncthreads();   // segment 0 landed (full drain)
#pragma unroll
    for (int t = 0; t < 4; t++) {
        if (t < 3) STAGE(t + 1);   // hides under this segment's 64 MFMAs
#pragma unroll
        for (int ks = 0; ks < 4; ks++) {
            bf16x8 a[4], b[4];
#pragma unroll
            for (int fn = 0; fn < 4; fn++)
                b[fn] = *(const bf16x8*)(Wl1T + (size_t)(j0 + wid * 64 + fn * 16 + lr) * 512
                                         + t * 128 + ks * 32 + kg * 8);
#pragma unroll
            for (int fm = 0; fm < 4; fm++)
                a[fm] = *(const bf16x8*)(&Abuf[t & 1][((ks * 4 + kg) * 64 + fm * 16 + lr) * 8]);
#pragma unroll
            for (int fm = 0; fm < 4; fm++)
#pragma unroll
                for (int fn = 0; fn < 4; fn++)
                    acc[fm][fn] = __builtin_amdgcn_mfma_f32_16x16x32_bf16(
                        a[fm], b[fn], acc[fm][fn], 0, 0, 0);
        }
        if (t < 3) __syncthreads();   // drains STAGE(t+1); buffer reads done
    }

    float w2[4], b1c[4];
#pragma unroll
    for (int fn = 0; fn < 4; fn++) {
        int c = j0 + wid * 64 + fn * 16 + lr;
        w2[fn]  = Wl2[c];
        b1c[fn] = bl1[c];
    }

#pragma unroll
    for (int fm = 0; fm < 4; fm++) {
#pragma unroll
        for (int r = 0; r < 4; r++) {
            float s = 0.f;
#pragma unroll
            for (int fn = 0; fn < 4; fn++) {
                float z = acc[fm][fn][r] + b1c[fn];
                z = z > 0.f ? z : 0.01f * z;
                s += z * w2[fn];
            }
            s += __shfl_xor(s, 1);
            s += __shfl_xor(s, 2);
            s += __shfl_xor(s, 4);
            s += __shfl_xor(s, 8);
            if (lr == 0) {
                int gr = n0 + fm * 16 + kg * 4 + r;
                if (gr < nrows) atomicAdd(out + gr, s);
            }
        }
    }
}

extern "C" void kernel_launch(void* const* d_in, const int* in_sizes, int n_in,
                              void* d_out, int out_size, void* d_ws, size_t ws_size,
                              hipStream_t stream) {
    const float* x     = (const float*)d_in[0];
    const int*   ei    = (const int*)d_in[1];
    const float* eattr = (const float*)d_in[2];
    const int*   batch = (const int*)d_in[3];
    const float* W[3]   = {(const float*)d_in[4],  (const float*)d_in[10], (const float*)d_in[16]};
    const float* We[3]  = {(const float*)d_in[5],  (const float*)d_in[11], (const float*)d_in[17]};
    const float* as_[3] = {(const float*)d_in[6],  (const float*)d_in[12], (const float*)d_in[18]};
    const float* ad_[3] = {(const float*)d_in[7],  (const float*)d_in[13], (const float*)d_in[19]};
    const float* ae_[3] = {(const float*)d_in[8],  (const float*)d_in[14], (const float*)d_in[20]};
    const float* b_[3]  = {(const float*)d_in[9],  (const float*)d_in[15], (const float*)d_in[21]};
    const float* Wl1 = (const float*)d_in[22];
    const float* bl1 = (const float*)d_in[23];
    const float* Wl2 = (const float*)d_in[24];
    const float* bl2 = (const float*)d_in[25];

    const int N = N_NODES, E = N_EDGES, G = N_GRAPH;

    float* ws    = (float*)d_ws;
    float* alsrc = ws;                          // N*8
    float* aldst = alsrc + (size_t)N * 8;       // N*8
    float* aeW3  = aldst + (size_t)N * 8;       // 3*128
    short* xsb   = (short*)(aeW3 + 384);        // N*128 bf16 (layer GEMM out)
    short* hb0   = xsb + (size_t)N * 128;       // N*128 bf16
    short* hb1   = hb0 + (size_t)N * 128;
    short* hb2   = hb1 + (size_t)N * 128;
    short* hb[3] = {hb0, hb1, hb2};
    short* poolb = hb2 + (size_t)N * 128;       // G*128 bf16
    short* wbt0  = poolb + (size_t)G * 128;     // 3 x 128*128 bf16
    short* wbt1  = wbt0 + 16384;
    short* wbt2  = wbt1 + 16384;
    short* wbt[3] = {wbt0, wbt1, wbt2};
    short* wl1t  = wbt2 + 16384;                // 512*512 bf16
    short* eatb  = wl1t + 262144;               // EPAD*16 bf16
    int*   cnt     = (int*)(eatb + (size_t)EPAD * 16);  // N
    int*   rowptr  = cnt + N;                   // N+1
    int*   cursor  = rowptr + N + 1;            // N
    int*   part    = cursor + N;                // 256
    int*   gb      = part + 256;                // G+1
    int*   csr_src = gb + G + 1;                // EPAD

    // ---- once per call: bf16 conversions + padded dst-CSR + graph bounds ----
    for (int l = 0; l < 3; l++)
        wbt_k<<<64, 256, 0, stream>>>(W[l], wbt[l]);
    wl1t_k<<<1024, 256, 0, stream>>>(Wl1, wl1t);
    aew3_k<<<3, 128, 0, stream>>>(We[0], ae_[0], We[1], ae_[1], We[2], ae_[2], aeW3);
    hipMemsetAsync(cnt, 0, (size_t)N * sizeof(int), stream);
    hipMemsetAsync(csr_src, 0x80, (size_t)EPAD * sizeof(int), stream);  // pads negative
    hist_k<<<(E + 255) / 256, 256, 0, stream>>>(ei, cnt, E);
    const int nblk = (N + 255) / 256;   // 196
    scan1_k<<<nblk, 256, 0, stream>>>(cnt, rowptr, part, N);
    scan2_k<<<1, 256, 0, stream>>>(part, nblk);
    scan3_k<<<nblk, 256, 0, stream>>>(rowptr, part, cnt, cursor, N);
    scatter_k<<<(E + 255) / 256, 256, 0, stream>>>(ei, eattr, cursor, csr_src, eatb, E);
    gbound_k<<<nblk, 256, 0, stream>>>(batch, gb, N, G);

    for (int l = 0; l < 3; l++) {
        if (l == 0)
            gemm_mfma<true><<<(N + 63) / 64, 256, 0, stream>>>(x, wbt[0], xsb, N);
        else
            gemm_mfma<false><<<(N + 63) / 64, 256, 0, stream>>>(hb[l - 1], wbt[l], xsb, N);
        node_al<<<(N * 8 + 255) / 256, 256, 0, stream>>>(xsb, as_[l], ad_[l], alsrc, aldst, N);
        gather_k<<<(N + 3) / 4, 256, 0, stream>>>(rowptr, csr_src, eatb, aeW3 + l * 128,
                                                  alsrc, aldst, xsb, b_[l], hb[l], N);
    }
    pools_k<<<G, 256, 0, stream>>>(hb[2], gb, poolb);

    init_out<<<(N + 255) / 256, 256, 0, stream>>>((float*)d_out, bl2, N);
    dim3 fg((N + 63) / 64, 2);
    final_mfma<<<fg, 256, 0, stream>>>(hb[0], hb[1], hb[2], poolb, batch,
                                       wl1t, bl1, Wl2, (float*)d_out, N);
}